// Round 1
// baseline (1754.481 us; speedup 1.0000x reference)
//
#include <hip/hip_runtime.h>
#include <math.h>

// Problem constants (from setup_inputs; k==8 is fixed by the harness inputs).
constexpr int B_   = 4;
constexpr int P_   = 384;
constexpr int M_   = 64;
constexpr int TOK  = 1024;
constexpr int C    = 128;
constexpr int RC   = 12;
constexpr int RP   = 12;
constexpr int KNN  = 8;
constexpr int NCTX = P_ * RC;      // 4608 ctx points per batch
constexpr int NPRD = M_ * RP;      // 768 pred points per batch
constexpr int NALL = NCTX + NPRD;  // 5376

// ---------------------------------------------------------------------------
// Wcat[t][0:128]  = We1[t] - We1[131+t]   (A part: xi @ (W1a - W1b))
// Wcat[t][128:256]= We1[131+t]            (B part: xj @ W1b)
__global__ __launch_bounds__(256) void wcat_kernel(const float* __restrict__ We1,
                                                   float* __restrict__ Wcat) {
  int n = blockIdx.x * 256 + threadIdx.x;
  if (n >= 131 * 256) return;
  int t = n >> 8, cc = n & 255;
  float v;
  if (cc < C) v = We1[t * C + cc] - We1[(131 + t) * C + cc];
  else        v = We1[(131 + t) * C + (cc - C)];
  Wcat[n] = v;
}

// ---------------------------------------------------------------------------
// tokens[rows][1024] @ Wp[1024][128] + bp ; 4 rows per block, 128 threads.
__global__ __launch_bounds__(128) void proj_kernel(const float* __restrict__ tok,
                                                   const float* __restrict__ Wp,
                                                   const float* __restrict__ bp,
                                                   float* __restrict__ out) {
  __shared__ float t_lds[4][TOK];
  const int tid = threadIdx.x;
  const int r0 = blockIdx.x * 4;
  for (int l = tid; l < 4 * TOK / 4; l += 128) {
    int idx4 = l * 4;
    int rr = idx4 >> 10, tt = idx4 & 1023;
    *(float4*)&t_lds[rr][tt] = *(const float4*)&tok[(r0 + rr) * TOK + tt];
  }
  __syncthreads();
  float a0 = 0.f, a1 = 0.f, a2 = 0.f, a3 = 0.f;
  #pragma unroll 4
  for (int t = 0; t < TOK; ++t) {
    float w = Wp[t * C + tid];
    a0 = fmaf(t_lds[0][t], w, a0);
    a1 = fmaf(t_lds[1][t], w, a1);
    a2 = fmaf(t_lds[2][t], w, a2);
    a3 = fmaf(t_lds[3][t], w, a3);
  }
  float b = bp[tid];
  out[(r0 + 0) * C + tid] = a0 + b;
  out[(r0 + 1) * C + tid] = a1 + b;
  out[(r0 + 2) * C + tid] = a2 + b;
  out[(r0 + 3) * C + tid] = a3 + b;
}

// ---------------------------------------------------------------------------
__global__ __launch_bounds__(64) void anchor_kernel(const float* __restrict__ cxyz,
                                                    float* __restrict__ anchor) {
  int b = blockIdx.x, d = blockIdx.y;
  float s = 0.f;
  for (int p = threadIdx.x; p < P_; p += 64) s += cxyz[(b * P_ + p) * 3 + d];
  for (int o = 32; o > 0; o >>= 1) s += __shfl_down(s, o);
  if (threadIdx.x == 0) anchor[b * 3 + d] = s * (1.0f / (float)P_);
}

// ---------------------------------------------------------------------------
__global__ __launch_bounds__(256) void build_ctx_kernel(const float* __restrict__ cxyz,
                                                        const float* __restrict__ noise,
                                                        float* __restrict__ xyz_all) {
  int n = blockIdx.x * 256 + threadIdx.x;
  if (n >= B_ * NCTX) return;
  int b = n / NCTX, i = n % NCTX, p = i / RC;
  float x = noise[n * 3 + 0], y = noise[n * 3 + 1], z = noise[n * 3 + 2];
  float s = 0.02f / (sqrtf(x * x + y * y + z * z) + 1e-6f);
  const float* c = &cxyz[(b * P_ + p) * 3];
  float* o = &xyz_all[(b * NALL + i) * 3];
  o[0] = c[0] + x * s;
  o[1] = c[1] + y * s;
  o[2] = c[2] + z * s;
}

__global__ __launch_bounds__(256) void build_pred_kernel(const float* __restrict__ anchor,
                                                         const float* __restrict__ noise,
                                                         float* __restrict__ xyz_all) {
  int n = blockIdx.x * 256 + threadIdx.x;
  if (n >= B_ * NPRD) return;
  int b = n / NPRD, i = n % NPRD;
  float x = noise[n * 3 + 0], y = noise[n * 3 + 1], z = noise[n * 3 + 2];
  float s = 0.05f / (sqrtf(x * x + y * y + z * z) + 1e-6f);
  const float* a = &anchor[b * 3];
  float* o = &xyz_all[(b * NALL + NCTX + i) * 3];
  o[0] = a[0] + x * s;
  o[1] = a[1] + y * s;
  o[2] = a[2] + z * s;
}

// ---------------------------------------------------------------------------
// Brute-force kNN (k=8), one graph per blockIdx.x, 256 queries per blockIdx.y.
// Row of point i of graph gr: (gr/GPB)*NALL + row_off + (gr%GPB)*Npg + i.
// idx_out holds stage-local point ids: gr*Npg + j.
__global__ __launch_bounds__(256) void knn_kernel(const float* __restrict__ xyz_all,
                                                  int Npg, int GPB, int row_off,
                                                  int* __restrict__ idx_out) {
  __shared__ float4 tile[256];
  int gr = blockIdx.x;
  int b = gr / GPB, w = gr % GPB;
  const float* base = xyz_all + (size_t)(b * NALL + row_off + w * Npg) * 3;

  int qi = blockIdx.y * 256 + threadIdx.x;
  bool act = qi < Npg;
  float qx = 0.f, qy = 0.f, qz = 0.f, sqi = 0.f;
  if (act) {
    qx = base[qi * 3 + 0]; qy = base[qi * 3 + 1]; qz = base[qi * 3 + 2];
    sqi = qx * qx + qy * qy + qz * qz;
  }
  float bd[KNN];
  int   bi[KNN];
  #pragma unroll
  for (int u = 0; u < KNN; ++u) { bd[u] = 3e38f; bi[u] = 0; }

  for (int ts = 0; ts < Npg; ts += 256) {
    int nj = min(256, Npg - ts);
    __syncthreads();
    if (threadIdx.x < nj) {
      int j = ts + threadIdx.x;
      float x = base[j * 3 + 0], y = base[j * 3 + 1], z = base[j * 3 + 2];
      tile[threadIdx.x] = make_float4(x, y, z, x * x + y * y + z * z);
    }
    __syncthreads();
    if (act) {
      for (int jj = 0; jj < nj; ++jj) {
        float4 t = tile[jj];
        // same formula as reference: sq_i + sq_j - 2*dot
        float d2 = sqi + t.w - 2.0f * (qx * t.x + qy * t.y + qz * t.z);
        int j = ts + jj;
        if (j != qi && d2 < bd[KNN - 1]) {   // strict <: keeps earlier index on ties
          bd[KNN - 1] = d2; bi[KNN - 1] = j;
          #pragma unroll
          for (int u = KNN - 1; u > 0; --u) {
            if (bd[u] < bd[u - 1]) {
              float td = bd[u]; bd[u] = bd[u - 1]; bd[u - 1] = td;
              int   ti = bi[u]; bi[u] = bi[u - 1]; bi[u - 1] = ti;
            }
          }
        }
      }
    }
  }
  if (act) {
    int g = gr * Npg + qi;
    #pragma unroll
    for (int u = 0; u < KNN; ++u) idx_out[g * KNN + u] = gr * Npg + bi[u];
  }
}

// ---------------------------------------------------------------------------
// AB[g][0:128] = x_g @ (W1a-W1b) + be1 ; AB[g][128:256] = x_g @ W1b
// x_g = [feat(128), xyz(3)]. 8 points per block, 256 threads (one output col each).
__global__ __launch_bounds__(256) void precompute_kernel(const float* __restrict__ feat,
                                                         int feat_div,
                                                         const float* __restrict__ xyz_all,
                                                         int NPB, int row_off,
                                                         const float* __restrict__ Wcat,
                                                         const float* __restrict__ be1,
                                                         float* __restrict__ AB) {
  __shared__ float x_lds[8][132];
  const int tid = threadIdx.x;
  const int base = blockIdx.x * 8;
  for (int l = tid; l < 8 * 131; l += 256) {
    int pt = l / 131, t = l % 131;
    int g = base + pt;
    float v;
    if (t < C) {
      v = feat[(g / feat_div) * C + t];
    } else {
      int b = g / NPB, loc = g % NPB;
      v = xyz_all[(b * NALL + row_off + loc) * 3 + (t - C)];
    }
    x_lds[pt][t] = v;
  }
  __syncthreads();
  float acc[8] = {0.f, 0.f, 0.f, 0.f, 0.f, 0.f, 0.f, 0.f};
  #pragma unroll 1
  for (int t = 0; t < 131; ++t) {
    float wv = Wcat[t * 256 + tid];
    #pragma unroll
    for (int p = 0; p < 8; ++p) acc[p] = fmaf(x_lds[p][t], wv, acc[p]);
  }
  float bias = (tid < C) ? be1[tid] : 0.0f;
  #pragma unroll
  for (int p = 0; p < 8; ++p) AB[(base + p) * 256 + tid] = acc[p] + bias;
}

// ---------------------------------------------------------------------------
// EdgeConv core: per point i, feat_out[i] = max_n ( relu(A_i + B_{j_n}) @ We2 ) + be2.
// 4 points per block, 256 threads. We2 staged in LDS in two 64-row chunks (32 KB).
// Thread tile: 2 neighbors (ng=tid>>6) x 2 channels (c, c+64).
__global__ __launch_bounds__(256) void conv_kernel(const float* __restrict__ AB,
                                                   const int* __restrict__ idx,
                                                   const float* __restrict__ We2,
                                                   const float* __restrict__ be2,
                                                   float* __restrict__ feat_out,
                                                   int NPB, int row_off) {
  __shared__ float w2c[64 * C];       // 32 KB chunk of We2
  __shared__ float h1[4][KNN][C];     // 16 KB
  __shared__ float a_lds[4][C];       // 2 KB
  __shared__ float red[4][C];         // 2 KB
  const int tid = threadIdx.x;
  const int base = blockIdx.x * 4;

  // A rows for the 4 points
  for (int l = tid; l < 4 * C; l += 256) {
    int p = l >> 7, t = l & 127;
    a_lds[p][t] = AB[(base + p) * 256 + t];
  }
  __syncthreads();
  // h1[p][n][t] = relu(A_i[t] + B_j[t])
  for (int l = tid; l < 4 * KNN * C; l += 256) {
    int p = l >> 10, rem = l & 1023, n = rem >> 7, t = rem & 127;
    int jg = idx[(base + p) * KNN + n];
    h1[p][n][t] = fmaxf(a_lds[p][t] + AB[jg * 256 + C + t], 0.0f);
  }

  const int ng = tid >> 6;   // neighbor pair 2ng, 2ng+1
  const int c  = tid & 63;   // channels c, c+64
  float s[4][4];
  #pragma unroll
  for (int p = 0; p < 4; ++p)
    #pragma unroll
    for (int q = 0; q < 4; ++q) s[p][q] = 0.f;

  for (int kk = 0; kk < 2; ++kk) {
    __syncthreads();
    for (int l = tid * 4; l < 64 * C; l += 1024)
      *(float4*)&w2c[l] = *(const float4*)&We2[kk * 64 * C + l];
    __syncthreads();
    #pragma unroll
    for (int p = 0; p < 4; ++p) {
      const float* h0p = &h1[p][2 * ng + 0][kk * 64];
      const float* h1p = &h1[p][2 * ng + 1][kk * 64];
      #pragma unroll 4
      for (int t = 0; t < 64; ++t) {
        float w0 = w2c[t * C + c];
        float w1 = w2c[t * C + c + 64];
        float ha = h0p[t], hb = h1p[t];
        s[p][0] = fmaf(ha, w0, s[p][0]);
        s[p][1] = fmaf(ha, w1, s[p][1]);
        s[p][2] = fmaf(hb, w0, s[p][2]);
        s[p][3] = fmaf(hb, w1, s[p][3]);
      }
    }
  }

  #pragma unroll 1
  for (int p = 0; p < 4; ++p) {
    red[ng][c]      = fmaxf(s[p][0], s[p][2]);
    red[ng][c + 64] = fmaxf(s[p][1], s[p][3]);
    __syncthreads();
    if (tid < C) {
      float m = fmaxf(fmaxf(red[0][tid], red[1][tid]),
                      fmaxf(red[2][tid], red[3][tid]));
      int g = base + p;
      int b = g / NPB, loc = g % NPB;
      feat_out[(b * NALL + row_off + loc) * C + tid] = m + be2[tid];
    }
    __syncthreads();
  }
}

// ---------------------------------------------------------------------------
// offset MLP: out_row = xyz_in_row + (relu(f@W1+b1) @ W2 + b2).
// 16 points per block (8 pairs), 256 threads; W1 staged in two 32 KB chunks.
__global__ __launch_bounds__(256) void offset_kernel(const float* __restrict__ feat,
                                                     const float* __restrict__ W1,
                                                     const float* __restrict__ b1,
                                                     const float* __restrict__ W2,
                                                     const float* __restrict__ b2,
                                                     const float* __restrict__ xyz_in,
                                                     float* __restrict__ xyz_out,
                                                     int NPB, int row_off) {
  __shared__ float w1c[64 * C];      // 32 KB chunk of W1
  __shared__ float f_lds[16][C];     // 8 KB
  __shared__ float wred[4][3];
  const int tid = threadIdx.x;
  const int base = blockIdx.x * 16;
  const int p = tid >> 7;            // which point of the pair
  const int cc = tid & 127;          // hidden channel
  const int wave = tid >> 6, lane = tid & 63;

  // load all 16 points' features (mapped rows)
  for (int l = tid; l < 16 * C; l += 256) {
    int pt = l >> 7, t = l & 127;
    int g = base + pt;
    int b = g / NPB, loc = g % NPB;
    f_lds[pt][t] = feat[(b * NALL + row_off + loc) * C + t];
  }

  float s[8];
  #pragma unroll
  for (int pp = 0; pp < 8; ++pp) s[pp] = 0.f;

  for (int kk = 0; kk < 2; ++kk) {
    __syncthreads();
    for (int l = tid * 4; l < 64 * C; l += 1024)
      *(float4*)&w1c[l] = *(const float4*)&W1[kk * 64 * C + l];
    __syncthreads();
    #pragma unroll
    for (int pp = 0; pp < 8; ++pp) {
      const float* f = &f_lds[pp * 2 + p][kk * 64];
      float acc = s[pp];
      #pragma unroll 4
      for (int t = 0; t < 64; ++t) acc = fmaf(f[t], w1c[t * C + cc], acc);
      s[pp] = acc;
    }
  }

  float b1v = b1[cc];
  float w20 = W2[cc * 3 + 0], w21 = W2[cc * 3 + 1], w22 = W2[cc * 3 + 2];
  float b20 = b2[0], b21 = b2[1], b22 = b2[2];

  #pragma unroll 1
  for (int pp = 0; pp < 8; ++pp) {
    float h = fmaxf(s[pp] + b1v, 0.0f);
    float p0 = h * w20, p1 = h * w21, p2 = h * w22;
    for (int o = 32; o > 0; o >>= 1) {
      p0 += __shfl_down(p0, o);
      p1 += __shfl_down(p1, o);
      p2 += __shfl_down(p2, o);
    }
    if (lane == 0) { wred[wave][0] = p0; wred[wave][1] = p1; wred[wave][2] = p2; }
    __syncthreads();
    if (tid < 2) {
      int g = base + pp * 2 + tid;
      int b = g / NPB, loc = g % NPB;
      int row = (b * NALL + row_off + loc) * 3;
      float o0 = wred[tid * 2][0] + wred[tid * 2 + 1][0] + b20;
      float o1 = wred[tid * 2][1] + wred[tid * 2 + 1][1] + b21;
      float o2 = wred[tid * 2][2] + wred[tid * 2 + 1][2] + b22;
      xyz_out[row + 0] = xyz_in[row + 0] + o0;
      xyz_out[row + 1] = xyz_in[row + 1] + o1;
      xyz_out[row + 2] = xyz_in[row + 2] + o2;
    }
    __syncthreads();
  }
}

// ---------------------------------------------------------------------------
extern "C" void kernel_launch(void* const* d_in, const int* in_sizes, int n_in,
                              void* d_out, int out_size, void* d_ws, size_t ws_size,
                              hipStream_t stream) {
  (void)in_sizes; (void)n_in; (void)out_size; (void)ws_size;
  const float* ctx_xyz   = (const float*)d_in[0];
  const float* ctx_tok   = (const float*)d_in[1];
  const float* pred_tok  = (const float*)d_in[2];
  const float* noise_ctx = (const float*)d_in[3];
  const float* noise_prd = (const float*)d_in[4];
  const float* Wp  = (const float*)d_in[5];
  const float* bp  = (const float*)d_in[6];
  const float* We1 = (const float*)d_in[7];
  const float* be1 = (const float*)d_in[8];
  const float* We2 = (const float*)d_in[9];
  const float* be2 = (const float*)d_in[10];
  const float* Wc1 = (const float*)d_in[11];
  const float* bc1 = (const float*)d_in[12];
  const float* Wc2 = (const float*)d_in[13];
  const float* bc2 = (const float*)d_in[14];
  const float* Wq1 = (const float*)d_in[15];
  const float* bq1 = (const float*)d_in[16];
  const float* Wq2 = (const float*)d_in[17];
  const float* bq2 = (const float*)d_in[18];
  const float* Wf1 = (const float*)d_in[19];
  const float* bf1 = (const float*)d_in[20];
  const float* Wf2 = (const float*)d_in[21];
  const float* bf2 = (const float*)d_in[22];
  // d_in[23] = k (always 8 in this problem configuration)
  float* out = (float*)d_out;

  // workspace layout (floats) — total ~46.8 MB
  float* ws        = (float*)d_ws;
  float* ctx_feat  = ws;                          // B*P*C       = 196608
  float* pred_feat = ctx_feat + B_ * P_ * C;      // B*M*C       = 32768
  float* anchor    = pred_feat + B_ * M_ * C;     // 16
  float* xyz_all   = anchor + 16;                 // B*NALL*3    = 64512
  float* feat_in   = xyz_all + B_ * NALL * 3;     // B*NALL*C    = 2752512
  float* feat_out  = feat_in + B_ * NALL * C;     // B*NALL*C    = 2752512
  float* AB        = feat_out + B_ * NALL * C;    // B*NALL*256  = 5505024
  float* Wcat      = AB + B_ * NALL * 256;        // 131*256     = 33536
  int*   idx1      = (int*)(Wcat + 131 * 256);    // B*NCTX*8    = 147456
  int*   idx2      = idx1 + B_ * NCTX * KNN;      // B*NPRD*8    = 24576
  int*   idx3      = idx2 + B_ * NPRD * KNN;      // B*NALL*8    = 172032

  // prep + projections + geometry
  wcat_kernel<<<131, 256, 0, stream>>>(We1, Wcat);
  proj_kernel<<<(B_ * P_) / 4, 128, 0, stream>>>(ctx_tok, Wp, bp, ctx_feat);
  proj_kernel<<<(B_ * M_) / 4, 128, 0, stream>>>(pred_tok, Wp, bp, pred_feat);
  anchor_kernel<<<dim3(B_, 3), 64, 0, stream>>>(ctx_xyz, anchor);
  build_ctx_kernel<<<(B_ * NCTX) / 256, 256, 0, stream>>>(ctx_xyz, noise_ctx, xyz_all);
  build_pred_kernel<<<(B_ * NPRD + 255) / 256, 256, 0, stream>>>(anchor, noise_prd, xyz_all);

  // ---- stage 1: context branch (4 graphs of 4608 points) ----
  knn_kernel<<<dim3(B_, NCTX / 256), 256, 0, stream>>>(xyz_all, NCTX, 1, 0, idx1);
  precompute_kernel<<<(B_ * NCTX) / 8, 256, 0, stream>>>(ctx_feat, RC, xyz_all, NCTX, 0, Wcat, be1, AB);
  conv_kernel<<<(B_ * NCTX) / 4, 256, 0, stream>>>(AB, idx1, We2, be2, feat_in, NCTX, 0);
  offset_kernel<<<(B_ * NCTX) / 16, 256, 0, stream>>>(feat_in, Wc1, bc1, Wc2, bc2,
                                                      xyz_all, xyz_all, NCTX, 0);

  // ---- stage 2: prediction branch (256 graphs of 12 points) ----
  knn_kernel<<<dim3(B_ * M_, 1), 256, 0, stream>>>(xyz_all, RP, M_, NCTX, idx2);
  precompute_kernel<<<(B_ * NPRD) / 8, 256, 0, stream>>>(pred_feat, RP, xyz_all, NPRD, NCTX, Wcat, be1, AB);
  conv_kernel<<<(B_ * NPRD) / 4, 256, 0, stream>>>(AB, idx2, We2, be2, feat_in, NPRD, NCTX);
  offset_kernel<<<(B_ * NPRD) / 16, 256, 0, stream>>>(feat_in, Wq1, bq1, Wq2, bq2,
                                                      xyz_all, xyz_all, NPRD, NCTX);

  // ---- stage 3: global refinement (4 graphs of 5376 points) ----
  knn_kernel<<<dim3(B_, NALL / 256), 256, 0, stream>>>(xyz_all, NALL, 1, 0, idx3);
  precompute_kernel<<<(B_ * NALL) / 8, 256, 0, stream>>>(feat_in, 1, xyz_all, NALL, 0, Wcat, be1, AB);
  conv_kernel<<<(B_ * NALL) / 4, 256, 0, stream>>>(AB, idx3, We2, be2, feat_out, NALL, 0);
  offset_kernel<<<(B_ * NALL) / 16, 256, 0, stream>>>(feat_out, Wf1, bf1, Wf2, bf2,
                                                      xyz_all, out, NALL, 0);
}

// Round 2
// 1005.058 us; speedup vs baseline: 1.7457x; 1.7457x over previous
//
#include <hip/hip_runtime.h>
#include <math.h>

// Problem constants (from setup_inputs; k==8 is fixed by the harness inputs).
constexpr int B_   = 4;
constexpr int P_   = 384;
constexpr int M_   = 64;
constexpr int TOK  = 1024;
constexpr int C    = 128;
constexpr int RC   = 12;
constexpr int RP   = 12;
constexpr int KNN  = 8;
constexpr int NCTX = P_ * RC;      // 4608 ctx points per batch
constexpr int NPRD = M_ * RP;      // 768 pred points per batch
constexpr int NALL = NCTX + NPRD;  // 5376

// ---------------------------------------------------------------------------
// Wcat[t][0:128]  = We1[t] - We1[131+t]   (A part: xi @ (W1a - W1b))
// Wcat[t][128:256]= We1[131+t]            (B part: xj @ W1b)
__global__ __launch_bounds__(256) void wcat_kernel(const float* __restrict__ We1,
                                                   float* __restrict__ Wcat) {
  int n = blockIdx.x * 256 + threadIdx.x;
  if (n >= 131 * 256) return;
  int t = n >> 8, cc = n & 255;
  float v;
  if (cc < C) v = We1[t * C + cc] - We1[(131 + t) * C + cc];
  else        v = We1[(131 + t) * C + (cc - C)];
  Wcat[n] = v;
}

// ---------------------------------------------------------------------------
// tokens[rows][1024] @ Wp[1024][128] + bp ; 4 rows per block, 128 threads.
__global__ __launch_bounds__(128) void proj_kernel(const float* __restrict__ tok,
                                                   const float* __restrict__ Wp,
                                                   const float* __restrict__ bp,
                                                   float* __restrict__ out) {
  __shared__ float t_lds[4][TOK];
  const int tid = threadIdx.x;
  const int r0 = blockIdx.x * 4;
  for (int l = tid; l < 4 * TOK / 4; l += 128) {
    int idx4 = l * 4;
    int rr = idx4 >> 10, tt = idx4 & 1023;
    *(float4*)&t_lds[rr][tt] = *(const float4*)&tok[(r0 + rr) * TOK + tt];
  }
  __syncthreads();
  float a0 = 0.f, a1 = 0.f, a2 = 0.f, a3 = 0.f;
  #pragma unroll 4
  for (int t = 0; t < TOK; ++t) {
    float w = Wp[t * C + tid];
    a0 = fmaf(t_lds[0][t], w, a0);
    a1 = fmaf(t_lds[1][t], w, a1);
    a2 = fmaf(t_lds[2][t], w, a2);
    a3 = fmaf(t_lds[3][t], w, a3);
  }
  float b = bp[tid];
  out[(r0 + 0) * C + tid] = a0 + b;
  out[(r0 + 1) * C + tid] = a1 + b;
  out[(r0 + 2) * C + tid] = a2 + b;
  out[(r0 + 3) * C + tid] = a3 + b;
}

// ---------------------------------------------------------------------------
__global__ __launch_bounds__(64) void anchor_kernel(const float* __restrict__ cxyz,
                                                    float* __restrict__ anchor) {
  int b = blockIdx.x, d = blockIdx.y;
  float s = 0.f;
  for (int p = threadIdx.x; p < P_; p += 64) s += cxyz[(b * P_ + p) * 3 + d];
  for (int o = 32; o > 0; o >>= 1) s += __shfl_down(s, o);
  if (threadIdx.x == 0) anchor[b * 3 + d] = s * (1.0f / (float)P_);
}

// ---------------------------------------------------------------------------
__global__ __launch_bounds__(256) void build_ctx_kernel(const float* __restrict__ cxyz,
                                                        const float* __restrict__ noise,
                                                        float* __restrict__ xyz_all) {
  int n = blockIdx.x * 256 + threadIdx.x;
  if (n >= B_ * NCTX) return;
  int b = n / NCTX, i = n % NCTX, p = i / RC;
  float x = noise[n * 3 + 0], y = noise[n * 3 + 1], z = noise[n * 3 + 2];
  float s = 0.02f / (sqrtf(x * x + y * y + z * z) + 1e-6f);
  const float* c = &cxyz[(b * P_ + p) * 3];
  float* o = &xyz_all[(b * NALL + i) * 3];
  o[0] = c[0] + x * s;
  o[1] = c[1] + y * s;
  o[2] = c[2] + z * s;
}

__global__ __launch_bounds__(256) void build_pred_kernel(const float* __restrict__ anchor,
                                                         const float* __restrict__ noise,
                                                         float* __restrict__ xyz_all) {
  int n = blockIdx.x * 256 + threadIdx.x;
  if (n >= B_ * NPRD) return;
  int b = n / NPRD, i = n % NPRD;
  float x = noise[n * 3 + 0], y = noise[n * 3 + 1], z = noise[n * 3 + 2];
  float s = 0.05f / (sqrtf(x * x + y * y + z * z) + 1e-6f);
  const float* a = &anchor[b * 3];
  float* o = &xyz_all[(b * NALL + NCTX + i) * 3];
  o[0] = a[0] + x * s;
  o[1] = a[1] + y * s;
  o[2] = a[2] + z * s;
}

// ---------------------------------------------------------------------------
// Wave-per-query kNN (k=8) for the big per-batch graphs (GPB==1).
// Grid: (B, Npg/4); block = 256 = 4 waves, one query per wave.
// 64 lanes partition candidates by j % 64; per-lane sorted top-8 in registers;
// 8-round wave pop-min merge with (d2, idx) tie-break by smaller idx — matches
// jax.lax.top_k stability combined with strict-< ascending-j insertion.
__global__ __launch_bounds__(256) void knn_wave_kernel(const float* __restrict__ xyz_all,
                                                       int Npg, int row_off,
                                                       int* __restrict__ idx_out) {
  __shared__ float4 tile[256];
  const int b = blockIdx.x;
  const float* base = xyz_all + (size_t)(b * NALL + row_off) * 3;
  const int tid = threadIdx.x;
  const int wv = tid >> 6, lane = tid & 63;
  const int qi = blockIdx.y * 4 + wv;

  const float qx = base[qi * 3 + 0], qy = base[qi * 3 + 1], qz = base[qi * 3 + 2];
  const float sqi = qx * qx + qy * qy + qz * qz;

  float bd[KNN];
  int   bi[KNN];
  #pragma unroll
  for (int u = 0; u < KNN; ++u) { bd[u] = 3e38f; bi[u] = 0x7fffffff; }

  for (int ts = 0; ts < Npg; ts += 256) {
    int nj = min(256, Npg - ts);
    __syncthreads();
    if (tid < nj) {
      int j = ts + tid;
      float x = base[j * 3 + 0], y = base[j * 3 + 1], z = base[j * 3 + 2];
      tile[tid] = make_float4(x, y, z, x * x + y * y + z * z);
    }
    __syncthreads();
    #pragma unroll
    for (int u = 0; u < 4; ++u) {
      int jj = lane + 64 * u;
      if (jj < nj) {
        float4 t = tile[jj];
        // same formula as reference: sq_i + sq_j - 2*dot
        float d2 = sqi + t.w - 2.0f * (qx * t.x + qy * t.y + qz * t.z);
        int j = ts + jj;
        if (j != qi && d2 < bd[KNN - 1]) {   // strict <: earlier j wins ties
          bd[KNN - 1] = d2; bi[KNN - 1] = j;
          #pragma unroll
          for (int u2 = KNN - 1; u2 > 0; --u2) {
            if (bd[u2] < bd[u2 - 1]) {
              float td = bd[u2]; bd[u2] = bd[u2 - 1]; bd[u2 - 1] = td;
              int   ti = bi[u2]; bi[u2] = bi[u2 - 1]; bi[u2 - 1] = ti;
            }
          }
        }
      }
    }
  }

  // merge the 64 per-lane sorted lists: 8 rounds of wave-wide pop-min
  const int g = b * Npg + qi;
  #pragma unroll 1
  for (int r = 0; r < KNN; ++r) {
    float d = bd[0];
    int   i = bi[0];
    #pragma unroll
    for (int m = 1; m < 64; m <<= 1) {
      float od = __shfl_xor(d, m);
      int   oi = __shfl_xor(i, m);
      if (od < d || (od == d && oi < i)) { d = od; i = oi; }
    }
    if (lane == 0) idx_out[g * KNN + r] = b * Npg + i;
    if (bi[0] == i) {   // unique owner pops its head
      #pragma unroll
      for (int u = 0; u < KNN - 1; ++u) { bd[u] = bd[u + 1]; bi[u] = bi[u + 1]; }
      bd[KNN - 1] = 3e38f; bi[KNN - 1] = 0x7fffffff;
    }
  }
}

// ---------------------------------------------------------------------------
// Packed thread-per-query kNN for the 12-point prediction graphs.
// q over B*M*RP queries; graph gr = q/RP lives at row NCTX + (gr%M)*RP.
__global__ __launch_bounds__(256) void knn_small_kernel(const float* __restrict__ xyz_all,
                                                        int* __restrict__ idx_out) {
  int q = blockIdx.x * 256 + threadIdx.x;
  if (q >= B_ * M_ * RP) return;
  int gr = q / RP, qi = q % RP;
  int b = gr / M_, w = gr % M_;
  const float* base = xyz_all + (size_t)(b * NALL + NCTX + w * RP) * 3;

  float cx[RP], cy[RP], cz[RP], cs[RP];
  #pragma unroll
  for (int j = 0; j < RP; ++j) {
    cx[j] = base[j * 3 + 0]; cy[j] = base[j * 3 + 1]; cz[j] = base[j * 3 + 2];
    cs[j] = cx[j] * cx[j] + cy[j] * cy[j] + cz[j] * cz[j];
  }
  float qx = cx[0], qy = cy[0], qz = cz[0], sqi = cs[0];
  #pragma unroll
  for (int j = 0; j < RP; ++j) {
    if (j == qi) { qx = cx[j]; qy = cy[j]; qz = cz[j]; sqi = cs[j]; }
  }

  float bd[KNN];
  int   bi[KNN];
  #pragma unroll
  for (int u = 0; u < KNN; ++u) { bd[u] = 3e38f; bi[u] = 0; }

  #pragma unroll
  for (int j = 0; j < RP; ++j) {
    float d2 = sqi + cs[j] - 2.0f * (qx * cx[j] + qy * cy[j] + qz * cz[j]);
    if (j != qi && d2 < bd[KNN - 1]) {
      bd[KNN - 1] = d2; bi[KNN - 1] = j;
      #pragma unroll
      for (int u = KNN - 1; u > 0; --u) {
        if (bd[u] < bd[u - 1]) {
          float td = bd[u]; bd[u] = bd[u - 1]; bd[u - 1] = td;
          int   ti = bi[u]; bi[u] = bi[u - 1]; bi[u - 1] = ti;
        }
      }
    }
  }
  #pragma unroll
  for (int u = 0; u < KNN; ++u) idx_out[q * KNN + u] = gr * RP + bi[u];
}

// ---------------------------------------------------------------------------
// AB[g][0:128] = x_g @ (W1a-W1b) + be1 ; AB[g][128:256] = x_g @ W1b
// x_g = [feat(128), xyz(3)]. 8 points per block, 256 threads (one output col each).
__global__ __launch_bounds__(256) void precompute_kernel(const float* __restrict__ feat,
                                                         int feat_div,
                                                         const float* __restrict__ xyz_all,
                                                         int NPB, int row_off,
                                                         const float* __restrict__ Wcat,
                                                         const float* __restrict__ be1,
                                                         float* __restrict__ AB) {
  __shared__ float x_lds[8][132];
  const int tid = threadIdx.x;
  const int base = blockIdx.x * 8;
  for (int l = tid; l < 8 * 131; l += 256) {
    int pt = l / 131, t = l % 131;
    int g = base + pt;
    float v;
    if (t < C) {
      v = feat[(g / feat_div) * C + t];
    } else {
      int b = g / NPB, loc = g % NPB;
      v = xyz_all[(b * NALL + row_off + loc) * 3 + (t - C)];
    }
    x_lds[pt][t] = v;
  }
  __syncthreads();
  float acc[8] = {0.f, 0.f, 0.f, 0.f, 0.f, 0.f, 0.f, 0.f};
  #pragma unroll 1
  for (int t = 0; t < 131; ++t) {
    float wv = Wcat[t * 256 + tid];
    #pragma unroll
    for (int p = 0; p < 8; ++p) acc[p] = fmaf(x_lds[p][t], wv, acc[p]);
  }
  float bias = (tid < C) ? be1[tid] : 0.0f;
  #pragma unroll
  for (int p = 0; p < 8; ++p) AB[(base + p) * 256 + tid] = acc[p] + bias;
}

// ---------------------------------------------------------------------------
// EdgeConv core: per point i, feat_out[i] = max_n ( relu(A_i + B_{j_n}) @ We2 ) + be2.
// 4 points per block, 256 threads. We2 staged in LDS in two 64-row chunks (32 KB).
// Thread tile: 2 neighbors (ng=tid>>6) x 2 channels (c, c+64).
__global__ __launch_bounds__(256) void conv_kernel(const float* __restrict__ AB,
                                                   const int* __restrict__ idx,
                                                   const float* __restrict__ We2,
                                                   const float* __restrict__ be2,
                                                   float* __restrict__ feat_out,
                                                   int NPB, int row_off) {
  __shared__ float w2c[64 * C];       // 32 KB chunk of We2
  __shared__ float h1[4][KNN][C];     // 16 KB
  __shared__ float a_lds[4][C];       // 2 KB
  __shared__ float red[4][C];         // 2 KB
  const int tid = threadIdx.x;
  const int base = blockIdx.x * 4;

  // A rows for the 4 points
  for (int l = tid; l < 4 * C; l += 256) {
    int p = l >> 7, t = l & 127;
    a_lds[p][t] = AB[(base + p) * 256 + t];
  }
  __syncthreads();
  // h1[p][n][t] = relu(A_i[t] + B_j[t])
  for (int l = tid; l < 4 * KNN * C; l += 256) {
    int p = l >> 10, rem = l & 1023, n = rem >> 7, t = rem & 127;
    int jg = idx[(base + p) * KNN + n];
    h1[p][n][t] = fmaxf(a_lds[p][t] + AB[jg * 256 + C + t], 0.0f);
  }

  const int ng = tid >> 6;   // neighbor pair 2ng, 2ng+1
  const int c  = tid & 63;   // channels c, c+64
  float s[4][4];
  #pragma unroll
  for (int p = 0; p < 4; ++p)
    #pragma unroll
    for (int q = 0; q < 4; ++q) s[p][q] = 0.f;

  for (int kk = 0; kk < 2; ++kk) {
    __syncthreads();
    for (int l = tid * 4; l < 64 * C; l += 1024)
      *(float4*)&w2c[l] = *(const float4*)&We2[kk * 64 * C + l];
    __syncthreads();
    #pragma unroll
    for (int p = 0; p < 4; ++p) {
      const float* h0p = &h1[p][2 * ng + 0][kk * 64];
      const float* h1p = &h1[p][2 * ng + 1][kk * 64];
      #pragma unroll 4
      for (int t = 0; t < 64; ++t) {
        float w0 = w2c[t * C + c];
        float w1 = w2c[t * C + c + 64];
        float ha = h0p[t], hb = h1p[t];
        s[p][0] = fmaf(ha, w0, s[p][0]);
        s[p][1] = fmaf(ha, w1, s[p][1]);
        s[p][2] = fmaf(hb, w0, s[p][2]);
        s[p][3] = fmaf(hb, w1, s[p][3]);
      }
    }
  }

  #pragma unroll 1
  for (int p = 0; p < 4; ++p) {
    red[ng][c]      = fmaxf(s[p][0], s[p][2]);
    red[ng][c + 64] = fmaxf(s[p][1], s[p][3]);
    __syncthreads();
    if (tid < C) {
      float m = fmaxf(fmaxf(red[0][tid], red[1][tid]),
                      fmaxf(red[2][tid], red[3][tid]));
      int g = base + p;
      int b = g / NPB, loc = g % NPB;
      feat_out[(b * NALL + row_off + loc) * C + tid] = m + be2[tid];
    }
    __syncthreads();
  }
}

// ---------------------------------------------------------------------------
// offset MLP: out_row = xyz_in_row + (relu(f@W1+b1) @ W2 + b2).
// 16 points per block (8 pairs), 256 threads; W1 staged in two 32 KB chunks.
__global__ __launch_bounds__(256) void offset_kernel(const float* __restrict__ feat,
                                                     const float* __restrict__ W1,
                                                     const float* __restrict__ b1,
                                                     const float* __restrict__ W2,
                                                     const float* __restrict__ b2,
                                                     const float* __restrict__ xyz_in,
                                                     float* __restrict__ xyz_out,
                                                     int NPB, int row_off) {
  __shared__ float w1c[64 * C];      // 32 KB chunk of W1
  __shared__ float f_lds[16][C];     // 8 KB
  __shared__ float wred[4][3];
  const int tid = threadIdx.x;
  const int base = blockIdx.x * 16;
  const int p = tid >> 7;            // which point of the pair
  const int cc = tid & 127;          // hidden channel
  const int wave = tid >> 6, lane = tid & 63;

  // load all 16 points' features (mapped rows)
  for (int l = tid; l < 16 * C; l += 256) {
    int pt = l >> 7, t = l & 127;
    int g = base + pt;
    int b = g / NPB, loc = g % NPB;
    f_lds[pt][t] = feat[(b * NALL + row_off + loc) * C + t];
  }

  float s[8];
  #pragma unroll
  for (int pp = 0; pp < 8; ++pp) s[pp] = 0.f;

  for (int kk = 0; kk < 2; ++kk) {
    __syncthreads();
    for (int l = tid * 4; l < 64 * C; l += 1024)
      *(float4*)&w1c[l] = *(const float4*)&W1[kk * 64 * C + l];
    __syncthreads();
    #pragma unroll
    for (int pp = 0; pp < 8; ++pp) {
      const float* f = &f_lds[pp * 2 + p][kk * 64];
      float acc = s[pp];
      #pragma unroll 4
      for (int t = 0; t < 64; ++t) acc = fmaf(f[t], w1c[t * C + cc], acc);
      s[pp] = acc;
    }
  }

  float b1v = b1[cc];
  float w20 = W2[cc * 3 + 0], w21 = W2[cc * 3 + 1], w22 = W2[cc * 3 + 2];
  float b20 = b2[0], b21 = b2[1], b22 = b2[2];

  #pragma unroll 1
  for (int pp = 0; pp < 8; ++pp) {
    float h = fmaxf(s[pp] + b1v, 0.0f);
    float p0 = h * w20, p1 = h * w21, p2 = h * w22;
    for (int o = 32; o > 0; o >>= 1) {
      p0 += __shfl_down(p0, o);
      p1 += __shfl_down(p1, o);
      p2 += __shfl_down(p2, o);
    }
    if (lane == 0) { wred[wave][0] = p0; wred[wave][1] = p1; wred[wave][2] = p2; }
    __syncthreads();
    if (tid < 2) {
      int g = base + pp * 2 + tid;
      int b = g / NPB, loc = g % NPB;
      int row = (b * NALL + row_off + loc) * 3;
      float o0 = wred[tid * 2][0] + wred[tid * 2 + 1][0] + b20;
      float o1 = wred[tid * 2][1] + wred[tid * 2 + 1][1] + b21;
      float o2 = wred[tid * 2][2] + wred[tid * 2 + 1][2] + b22;
      xyz_out[row + 0] = xyz_in[row + 0] + o0;
      xyz_out[row + 1] = xyz_in[row + 1] + o1;
      xyz_out[row + 2] = xyz_in[row + 2] + o2;
    }
    __syncthreads();
  }
}

// ---------------------------------------------------------------------------
extern "C" void kernel_launch(void* const* d_in, const int* in_sizes, int n_in,
                              void* d_out, int out_size, void* d_ws, size_t ws_size,
                              hipStream_t stream) {
  (void)in_sizes; (void)n_in; (void)out_size; (void)ws_size;
  const float* ctx_xyz   = (const float*)d_in[0];
  const float* ctx_tok   = (const float*)d_in[1];
  const float* pred_tok  = (const float*)d_in[2];
  const float* noise_ctx = (const float*)d_in[3];
  const float* noise_prd = (const float*)d_in[4];
  const float* Wp  = (const float*)d_in[5];
  const float* bp  = (const float*)d_in[6];
  const float* We1 = (const float*)d_in[7];
  const float* be1 = (const float*)d_in[8];
  const float* We2 = (const float*)d_in[9];
  const float* be2 = (const float*)d_in[10];
  const float* Wc1 = (const float*)d_in[11];
  const float* bc1 = (const float*)d_in[12];
  const float* Wc2 = (const float*)d_in[13];
  const float* bc2 = (const float*)d_in[14];
  const float* Wq1 = (const float*)d_in[15];
  const float* bq1 = (const float*)d_in[16];
  const float* Wq2 = (const float*)d_in[17];
  const float* bq2 = (const float*)d_in[18];
  const float* Wf1 = (const float*)d_in[19];
  const float* bf1 = (const float*)d_in[20];
  const float* Wf2 = (const float*)d_in[21];
  const float* bf2 = (const float*)d_in[22];
  // d_in[23] = k (always 8 in this problem configuration)
  float* out = (float*)d_out;

  // workspace layout (floats) — total ~46.8 MB
  float* ws        = (float*)d_ws;
  float* ctx_feat  = ws;                          // B*P*C       = 196608
  float* pred_feat = ctx_feat + B_ * P_ * C;      // B*M*C       = 32768
  float* anchor    = pred_feat + B_ * M_ * C;     // 16
  float* xyz_all   = anchor + 16;                 // B*NALL*3    = 64512
  float* feat_in   = xyz_all + B_ * NALL * 3;     // B*NALL*C    = 2752512
  float* feat_out  = feat_in + B_ * NALL * C;     // B*NALL*C    = 2752512
  float* AB        = feat_out + B_ * NALL * C;    // B*NALL*256  = 5505024
  float* Wcat      = AB + B_ * NALL * 256;        // 131*256     = 33536
  int*   idx1      = (int*)(Wcat + 131 * 256);    // B*NCTX*8    = 147456
  int*   idx2      = idx1 + B_ * NCTX * KNN;      // B*NPRD*8    = 24576
  int*   idx3      = idx2 + B_ * NPRD * KNN;      // B*NALL*8    = 172032

  // prep + projections + geometry
  wcat_kernel<<<131, 256, 0, stream>>>(We1, Wcat);
  proj_kernel<<<(B_ * P_) / 4, 128, 0, stream>>>(ctx_tok, Wp, bp, ctx_feat);
  proj_kernel<<<(B_ * M_) / 4, 128, 0, stream>>>(pred_tok, Wp, bp, pred_feat);
  anchor_kernel<<<dim3(B_, 3), 64, 0, stream>>>(ctx_xyz, anchor);
  build_ctx_kernel<<<(B_ * NCTX) / 256, 256, 0, stream>>>(ctx_xyz, noise_ctx, xyz_all);
  build_pred_kernel<<<(B_ * NPRD + 255) / 256, 256, 0, stream>>>(anchor, noise_prd, xyz_all);

  // ---- stage 1: context branch (4 graphs of 4608 points) ----
  knn_wave_kernel<<<dim3(B_, NCTX / 4), 256, 0, stream>>>(xyz_all, NCTX, 0, idx1);
  precompute_kernel<<<(B_ * NCTX) / 8, 256, 0, stream>>>(ctx_feat, RC, xyz_all, NCTX, 0, Wcat, be1, AB);
  conv_kernel<<<(B_ * NCTX) / 4, 256, 0, stream>>>(AB, idx1, We2, be2, feat_in, NCTX, 0);
  offset_kernel<<<(B_ * NCTX) / 16, 256, 0, stream>>>(feat_in, Wc1, bc1, Wc2, bc2,
                                                      xyz_all, xyz_all, NCTX, 0);

  // ---- stage 2: prediction branch (256 graphs of 12 points) ----
  knn_small_kernel<<<(B_ * M_ * RP + 255) / 256, 256, 0, stream>>>(xyz_all, idx2);
  precompute_kernel<<<(B_ * NPRD) / 8, 256, 0, stream>>>(pred_feat, RP, xyz_all, NPRD, NCTX, Wcat, be1, AB);
  conv_kernel<<<(B_ * NPRD) / 4, 256, 0, stream>>>(AB, idx2, We2, be2, feat_in, NPRD, NCTX);
  offset_kernel<<<(B_ * NPRD) / 16, 256, 0, stream>>>(feat_in, Wq1, bq1, Wq2, bq2,
                                                      xyz_all, xyz_all, NPRD, NCTX);

  // ---- stage 3: global refinement (4 graphs of 5376 points) ----
  knn_wave_kernel<<<dim3(B_, NALL / 4), 256, 0, stream>>>(xyz_all, NALL, 0, idx3);
  precompute_kernel<<<(B_ * NALL) / 8, 256, 0, stream>>>(feat_in, 1, xyz_all, NALL, 0, Wcat, be1, AB);
  conv_kernel<<<(B_ * NALL) / 4, 256, 0, stream>>>(AB, idx3, We2, be2, feat_out, NALL, 0);
  offset_kernel<<<(B_ * NALL) / 16, 256, 0, stream>>>(feat_out, Wf1, bf1, Wf2, bf2,
                                                      xyz_all, out, NALL, 0);
}

// Round 3
// 838.235 us; speedup vs baseline: 2.0931x; 1.1990x over previous
//
#include <hip/hip_runtime.h>
#include <math.h>

// Problem constants (from setup_inputs; k==8 is fixed by the harness inputs).
constexpr int B_   = 4;
constexpr int P_   = 384;
constexpr int M_   = 64;
constexpr int TOK  = 1024;
constexpr int C    = 128;
constexpr int RC   = 12;
constexpr int RP   = 12;
constexpr int KNN  = 8;
constexpr int NCTX = P_ * RC;      // 4608 ctx points per batch
constexpr int NPRD = M_ * RP;      // 768 pred points per batch
constexpr int NALL = NCTX + NPRD;  // 5376

typedef __attribute__((ext_vector_type(8))) short bf16x8;
typedef __attribute__((ext_vector_type(4))) float f32x4;

__device__ inline unsigned short f32_to_bf16_rne(float x) {
  union { float f; unsigned int u; } v; v.f = x;
  unsigned int r = v.u + 0x7fffu + ((v.u >> 16) & 1u);
  return (unsigned short)(r >> 16);
}
__device__ inline float bf16_to_f32(unsigned short h) {
  union { float f; unsigned int u; } v; v.u = ((unsigned int)h) << 16;
  return v.f;
}

// ---------------------------------------------------------------------------
// Wcat[t][0:128]  = We1[t] - We1[131+t]   (A part: xi @ (W1a - W1b))
// Wcat[t][128:256]= We1[131+t]            (B part: xj @ W1b)
__global__ __launch_bounds__(256) void wcat_kernel(const float* __restrict__ We1,
                                                   float* __restrict__ Wcat) {
  int n = blockIdx.x * 256 + threadIdx.x;
  if (n >= 131 * 256) return;
  int t = n >> 8, cc = n & 255;
  float v;
  if (cc < C) v = We1[t * C + cc] - We1[(131 + t) * C + cc];
  else        v = We1[(131 + t) * C + (cc - C)];
  Wcat[n] = v;
}

// ---------------------------------------------------------------------------
// We2 (fp32 [k][n]) -> transposed bf16 hi/lo [n][k] for MFMA B-fragment loads.
__global__ __launch_bounds__(256) void we2t_kernel(const float* __restrict__ We2,
                                                   unsigned short* __restrict__ hi,
                                                   unsigned short* __restrict__ lo) {
  int e = blockIdx.x * 256 + threadIdx.x;
  if (e >= C * C) return;
  int n = e >> 7, k = e & 127;
  float w = We2[k * C + n];
  unsigned short h = f32_to_bf16_rne(w);
  hi[n * C + k] = h;
  lo[n * C + k] = f32_to_bf16_rne(w - bf16_to_f32(h));
}

// ---------------------------------------------------------------------------
// tokens[rows][1024] @ Wp[1024][128] + bp ; 4 rows per block, 128 threads.
__global__ __launch_bounds__(128) void proj_kernel(const float* __restrict__ tok,
                                                   const float* __restrict__ Wp,
                                                   const float* __restrict__ bp,
                                                   float* __restrict__ out) {
  __shared__ float t_lds[4][TOK];
  const int tid = threadIdx.x;
  const int r0 = blockIdx.x * 4;
  for (int l = tid; l < 4 * TOK / 4; l += 128) {
    int idx4 = l * 4;
    int rr = idx4 >> 10, tt = idx4 & 1023;
    *(float4*)&t_lds[rr][tt] = *(const float4*)&tok[(r0 + rr) * TOK + tt];
  }
  __syncthreads();
  float a0 = 0.f, a1 = 0.f, a2 = 0.f, a3 = 0.f;
  #pragma unroll 4
  for (int t = 0; t < TOK; ++t) {
    float w = Wp[t * C + tid];
    a0 = fmaf(t_lds[0][t], w, a0);
    a1 = fmaf(t_lds[1][t], w, a1);
    a2 = fmaf(t_lds[2][t], w, a2);
    a3 = fmaf(t_lds[3][t], w, a3);
  }
  float b = bp[tid];
  out[(r0 + 0) * C + tid] = a0 + b;
  out[(r0 + 1) * C + tid] = a1 + b;
  out[(r0 + 2) * C + tid] = a2 + b;
  out[(r0 + 3) * C + tid] = a3 + b;
}

// ---------------------------------------------------------------------------
__global__ __launch_bounds__(64) void anchor_kernel(const float* __restrict__ cxyz,
                                                    float* __restrict__ anchor) {
  int b = blockIdx.x, d = blockIdx.y;
  float s = 0.f;
  for (int p = threadIdx.x; p < P_; p += 64) s += cxyz[(b * P_ + p) * 3 + d];
  for (int o = 32; o > 0; o >>= 1) s += __shfl_down(s, o);
  if (threadIdx.x == 0) anchor[b * 3 + d] = s * (1.0f / (float)P_);
}

// ---------------------------------------------------------------------------
__global__ __launch_bounds__(256) void build_ctx_kernel(const float* __restrict__ cxyz,
                                                        const float* __restrict__ noise,
                                                        float* __restrict__ xyz_all) {
  int n = blockIdx.x * 256 + threadIdx.x;
  if (n >= B_ * NCTX) return;
  int b = n / NCTX, i = n % NCTX, p = i / RC;
  float x = noise[n * 3 + 0], y = noise[n * 3 + 1], z = noise[n * 3 + 2];
  float s = 0.02f / (sqrtf(x * x + y * y + z * z) + 1e-6f);
  const float* c = &cxyz[(b * P_ + p) * 3];
  float* o = &xyz_all[(b * NALL + i) * 3];
  o[0] = c[0] + x * s;
  o[1] = c[1] + y * s;
  o[2] = c[2] + z * s;
}

__global__ __launch_bounds__(256) void build_pred_kernel(const float* __restrict__ anchor,
                                                         const float* __restrict__ noise,
                                                         float* __restrict__ xyz_all) {
  int n = blockIdx.x * 256 + threadIdx.x;
  if (n >= B_ * NPRD) return;
  int b = n / NPRD, i = n % NPRD;
  float x = noise[n * 3 + 0], y = noise[n * 3 + 1], z = noise[n * 3 + 2];
  float s = 0.05f / (sqrtf(x * x + y * y + z * z) + 1e-6f);
  const float* a = &anchor[b * 3];
  float* o = &xyz_all[(b * NALL + NCTX + i) * 3];
  o[0] = a[0] + x * s;
  o[1] = a[1] + y * s;
  o[2] = a[2] + z * s;
}

// ---------------------------------------------------------------------------
// Wave-per-query kNN (k=8) for the big per-batch graphs.
__global__ __launch_bounds__(256) void knn_wave_kernel(const float* __restrict__ xyz_all,
                                                       int Npg, int row_off,
                                                       int* __restrict__ idx_out) {
  __shared__ float4 tile[256];
  const int b = blockIdx.x;
  const float* base = xyz_all + (size_t)(b * NALL + row_off) * 3;
  const int tid = threadIdx.x;
  const int wv = tid >> 6, lane = tid & 63;
  const int qi = blockIdx.y * 4 + wv;

  const float qx = base[qi * 3 + 0], qy = base[qi * 3 + 1], qz = base[qi * 3 + 2];
  const float sqi = qx * qx + qy * qy + qz * qz;

  float bd[KNN];
  int   bi[KNN];
  #pragma unroll
  for (int u = 0; u < KNN; ++u) { bd[u] = 3e38f; bi[u] = 0x7fffffff; }

  for (int ts = 0; ts < Npg; ts += 256) {
    int nj = min(256, Npg - ts);
    __syncthreads();
    if (tid < nj) {
      int j = ts + tid;
      float x = base[j * 3 + 0], y = base[j * 3 + 1], z = base[j * 3 + 2];
      tile[tid] = make_float4(x, y, z, x * x + y * y + z * z);
    }
    __syncthreads();
    #pragma unroll
    for (int u = 0; u < 4; ++u) {
      int jj = lane + 64 * u;
      if (jj < nj) {
        float4 t = tile[jj];
        float d2 = sqi + t.w - 2.0f * (qx * t.x + qy * t.y + qz * t.z);
        int j = ts + jj;
        if (j != qi && d2 < bd[KNN - 1]) {   // strict <: earlier j wins ties
          bd[KNN - 1] = d2; bi[KNN - 1] = j;
          #pragma unroll
          for (int u2 = KNN - 1; u2 > 0; --u2) {
            if (bd[u2] < bd[u2 - 1]) {
              float td = bd[u2]; bd[u2] = bd[u2 - 1]; bd[u2 - 1] = td;
              int   ti = bi[u2]; bi[u2] = bi[u2 - 1]; bi[u2 - 1] = ti;
            }
          }
        }
      }
    }
  }

  const int g = b * Npg + qi;
  #pragma unroll 1
  for (int r = 0; r < KNN; ++r) {
    float d = bd[0];
    int   i = bi[0];
    #pragma unroll
    for (int m = 1; m < 64; m <<= 1) {
      float od = __shfl_xor(d, m);
      int   oi = __shfl_xor(i, m);
      if (od < d || (od == d && oi < i)) { d = od; i = oi; }
    }
    if (lane == 0) idx_out[g * KNN + r] = b * Npg + i;
    if (bi[0] == i) {
      #pragma unroll
      for (int u = 0; u < KNN - 1; ++u) { bd[u] = bd[u + 1]; bi[u] = bi[u + 1]; }
      bd[KNN - 1] = 3e38f; bi[KNN - 1] = 0x7fffffff;
    }
  }
}

// ---------------------------------------------------------------------------
// Packed thread-per-query kNN for the 12-point prediction graphs.
__global__ __launch_bounds__(256) void knn_small_kernel(const float* __restrict__ xyz_all,
                                                        int* __restrict__ idx_out) {
  int q = blockIdx.x * 256 + threadIdx.x;
  if (q >= B_ * M_ * RP) return;
  int gr = q / RP, qi = q % RP;
  int b = gr / M_, w = gr % M_;
  const float* base = xyz_all + (size_t)(b * NALL + NCTX + w * RP) * 3;

  float cx[RP], cy[RP], cz[RP], cs[RP];
  #pragma unroll
  for (int j = 0; j < RP; ++j) {
    cx[j] = base[j * 3 + 0]; cy[j] = base[j * 3 + 1]; cz[j] = base[j * 3 + 2];
    cs[j] = cx[j] * cx[j] + cy[j] * cy[j] + cz[j] * cz[j];
  }
  float qx = cx[0], qy = cy[0], qz = cz[0], sqi = cs[0];
  #pragma unroll
  for (int j = 0; j < RP; ++j) {
    if (j == qi) { qx = cx[j]; qy = cy[j]; qz = cz[j]; sqi = cs[j]; }
  }

  float bd[KNN];
  int   bi[KNN];
  #pragma unroll
  for (int u = 0; u < KNN; ++u) { bd[u] = 3e38f; bi[u] = 0; }

  #pragma unroll
  for (int j = 0; j < RP; ++j) {
    float d2 = sqi + cs[j] - 2.0f * (qx * cx[j] + qy * cy[j] + qz * cz[j]);
    if (j != qi && d2 < bd[KNN - 1]) {
      bd[KNN - 1] = d2; bi[KNN - 1] = j;
      #pragma unroll
      for (int u = KNN - 1; u > 0; --u) {
        if (bd[u] < bd[u - 1]) {
          float td = bd[u]; bd[u] = bd[u - 1]; bd[u - 1] = td;
          int   ti = bi[u]; bi[u] = bi[u - 1]; bi[u - 1] = ti;
        }
      }
    }
  }
  #pragma unroll
  for (int u = 0; u < KNN; ++u) idx_out[q * KNN + u] = gr * RP + bi[u];
}

// ---------------------------------------------------------------------------
// AB[g][0:128] = x_g @ (W1a-W1b) + be1 ; AB[g][128:256] = x_g @ W1b
__global__ __launch_bounds__(256) void precompute_kernel(const float* __restrict__ feat,
                                                         int feat_div,
                                                         const float* __restrict__ xyz_all,
                                                         int NPB, int row_off,
                                                         const float* __restrict__ Wcat,
                                                         const float* __restrict__ be1,
                                                         float* __restrict__ AB) {
  __shared__ float x_lds[8][132];
  const int tid = threadIdx.x;
  const int base = blockIdx.x * 8;
  for (int l = tid; l < 8 * 131; l += 256) {
    int pt = l / 131, t = l % 131;
    int g = base + pt;
    float v;
    if (t < C) {
      v = feat[(g / feat_div) * C + t];
    } else {
      int b = g / NPB, loc = g % NPB;
      v = xyz_all[(b * NALL + row_off + loc) * 3 + (t - C)];
    }
    x_lds[pt][t] = v;
  }
  __syncthreads();
  float acc[8] = {0.f, 0.f, 0.f, 0.f, 0.f, 0.f, 0.f, 0.f};
  #pragma unroll 1
  for (int t = 0; t < 131; ++t) {
    float wv = Wcat[t * 256 + tid];
    #pragma unroll
    for (int p = 0; p < 8; ++p) acc[p] = fmaf(x_lds[p][t], wv, acc[p]);
  }
  float bias = (tid < C) ? be1[tid] : 0.0f;
  #pragma unroll
  for (int p = 0; p < 8; ++p) AB[(base + p) * 256 + tid] = acc[p] + bias;
}

// ---------------------------------------------------------------------------
// MFMA EdgeConv core. Per block: 8 points -> 64 rows (8 nbrs each), N=128, K=128.
// h = relu(A_i + B_j) split into bf16 hi+lo; GEMM = 3 MFMAs (Ah*Bh + Ah*Bl + Al*Bh)
// giving ~2^-16 relative error (fp32-grade, keeps downstream kNN stable).
// LDS: h hi/lo [64][128] bf16 + We2-hi [n][k] bf16, all XOR-swizzled in 16B chunks
// (chunk ^ (row&15)) so MFMA fragment reads are ~2-way (free). We2-lo fragments
// stream from global (32 KB, L1-resident). 64 KB LDS -> 2 blocks/CU.
__global__ __launch_bounds__(256) void conv_mfma_kernel(const float* __restrict__ AB,
                                                        const int* __restrict__ idx,
                                                        const unsigned short* __restrict__ w2hi_g,
                                                        const unsigned short* __restrict__ w2lo_g,
                                                        const float* __restrict__ be2,
                                                        float* __restrict__ feat_out,
                                                        int NPB, int row_off) {
  __shared__ unsigned short hhi[64 * 128];    // 16 KB
  __shared__ unsigned short hlo[64 * 128];    // 16 KB
  __shared__ unsigned short w2hi[128 * 128];  // 32 KB
  const int tid = threadIdx.x;
  const int base = blockIdx.x * 8;

  // stage We2-hi (already [n][k] bf16 in global) into LDS, swizzled 16B chunks
  #pragma unroll
  for (int i = 0; i < 8; ++i) {
    int q = tid + 256 * i;              // 0..2047
    int n = q >> 4, c = q & 15;
    f32x4 v = *(const f32x4*)(w2hi_g + n * 128 + c * 8);
    *(f32x4*)(w2hi + (n * 16 + (c ^ (n & 15))) * 8) = v;
  }

  // produce h hi/lo: 1024 (row, chunk) tasks of 8 elements
  #pragma unroll
  for (int i = 0; i < 4; ++i) {
    int task = tid + 256 * i;
    int r = task >> 4, c = task & 15;
    int p = r >> 3, nb = r & 7;
    int g = base + p;
    int j = idx[g * KNN + nb];
    const float* aP = AB + (size_t)g * 256 + c * 8;
    const float* bP = AB + (size_t)j * 256 + 128 + c * 8;
    f32x4 a0 = *(const f32x4*)aP;
    f32x4 a1 = *(const f32x4*)(aP + 4);
    f32x4 b0 = *(const f32x4*)bP;
    f32x4 b1 = *(const f32x4*)(bP + 4);
    float hv[8] = {a0.x + b0.x, a0.y + b0.y, a0.z + b0.z, a0.w + b0.w,
                   a1.x + b1.x, a1.y + b1.y, a1.z + b1.z, a1.w + b1.w};
    union { unsigned short s[8]; f32x4 v; } oh, ol;
    #pragma unroll
    for (int e = 0; e < 8; ++e) {
      float h = fmaxf(hv[e], 0.0f);
      unsigned short x = f32_to_bf16_rne(h);
      oh.s[e] = x;
      ol.s[e] = f32_to_bf16_rne(h - bf16_to_f32(x));
    }
    int dst = (r * 16 + (c ^ (r & 15))) * 8;
    *(f32x4*)(hhi + dst) = oh.v;
    *(f32x4*)(hlo + dst) = ol.v;
  }
  __syncthreads();

  const int lane = tid & 63, w = tid >> 6;
  const int m = lane & 15, quad = lane >> 4;
  f32x4 acc[8];
  #pragma unroll
  for (int nt = 0; nt < 8; ++nt) acc[nt] = (f32x4){0.f, 0.f, 0.f, 0.f};

  #pragma unroll 1
  for (int ks = 0; ks < 4; ++ks) {
    int c0 = ks * 4 + quad;
    int rowA = w * 16 + m;
    int aoff = (rowA * 16 + (c0 ^ m)) * 8;
    bf16x8 ahi = *(const bf16x8*)(hhi + aoff);
    bf16x8 alo = *(const bf16x8*)(hlo + aoff);
    #pragma unroll
    for (int nt = 0; nt < 8; ++nt) {
      int n = nt * 16 + m;
      bf16x8 bhi = *(const bf16x8*)(w2hi + (n * 16 + (c0 ^ m)) * 8);
      bf16x8 blo = *(const bf16x8*)(w2lo_g + n * 128 + c0 * 8);
      acc[nt] = __builtin_amdgcn_mfma_f32_16x16x32_bf16(ahi, bhi, acc[nt], 0, 0, 0);
      acc[nt] = __builtin_amdgcn_mfma_f32_16x16x32_bf16(ahi, blo, acc[nt], 0, 0, 0);
      acc[nt] = __builtin_amdgcn_mfma_f32_16x16x32_bf16(alo, bhi, acc[nt], 0, 0, 0);
    }
  }

  // epilogue: C row = quad*4+reg (within 16-tile); rows 0-7 -> point 2w, 8-15 -> 2w+1.
  // max over 4 regs, then across quad pairs via shfl_xor(16); quads 0 and 2 write.
  int pt = 2 * w + (quad >> 1);
  int g = base + pt;
  int b = g / NPB, loc = g % NPB;
  float* orow = feat_out + (size_t)(b * NALL + row_off + loc) * C;
  bool writer = (quad & 1) == 0;
  #pragma unroll
  for (int nt = 0; nt < 8; ++nt) {
    float v = fmaxf(fmaxf(acc[nt].x, acc[nt].y), fmaxf(acc[nt].z, acc[nt].w));
    v = fmaxf(v, __shfl_xor(v, 16));
    if (writer) {
      int col = nt * 16 + m;
      orow[col] = v + be2[col];
    }
  }
}

// ---------------------------------------------------------------------------
// offset MLP: out_row = xyz_in_row + (relu(f@W1+b1) @ W2 + b2).
__global__ __launch_bounds__(256) void offset_kernel(const float* __restrict__ feat,
                                                     const float* __restrict__ W1,
                                                     const float* __restrict__ b1,
                                                     const float* __restrict__ W2,
                                                     const float* __restrict__ b2,
                                                     const float* __restrict__ xyz_in,
                                                     float* __restrict__ xyz_out,
                                                     int NPB, int row_off) {
  __shared__ float w1c[64 * C];      // 32 KB chunk of W1
  __shared__ float f_lds[16][C];     // 8 KB
  __shared__ float wred[4][3];
  const int tid = threadIdx.x;
  const int base = blockIdx.x * 16;
  const int p = tid >> 7;
  const int cc = tid & 127;
  const int wave = tid >> 6, lane = tid & 63;

  for (int l = tid; l < 16 * C; l += 256) {
    int pt = l >> 7, t = l & 127;
    int g = base + pt;
    int b = g / NPB, loc = g % NPB;
    f_lds[pt][t] = feat[(b * NALL + row_off + loc) * C + t];
  }

  float s[8];
  #pragma unroll
  for (int pp = 0; pp < 8; ++pp) s[pp] = 0.f;

  for (int kk = 0; kk < 2; ++kk) {
    __syncthreads();
    for (int l = tid * 4; l < 64 * C; l += 1024)
      *(float4*)&w1c[l] = *(const float4*)&W1[kk * 64 * C + l];
    __syncthreads();
    #pragma unroll
    for (int pp = 0; pp < 8; ++pp) {
      const float* f = &f_lds[pp * 2 + p][kk * 64];
      float acc = s[pp];
      #pragma unroll 4
      for (int t = 0; t < 64; ++t) acc = fmaf(f[t], w1c[t * C + cc], acc);
      s[pp] = acc;
    }
  }

  float b1v = b1[cc];
  float w20 = W2[cc * 3 + 0], w21 = W2[cc * 3 + 1], w22 = W2[cc * 3 + 2];
  float b20 = b2[0], b21 = b2[1], b22 = b2[2];

  #pragma unroll 1
  for (int pp = 0; pp < 8; ++pp) {
    float h = fmaxf(s[pp] + b1v, 0.0f);
    float p0 = h * w20, p1 = h * w21, p2 = h * w22;
    for (int o = 32; o > 0; o >>= 1) {
      p0 += __shfl_down(p0, o);
      p1 += __shfl_down(p1, o);
      p2 += __shfl_down(p2, o);
    }
    if (lane == 0) { wred[wave][0] = p0; wred[wave][1] = p1; wred[wave][2] = p2; }
    __syncthreads();
    if (tid < 2) {
      int g = base + pp * 2 + tid;
      int b = g / NPB, loc = g % NPB;
      int row = (b * NALL + row_off + loc) * 3;
      float o0 = wred[tid * 2][0] + wred[tid * 2 + 1][0] + b20;
      float o1 = wred[tid * 2][1] + wred[tid * 2 + 1][1] + b21;
      float o2 = wred[tid * 2][2] + wred[tid * 2 + 1][2] + b22;
      xyz_out[row + 0] = xyz_in[row + 0] + o0;
      xyz_out[row + 1] = xyz_in[row + 1] + o1;
      xyz_out[row + 2] = xyz_in[row + 2] + o2;
    }
    __syncthreads();
  }
}

// ---------------------------------------------------------------------------
extern "C" void kernel_launch(void* const* d_in, const int* in_sizes, int n_in,
                              void* d_out, int out_size, void* d_ws, size_t ws_size,
                              hipStream_t stream) {
  (void)in_sizes; (void)n_in; (void)out_size; (void)ws_size;
  const float* ctx_xyz   = (const float*)d_in[0];
  const float* ctx_tok   = (const float*)d_in[1];
  const float* pred_tok  = (const float*)d_in[2];
  const float* noise_ctx = (const float*)d_in[3];
  const float* noise_prd = (const float*)d_in[4];
  const float* Wp  = (const float*)d_in[5];
  const float* bp  = (const float*)d_in[6];
  const float* We1 = (const float*)d_in[7];
  const float* be1 = (const float*)d_in[8];
  const float* We2 = (const float*)d_in[9];
  const float* be2 = (const float*)d_in[10];
  const float* Wc1 = (const float*)d_in[11];
  const float* bc1 = (const float*)d_in[12];
  const float* Wc2 = (const float*)d_in[13];
  const float* bc2 = (const float*)d_in[14];
  const float* Wq1 = (const float*)d_in[15];
  const float* bq1 = (const float*)d_in[16];
  const float* Wq2 = (const float*)d_in[17];
  const float* bq2 = (const float*)d_in[18];
  const float* Wf1 = (const float*)d_in[19];
  const float* bf1 = (const float*)d_in[20];
  const float* Wf2 = (const float*)d_in[21];
  const float* bf2 = (const float*)d_in[22];
  float* out = (float*)d_out;

  // workspace layout (floats) — total ~47 MB
  float* ws        = (float*)d_ws;
  float* ctx_feat  = ws;                          // B*P*C       = 196608
  float* pred_feat = ctx_feat + B_ * P_ * C;      // B*M*C       = 32768
  float* anchor    = pred_feat + B_ * M_ * C;     // 16
  float* xyz_all   = anchor + 16;                 // B*NALL*3    = 64512
  float* feat_in   = xyz_all + B_ * NALL * 3;     // B*NALL*C    = 2752512
  float* feat_out  = feat_in + B_ * NALL * C;     // B*NALL*C    = 2752512
  float* AB        = feat_out + B_ * NALL * C;    // B*NALL*256  = 5505024
  float* Wcat      = AB + B_ * NALL * 256;        // 131*256     = 33536
  int*   idx1      = (int*)(Wcat + 131 * 256);    // B*NCTX*8    = 147456
  int*   idx2      = idx1 + B_ * NCTX * KNN;      // B*NPRD*8    = 24576
  int*   idx3      = idx2 + B_ * NPRD * KNN;      // B*NALL*8    = 172032
  unsigned short* we2hi = (unsigned short*)(idx3 + B_ * NALL * KNN); // 16384
  unsigned short* we2lo = we2hi + C * C;                             // 16384

  // prep + projections + geometry
  wcat_kernel<<<131, 256, 0, stream>>>(We1, Wcat);
  we2t_kernel<<<(C * C) / 256, 256, 0, stream>>>(We2, we2hi, we2lo);
  proj_kernel<<<(B_ * P_) / 4, 128, 0, stream>>>(ctx_tok, Wp, bp, ctx_feat);
  proj_kernel<<<(B_ * M_) / 4, 128, 0, stream>>>(pred_tok, Wp, bp, pred_feat);
  anchor_kernel<<<dim3(B_, 3), 64, 0, stream>>>(ctx_xyz, anchor);
  build_ctx_kernel<<<(B_ * NCTX) / 256, 256, 0, stream>>>(ctx_xyz, noise_ctx, xyz_all);
  build_pred_kernel<<<(B_ * NPRD + 255) / 256, 256, 0, stream>>>(anchor, noise_prd, xyz_all);

  // ---- stage 1: context branch (4 graphs of 4608 points) ----
  knn_wave_kernel<<<dim3(B_, NCTX / 4), 256, 0, stream>>>(xyz_all, NCTX, 0, idx1);
  precompute_kernel<<<(B_ * NCTX) / 8, 256, 0, stream>>>(ctx_feat, RC, xyz_all, NCTX, 0, Wcat, be1, AB);
  conv_mfma_kernel<<<(B_ * NCTX) / 8, 256, 0, stream>>>(AB, idx1, we2hi, we2lo, be2, feat_in, NCTX, 0);
  offset_kernel<<<(B_ * NCTX) / 16, 256, 0, stream>>>(feat_in, Wc1, bc1, Wc2, bc2,
                                                      xyz_all, xyz_all, NCTX, 0);

  // ---- stage 2: prediction branch (256 graphs of 12 points) ----
  knn_small_kernel<<<(B_ * M_ * RP + 255) / 256, 256, 0, stream>>>(xyz_all, idx2);
  precompute_kernel<<<(B_ * NPRD) / 8, 256, 0, stream>>>(pred_feat, RP, xyz_all, NPRD, NCTX, Wcat, be1, AB);
  conv_mfma_kernel<<<(B_ * NPRD) / 8, 256, 0, stream>>>(AB, idx2, we2hi, we2lo, be2, feat_in, NPRD, NCTX);
  offset_kernel<<<(B_ * NPRD) / 16, 256, 0, stream>>>(feat_in, Wq1, bq1, Wq2, bq2,
                                                      xyz_all, xyz_all, NPRD, NCTX);

  // ---- stage 3: global refinement (4 graphs of 5376 points) ----
  knn_wave_kernel<<<dim3(B_, NALL / 4), 256, 0, stream>>>(xyz_all, NALL, 0, idx3);
  precompute_kernel<<<(B_ * NALL) / 8, 256, 0, stream>>>(feat_in, 1, xyz_all, NALL, 0, Wcat, be1, AB);
  conv_mfma_kernel<<<(B_ * NALL) / 8, 256, 0, stream>>>(AB, idx3, we2hi, we2lo, be2, feat_out, NALL, 0);
  offset_kernel<<<(B_ * NALL) / 16, 256, 0, stream>>>(feat_out, Wf1, bf1, Wf2, bf2,
                                                      xyz_all, out, NALL, 0);
}

// Round 4
// 728.903 us; speedup vs baseline: 2.4070x; 1.1500x over previous
//
#include <hip/hip_runtime.h>
#include <math.h>

// Problem constants (from setup_inputs; k==8 is fixed by the harness inputs).
constexpr int B_   = 4;
constexpr int P_   = 384;
constexpr int M_   = 64;
constexpr int TOK  = 1024;
constexpr int C    = 128;
constexpr int RC   = 12;
constexpr int RP   = 12;
constexpr int KNN  = 8;
constexpr int GS   = 12;           // group size (both ctx clusters and pred rings)
constexpr int NCTX = P_ * RC;      // 4608 ctx points per batch
constexpr int NPRD = M_ * RP;      // 768 pred points per batch
constexpr int NALL = NCTX + NPRD;  // 5376
constexpr int NG1  = NCTX / GS;    // 384 groups, stage 1
constexpr int NG3  = NALL / GS;    // 448 groups, stage 3

typedef __attribute__((ext_vector_type(8))) short bf16x8;
typedef __attribute__((ext_vector_type(4))) float f32x4;

__device__ inline unsigned short f32_to_bf16_rne(float x) {
  union { float f; unsigned int u; } v; v.f = x;
  unsigned int r = v.u + 0x7fffu + ((v.u >> 16) & 1u);
  return (unsigned short)(r >> 16);
}
__device__ inline float bf16_to_f32(unsigned short h) {
  union { float f; unsigned int u; } v; v.u = ((unsigned int)h) << 16;
  return v.f;
}

// ---------------------------------------------------------------------------
// Wcat[t][0:128]  = We1[t] - We1[131+t]   (A part: xi @ (W1a - W1b))
// Wcat[t][128:256]= We1[131+t]            (B part: xj @ W1b)
__global__ __launch_bounds__(256) void wcat_kernel(const float* __restrict__ We1,
                                                   float* __restrict__ Wcat) {
  int n = blockIdx.x * 256 + threadIdx.x;
  if (n >= 131 * 256) return;
  int t = n >> 8, cc = n & 255;
  float v;
  if (cc < C) v = We1[t * C + cc] - We1[(131 + t) * C + cc];
  else        v = We1[(131 + t) * C + (cc - C)];
  Wcat[n] = v;
}

// ---------------------------------------------------------------------------
// We2 (fp32 [k][n]) -> transposed bf16 hi/lo [n][k] for MFMA B-fragment loads.
__global__ __launch_bounds__(256) void we2t_kernel(const float* __restrict__ We2,
                                                   unsigned short* __restrict__ hi,
                                                   unsigned short* __restrict__ lo) {
  int e = blockIdx.x * 256 + threadIdx.x;
  if (e >= C * C) return;
  int n = e >> 7, k = e & 127;
  float w = We2[k * C + n];
  unsigned short h = f32_to_bf16_rne(w);
  hi[n * C + k] = h;
  lo[n * C + k] = f32_to_bf16_rne(w - bf16_to_f32(h));
}

// ---------------------------------------------------------------------------
// tokens[rows][1024] @ Wp[1024][128] + bp ; 4 rows per block, 128 threads.
__global__ __launch_bounds__(128) void proj_kernel(const float* __restrict__ tok,
                                                   const float* __restrict__ Wp,
                                                   const float* __restrict__ bp,
                                                   float* __restrict__ out) {
  __shared__ float t_lds[4][TOK];
  const int tid = threadIdx.x;
  const int r0 = blockIdx.x * 4;
  for (int l = tid; l < 4 * TOK / 4; l += 128) {
    int idx4 = l * 4;
    int rr = idx4 >> 10, tt = idx4 & 1023;
    *(float4*)&t_lds[rr][tt] = *(const float4*)&tok[(r0 + rr) * TOK + tt];
  }
  __syncthreads();
  float a0 = 0.f, a1 = 0.f, a2 = 0.f, a3 = 0.f;
  #pragma unroll 4
  for (int t = 0; t < TOK; ++t) {
    float w = Wp[t * C + tid];
    a0 = fmaf(t_lds[0][t], w, a0);
    a1 = fmaf(t_lds[1][t], w, a1);
    a2 = fmaf(t_lds[2][t], w, a2);
    a3 = fmaf(t_lds[3][t], w, a3);
  }
  float b = bp[tid];
  out[(r0 + 0) * C + tid] = a0 + b;
  out[(r0 + 1) * C + tid] = a1 + b;
  out[(r0 + 2) * C + tid] = a2 + b;
  out[(r0 + 3) * C + tid] = a3 + b;
}

// ---------------------------------------------------------------------------
__global__ __launch_bounds__(64) void anchor_kernel(const float* __restrict__ cxyz,
                                                    float* __restrict__ anchor) {
  int b = blockIdx.x, d = blockIdx.y;
  float s = 0.f;
  for (int p = threadIdx.x; p < P_; p += 64) s += cxyz[(b * P_ + p) * 3 + d];
  for (int o = 32; o > 0; o >>= 1) s += __shfl_down(s, o);
  if (threadIdx.x == 0) anchor[b * 3 + d] = s * (1.0f / (float)P_);
}

// ---------------------------------------------------------------------------
__global__ __launch_bounds__(256) void build_ctx_kernel(const float* __restrict__ cxyz,
                                                        const float* __restrict__ noise,
                                                        float* __restrict__ xyz_all) {
  int n = blockIdx.x * 256 + threadIdx.x;
  if (n >= B_ * NCTX) return;
  int b = n / NCTX, i = n % NCTX, p = i / RC;
  float x = noise[n * 3 + 0], y = noise[n * 3 + 1], z = noise[n * 3 + 2];
  float s = 0.02f / (sqrtf(x * x + y * y + z * z) + 1e-6f);
  const float* c = &cxyz[(b * P_ + p) * 3];
  float* o = &xyz_all[(b * NALL + i) * 3];
  o[0] = c[0] + x * s;
  o[1] = c[1] + y * s;
  o[2] = c[2] + z * s;
}

__global__ __launch_bounds__(256) void build_pred_kernel(const float* __restrict__ anchor,
                                                         const float* __restrict__ noise,
                                                         float* __restrict__ xyz_all) {
  int n = blockIdx.x * 256 + threadIdx.x;
  if (n >= B_ * NPRD) return;
  int b = n / NPRD, i = n % NPRD;
  float x = noise[n * 3 + 0], y = noise[n * 3 + 1], z = noise[n * 3 + 2];
  float s = 0.05f / (sqrtf(x * x + y * y + z * z) + 1e-6f);
  const float* a = &anchor[b * 3];
  float* o = &xyz_all[(b * NALL + NCTX + i) * 3];
  o[0] = a[0] + x * s;
  o[1] = a[1] + y * s;
  o[2] = a[2] + z * s;
}

// ---------------------------------------------------------------------------
// Bounding sphere per 12-point group: centroid + (inflated) max radius.
// One thread per group; grid (ceil(NG/64), B).
__global__ __launch_bounds__(64) void group_bounds_kernel(const float* __restrict__ xyz_all,
                                                          int NG,
                                                          float4* __restrict__ grp) {
  int g = blockIdx.x * 64 + threadIdx.x;
  int b = blockIdx.y;
  if (g >= NG) return;
  const float* base = xyz_all + (size_t)b * NALL * 3 + (size_t)g * GS * 3;
  float cx = 0.f, cy = 0.f, cz = 0.f;
  #pragma unroll
  for (int j = 0; j < GS; ++j) {
    cx += base[j * 3 + 0]; cy += base[j * 3 + 1]; cz += base[j * 3 + 2];
  }
  const float inv = 1.0f / (float)GS;
  cx *= inv; cy *= inv; cz *= inv;
  float r2 = 0.f;
  #pragma unroll
  for (int j = 0; j < GS; ++j) {
    float dx = base[j * 3 + 0] - cx, dy = base[j * 3 + 1] - cy, dz = base[j * 3 + 2] - cz;
    r2 = fmaxf(r2, dx * dx + dy * dy + dz * dz);
  }
  grp[b * NG + g] = make_float4(cx, cy, cz, sqrtf(r2) * 1.0002f + 1e-7f);
}

// ---------------------------------------------------------------------------
// Group-pruned exact kNN (k=8). One wave (64 threads) per group of 12 queries.
// Phase 1: each owner lane (0..11) takes full top-8 within its own group ->
//          wave threshold t = max bd[7]. True 8th-NN d2 <= t.
// Phase 2: ballot-scan all NG bounding spheres; group q can contain a
//          candidate with d2 < t only if ||c_p - c_q|| < sqrt(t)+rad_p+rad_q.
// Phase 3: scan relevant groups' points with strict-< sorted insert.
// Excluded points have d2 >= t >= final bd[7] -> could never enter (strict <).
// Grid: (NG, B). Output ids: b*Npg + local (matches AB row convention).
__global__ __launch_bounds__(64) void knn_group_kernel(const float* __restrict__ xyz_all,
                                                       const float4* __restrict__ grp,
                                                       int NG, int Npg,
                                                       int* __restrict__ idx_out) {
  const int p = blockIdx.x;
  const int b = blockIdx.y;
  const int lane = threadIdx.x;
  const float* base = xyz_all + (size_t)b * NALL * 3;
  const bool owner = lane < GS;
  const int qloc = p * GS + lane;   // valid for owner lanes

  float qx = 0.f, qy = 0.f, qz = 0.f, sqi = 0.f;
  if (owner) {
    qx = base[qloc * 3 + 0]; qy = base[qloc * 3 + 1]; qz = base[qloc * 3 + 2];
    sqi = qx * qx + qy * qy + qz * qz;
  }

  float bd[KNN];
  int   bi[KNN];
  #pragma unroll
  for (int u = 0; u < KNN; ++u) { bd[u] = 3e38f; bi[u] = 0x7fffffff; }

  // ---- phase 1: own group (11 candidates each) ----
  #pragma unroll 1
  for (int j = 0; j < GS; ++j) {
    int jloc = p * GS + j;
    float x = base[jloc * 3 + 0], y = base[jloc * 3 + 1], z = base[jloc * 3 + 2];
    float sj = x * x + y * y + z * z;
    float d2 = sqi + sj - 2.0f * (qx * x + qy * y + qz * z);
    if (owner && jloc != qloc && d2 < bd[KNN - 1]) {
      bd[KNN - 1] = d2; bi[KNN - 1] = jloc;
      #pragma unroll
      for (int u = KNN - 1; u > 0; --u) {
        if (bd[u] < bd[u - 1]) {
          float td = bd[u]; bd[u] = bd[u - 1]; bd[u - 1] = td;
          int   ti = bi[u]; bi[u] = bi[u - 1]; bi[u - 1] = ti;
        }
      }
    }
  }

  // ---- wave threshold: max over the 12 queries' current 8th-best ----
  float t = owner ? bd[KNN - 1] : 0.f;
  #pragma unroll
  for (int m = 1; m < 64; m <<= 1) t = fmaxf(t, __shfl_xor(t, m));
  float r = sqrtf(fmaxf(t, 0.f)) * 1.0002f + 1e-7f;

  const float4 gp = grp[b * NG + p];
  const float rlim = r + gp.w;

  // ---- phase 2+3: ballot-scan spheres, process relevant groups ----
  #pragma unroll 1
  for (int gs = 0; gs < NG; gs += 64) {
    int g = gs + lane;
    bool ok = false;
    if (g < NG && g != p) {
      float4 gq = grp[b * NG + g];
      float dx = gq.x - gp.x, dy = gq.y - gp.y, dz = gq.z - gp.z;
      float lim = rlim + gq.w;
      ok = (dx * dx + dy * dy + dz * dz) < lim * lim * 1.0002f;
    }
    unsigned long long mask = __ballot(ok);
    while (mask) {
      int bit = __builtin_ctzll(mask);
      mask &= mask - 1;
      int gg = gs + bit;
      #pragma unroll 1
      for (int j = 0; j < GS; ++j) {
        int jloc = gg * GS + j;
        float x = base[jloc * 3 + 0], y = base[jloc * 3 + 1], z = base[jloc * 3 + 2];
        float sj = x * x + y * y + z * z;
        float d2 = sqi + sj - 2.0f * (qx * x + qy * y + qz * z);
        if (owner && d2 < bd[KNN - 1]) {
          bd[KNN - 1] = d2; bi[KNN - 1] = jloc;
          #pragma unroll
          for (int u = KNN - 1; u > 0; --u) {
            if (bd[u] < bd[u - 1]) {
              float td = bd[u]; bd[u] = bd[u - 1]; bd[u - 1] = td;
              int   ti = bi[u]; bi[u] = bi[u - 1]; bi[u - 1] = ti;
            }
          }
        }
      }
    }
  }

  if (owner) {
    int gid = b * Npg + qloc;
    #pragma unroll
    for (int u = 0; u < KNN; ++u) idx_out[gid * KNN + u] = b * Npg + bi[u];
  }
}

// ---------------------------------------------------------------------------
// Packed thread-per-query kNN for the 12-point prediction graphs (stage 2).
__global__ __launch_bounds__(256) void knn_small_kernel(const float* __restrict__ xyz_all,
                                                        int* __restrict__ idx_out) {
  int q = blockIdx.x * 256 + threadIdx.x;
  if (q >= B_ * M_ * RP) return;
  int gr = q / RP, qi = q % RP;
  int b = gr / M_, w = gr % M_;
  const float* base = xyz_all + (size_t)(b * NALL + NCTX + w * RP) * 3;

  float cx[RP], cy[RP], cz[RP], cs[RP];
  #pragma unroll
  for (int j = 0; j < RP; ++j) {
    cx[j] = base[j * 3 + 0]; cy[j] = base[j * 3 + 1]; cz[j] = base[j * 3 + 2];
    cs[j] = cx[j] * cx[j] + cy[j] * cy[j] + cz[j] * cz[j];
  }
  float qx = cx[0], qy = cy[0], qz = cz[0], sqi = cs[0];
  #pragma unroll
  for (int j = 0; j < RP; ++j) {
    if (j == qi) { qx = cx[j]; qy = cy[j]; qz = cz[j]; sqi = cs[j]; }
  }

  float bd[KNN];
  int   bi[KNN];
  #pragma unroll
  for (int u = 0; u < KNN; ++u) { bd[u] = 3e38f; bi[u] = 0; }

  #pragma unroll
  for (int j = 0; j < RP; ++j) {
    float d2 = sqi + cs[j] - 2.0f * (qx * cx[j] + qy * cy[j] + qz * cz[j]);
    if (j != qi && d2 < bd[KNN - 1]) {
      bd[KNN - 1] = d2; bi[KNN - 1] = j;
      #pragma unroll
      for (int u = KNN - 1; u > 0; --u) {
        if (bd[u] < bd[u - 1]) {
          float td = bd[u]; bd[u] = bd[u - 1]; bd[u - 1] = td;
          int   ti = bi[u]; bi[u] = bi[u - 1]; bi[u - 1] = ti;
        }
      }
    }
  }
  #pragma unroll
  for (int u = 0; u < KNN; ++u) idx_out[q * KNN + u] = gr * RP + bi[u];
}

// ---------------------------------------------------------------------------
// AB[g][0:128] = x_g @ (W1a-W1b) + be1 ; AB[g][128:256] = x_g @ W1b
__global__ __launch_bounds__(256) void precompute_kernel(const float* __restrict__ feat,
                                                         int feat_div,
                                                         const float* __restrict__ xyz_all,
                                                         int NPB, int row_off,
                                                         const float* __restrict__ Wcat,
                                                         const float* __restrict__ be1,
                                                         float* __restrict__ AB) {
  __shared__ float x_lds[8][132];
  const int tid = threadIdx.x;
  const int base = blockIdx.x * 8;
  for (int l = tid; l < 8 * 131; l += 256) {
    int pt = l / 131, t = l % 131;
    int g = base + pt;
    float v;
    if (t < C) {
      v = feat[(g / feat_div) * C + t];
    } else {
      int b = g / NPB, loc = g % NPB;
      v = xyz_all[(b * NALL + row_off + loc) * 3 + (t - C)];
    }
    x_lds[pt][t] = v;
  }
  __syncthreads();
  float acc[8] = {0.f, 0.f, 0.f, 0.f, 0.f, 0.f, 0.f, 0.f};
  #pragma unroll 1
  for (int t = 0; t < 131; ++t) {
    float wv = Wcat[t * 256 + tid];
    #pragma unroll
    for (int p = 0; p < 8; ++p) acc[p] = fmaf(x_lds[p][t], wv, acc[p]);
  }
  float bias = (tid < C) ? be1[tid] : 0.0f;
  #pragma unroll
  for (int p = 0; p < 8; ++p) AB[(base + p) * 256 + tid] = acc[p] + bias;
}

// ---------------------------------------------------------------------------
// MFMA EdgeConv core. Per block: 8 points -> 64 rows (8 nbrs each), N=128, K=128.
// h = relu(A_i + B_j) split into bf16 hi+lo; GEMM = 3 MFMAs (Ah*Bh + Ah*Bl + Al*Bh)
// giving ~2^-16 relative error (fp32-grade, keeps downstream kNN stable).
__global__ __launch_bounds__(256) void conv_mfma_kernel(const float* __restrict__ AB,
                                                        const int* __restrict__ idx,
                                                        const unsigned short* __restrict__ w2hi_g,
                                                        const unsigned short* __restrict__ w2lo_g,
                                                        const float* __restrict__ be2,
                                                        float* __restrict__ feat_out,
                                                        int NPB, int row_off) {
  __shared__ unsigned short hhi[64 * 128];    // 16 KB
  __shared__ unsigned short hlo[64 * 128];    // 16 KB
  __shared__ unsigned short w2hi[128 * 128];  // 32 KB
  const int tid = threadIdx.x;
  const int base = blockIdx.x * 8;

  // stage We2-hi (already [n][k] bf16 in global) into LDS, swizzled 16B chunks
  #pragma unroll
  for (int i = 0; i < 8; ++i) {
    int q = tid + 256 * i;              // 0..2047
    int n = q >> 4, c = q & 15;
    f32x4 v = *(const f32x4*)(w2hi_g + n * 128 + c * 8);
    *(f32x4*)(w2hi + (n * 16 + (c ^ (n & 15))) * 8) = v;
  }

  // produce h hi/lo: 1024 (row, chunk) tasks of 8 elements
  #pragma unroll
  for (int i = 0; i < 4; ++i) {
    int task = tid + 256 * i;
    int r = task >> 4, c = task & 15;
    int p = r >> 3, nb = r & 7;
    int g = base + p;
    int j = idx[g * KNN + nb];
    const float* aP = AB + (size_t)g * 256 + c * 8;
    const float* bP = AB + (size_t)j * 256 + 128 + c * 8;
    f32x4 a0 = *(const f32x4*)aP;
    f32x4 a1 = *(const f32x4*)(aP + 4);
    f32x4 b0 = *(const f32x4*)bP;
    f32x4 b1 = *(const f32x4*)(bP + 4);
    float hv[8] = {a0.x + b0.x, a0.y + b0.y, a0.z + b0.z, a0.w + b0.w,
                   a1.x + b1.x, a1.y + b1.y, a1.z + b1.z, a1.w + b1.w};
    union { unsigned short s[8]; f32x4 v; } oh, ol;
    #pragma unroll
    for (int e = 0; e < 8; ++e) {
      float h = fmaxf(hv[e], 0.0f);
      unsigned short x = f32_to_bf16_rne(h);
      oh.s[e] = x;
      ol.s[e] = f32_to_bf16_rne(h - bf16_to_f32(x));
    }
    int dst = (r * 16 + (c ^ (r & 15))) * 8;
    *(f32x4*)(hhi + dst) = oh.v;
    *(f32x4*)(hlo + dst) = ol.v;
  }
  __syncthreads();

  const int lane = tid & 63, w = tid >> 6;
  const int m = lane & 15, quad = lane >> 4;
  f32x4 acc[8];
  #pragma unroll
  for (int nt = 0; nt < 8; ++nt) acc[nt] = (f32x4){0.f, 0.f, 0.f, 0.f};

  #pragma unroll 1
  for (int ks = 0; ks < 4; ++ks) {
    int c0 = ks * 4 + quad;
    int rowA = w * 16 + m;
    int aoff = (rowA * 16 + (c0 ^ m)) * 8;
    bf16x8 ahi = *(const bf16x8*)(hhi + aoff);
    bf16x8 alo = *(const bf16x8*)(hlo + aoff);
    #pragma unroll
    for (int nt = 0; nt < 8; ++nt) {
      int n = nt * 16 + m;
      bf16x8 bhi = *(const bf16x8*)(w2hi + (n * 16 + (c0 ^ m)) * 8);
      bf16x8 blo = *(const bf16x8*)(w2lo_g + n * 128 + c0 * 8);
      acc[nt] = __builtin_amdgcn_mfma_f32_16x16x32_bf16(ahi, bhi, acc[nt], 0, 0, 0);
      acc[nt] = __builtin_amdgcn_mfma_f32_16x16x32_bf16(ahi, blo, acc[nt], 0, 0, 0);
      acc[nt] = __builtin_amdgcn_mfma_f32_16x16x32_bf16(alo, bhi, acc[nt], 0, 0, 0);
    }
  }

  // epilogue: C row = quad*4+reg; rows 0-7 -> point 2w, 8-15 -> 2w+1.
  int pt = 2 * w + (quad >> 1);
  int g = base + pt;
  int b = g / NPB, loc = g % NPB;
  float* orow = feat_out + (size_t)(b * NALL + row_off + loc) * C;
  bool writer = (quad & 1) == 0;
  #pragma unroll
  for (int nt = 0; nt < 8; ++nt) {
    float v = fmaxf(fmaxf(acc[nt].x, acc[nt].y), fmaxf(acc[nt].z, acc[nt].w));
    v = fmaxf(v, __shfl_xor(v, 16));
    if (writer) {
      int col = nt * 16 + m;
      orow[col] = v + be2[col];
    }
  }
}

// ---------------------------------------------------------------------------
// offset MLP: out_row = xyz_in_row + (relu(f@W1+b1) @ W2 + b2).
__global__ __launch_bounds__(256) void offset_kernel(const float* __restrict__ feat,
                                                     const float* __restrict__ W1,
                                                     const float* __restrict__ b1,
                                                     const float* __restrict__ W2,
                                                     const float* __restrict__ b2,
                                                     const float* __restrict__ xyz_in,
                                                     float* __restrict__ xyz_out,
                                                     int NPB, int row_off) {
  __shared__ float w1c[64 * C];      // 32 KB chunk of W1
  __shared__ float f_lds[16][C];     // 8 KB
  __shared__ float wred[4][3];
  const int tid = threadIdx.x;
  const int base = blockIdx.x * 16;
  const int p = tid >> 7;
  const int cc = tid & 127;
  const int wave = tid >> 6, lane = tid & 63;

  for (int l = tid; l < 16 * C; l += 256) {
    int pt = l >> 7, t = l & 127;
    int g = base + pt;
    int b = g / NPB, loc = g % NPB;
    f_lds[pt][t] = feat[(b * NALL + row_off + loc) * C + t];
  }

  float s[8];
  #pragma unroll
  for (int pp = 0; pp < 8; ++pp) s[pp] = 0.f;

  for (int kk = 0; kk < 2; ++kk) {
    __syncthreads();
    for (int l = tid * 4; l < 64 * C; l += 1024)
      *(float4*)&w1c[l] = *(const float4*)&W1[kk * 64 * C + l];
    __syncthreads();
    #pragma unroll
    for (int pp = 0; pp < 8; ++pp) {
      const float* f = &f_lds[pp * 2 + p][kk * 64];
      float acc = s[pp];
      #pragma unroll 4
      for (int t = 0; t < 64; ++t) acc = fmaf(f[t], w1c[t * C + cc], acc);
      s[pp] = acc;
    }
  }

  float b1v = b1[cc];
  float w20 = W2[cc * 3 + 0], w21 = W2[cc * 3 + 1], w22 = W2[cc * 3 + 2];
  float b20 = b2[0], b21 = b2[1], b22 = b2[2];

  #pragma unroll 1
  for (int pp = 0; pp < 8; ++pp) {
    float h = fmaxf(s[pp] + b1v, 0.0f);
    float p0 = h * w20, p1 = h * w21, p2 = h * w22;
    for (int o = 32; o > 0; o >>= 1) {
      p0 += __shfl_down(p0, o);
      p1 += __shfl_down(p1, o);
      p2 += __shfl_down(p2, o);
    }
    if (lane == 0) { wred[wave][0] = p0; wred[wave][1] = p1; wred[wave][2] = p2; }
    __syncthreads();
    if (tid < 2) {
      int g = base + pp * 2 + tid;
      int b = g / NPB, loc = g % NPB;
      int row = (b * NALL + row_off + loc) * 3;
      float o0 = wred[tid * 2][0] + wred[tid * 2 + 1][0] + b20;
      float o1 = wred[tid * 2][1] + wred[tid * 2 + 1][1] + b21;
      float o2 = wred[tid * 2][2] + wred[tid * 2 + 1][2] + b22;
      xyz_out[row + 0] = xyz_in[row + 0] + o0;
      xyz_out[row + 1] = xyz_in[row + 1] + o1;
      xyz_out[row + 2] = xyz_in[row + 2] + o2;
    }
    __syncthreads();
  }
}

// ---------------------------------------------------------------------------
extern "C" void kernel_launch(void* const* d_in, const int* in_sizes, int n_in,
                              void* d_out, int out_size, void* d_ws, size_t ws_size,
                              hipStream_t stream) {
  (void)in_sizes; (void)n_in; (void)out_size; (void)ws_size;
  const float* ctx_xyz   = (const float*)d_in[0];
  const float* ctx_tok   = (const float*)d_in[1];
  const float* pred_tok  = (const float*)d_in[2];
  const float* noise_ctx = (const float*)d_in[3];
  const float* noise_prd = (const float*)d_in[4];
  const float* Wp  = (const float*)d_in[5];
  const float* bp  = (const float*)d_in[6];
  const float* We1 = (const float*)d_in[7];
  const float* be1 = (const float*)d_in[8];
  const float* We2 = (const float*)d_in[9];
  const float* be2 = (const float*)d_in[10];
  const float* Wc1 = (const float*)d_in[11];
  const float* bc1 = (const float*)d_in[12];
  const float* Wc2 = (const float*)d_in[13];
  const float* bc2 = (const float*)d_in[14];
  const float* Wq1 = (const float*)d_in[15];
  const float* bq1 = (const float*)d_in[16];
  const float* Wq2 = (const float*)d_in[17];
  const float* bq2 = (const float*)d_in[18];
  const float* Wf1 = (const float*)d_in[19];
  const float* bf1 = (const float*)d_in[20];
  const float* Wf2 = (const float*)d_in[21];
  const float* bf2 = (const float*)d_in[22];
  float* out = (float*)d_out;

  // workspace layout (floats) — total ~47 MB
  float* ws        = (float*)d_ws;
  float* ctx_feat  = ws;                          // B*P*C       = 196608
  float* pred_feat = ctx_feat + B_ * P_ * C;      // B*M*C       = 32768
  float* anchor    = pred_feat + B_ * M_ * C;     // 16
  float* xyz_all   = anchor + 16;                 // B*NALL*3    = 64512
  float* feat_in   = xyz_all + B_ * NALL * 3;     // B*NALL*C    = 2752512
  float* feat_out  = feat_in + B_ * NALL * C;     // B*NALL*C    = 2752512
  float* AB        = feat_out + B_ * NALL * C;    // B*NALL*256  = 5505024
  float* Wcat      = AB + B_ * NALL * 256;        // 131*256     = 33536
  int*   idx1      = (int*)(Wcat + 131 * 256);    // B*NCTX*8    = 147456
  int*   idx2      = idx1 + B_ * NCTX * KNN;      // B*NPRD*8    = 24576
  int*   idx3      = idx2 + B_ * NPRD * KNN;      // B*NALL*8    = 172032
  unsigned short* we2hi = (unsigned short*)(idx3 + B_ * NALL * KNN); // 16384
  unsigned short* we2lo = we2hi + C * C;                             // 16384
  float4* grp      = (float4*)(we2lo + C * C);    // B*NG3*4     = 7168 floats

  // prep + projections + geometry
  wcat_kernel<<<131, 256, 0, stream>>>(We1, Wcat);
  we2t_kernel<<<(C * C) / 256, 256, 0, stream>>>(We2, we2hi, we2lo);
  proj_kernel<<<(B_ * P_) / 4, 128, 0, stream>>>(ctx_tok, Wp, bp, ctx_feat);
  proj_kernel<<<(B_ * M_) / 4, 128, 0, stream>>>(pred_tok, Wp, bp, pred_feat);
  anchor_kernel<<<dim3(B_, 3), 64, 0, stream>>>(ctx_xyz, anchor);
  build_ctx_kernel<<<(B_ * NCTX) / 256, 256, 0, stream>>>(ctx_xyz, noise_ctx, xyz_all);
  build_pred_kernel<<<(B_ * NPRD + 255) / 256, 256, 0, stream>>>(anchor, noise_prd, xyz_all);

  // ---- stage 1: context branch (4 graphs of 4608 points, 384 groups) ----
  group_bounds_kernel<<<dim3((NG1 + 63) / 64, B_), 64, 0, stream>>>(xyz_all, NG1, grp);
  knn_group_kernel<<<dim3(NG1, B_), 64, 0, stream>>>(xyz_all, grp, NG1, NCTX, idx1);
  precompute_kernel<<<(B_ * NCTX) / 8, 256, 0, stream>>>(ctx_feat, RC, xyz_all, NCTX, 0, Wcat, be1, AB);
  conv_mfma_kernel<<<(B_ * NCTX) / 8, 256, 0, stream>>>(AB, idx1, we2hi, we2lo, be2, feat_in, NCTX, 0);
  offset_kernel<<<(B_ * NCTX) / 16, 256, 0, stream>>>(feat_in, Wc1, bc1, Wc2, bc2,
                                                      xyz_all, xyz_all, NCTX, 0);

  // ---- stage 2: prediction branch (256 graphs of 12 points) ----
  knn_small_kernel<<<(B_ * M_ * RP + 255) / 256, 256, 0, stream>>>(xyz_all, idx2);
  precompute_kernel<<<(B_ * NPRD) / 8, 256, 0, stream>>>(pred_feat, RP, xyz_all, NPRD, NCTX, Wcat, be1, AB);
  conv_mfma_kernel<<<(B_ * NPRD) / 8, 256, 0, stream>>>(AB, idx2, we2hi, we2lo, be2, feat_in, NPRD, NCTX);
  offset_kernel<<<(B_ * NPRD) / 16, 256, 0, stream>>>(feat_in, Wq1, bq1, Wq2, bq2,
                                                      xyz_all, xyz_all, NPRD, NCTX);

  // ---- stage 3: global refinement (4 graphs of 5376 points, 448 groups) ----
  group_bounds_kernel<<<dim3((NG3 + 63) / 64, B_), 64, 0, stream>>>(xyz_all, NG3, grp);
  knn_group_kernel<<<dim3(NG3, B_), 64, 0, stream>>>(xyz_all, grp, NG3, NALL, idx3);
  precompute_kernel<<<(B_ * NALL) / 8, 256, 0, stream>>>(feat_in, 1, xyz_all, NALL, 0, Wcat, be1, AB);
  conv_mfma_kernel<<<(B_ * NALL) / 8, 256, 0, stream>>>(AB, idx3, we2hi, we2lo, be2, feat_out, NALL, 0);
  offset_kernel<<<(B_ * NALL) / 16, 256, 0, stream>>>(feat_out, Wf1, bf1, Wf2, bf2,
                                                      xyz_all, out, NALL, 0);
}

// Round 5
// 663.994 us; speedup vs baseline: 2.6423x; 1.0978x over previous
//
#include <hip/hip_runtime.h>
#include <math.h>

// Problem constants (from setup_inputs; k==8 is fixed by the harness inputs).
constexpr int B_   = 4;
constexpr int P_   = 384;
constexpr int M_   = 64;
constexpr int TOK  = 1024;
constexpr int C    = 128;
constexpr int RC   = 12;
constexpr int RP   = 12;
constexpr int KNN  = 8;
constexpr int GS   = 12;           // group size (both ctx clusters and pred rings)
constexpr int NCTX = P_ * RC;      // 4608 ctx points per batch
constexpr int NPRD = M_ * RP;      // 768 pred points per batch
constexpr int NALL = NCTX + NPRD;  // 5376
constexpr int NG1  = NCTX / GS;    // 384 groups, stage 1
constexpr int NG3  = NALL / GS;    // 448 groups, stage 3
constexpr int TROWS = B_ * P_ + B_ * M_;  // 1792 token rows (ctx then pred)

typedef __attribute__((ext_vector_type(8))) short bf16x8;
typedef __attribute__((ext_vector_type(4))) float f32x4;

__device__ inline unsigned short f32_to_bf16_rne(float x) {
  union { float f; unsigned int u; } v; v.f = x;
  unsigned int r = v.u + 0x7fffu + ((v.u >> 16) & 1u);
  return (unsigned short)(r >> 16);
}
__device__ inline float bf16_to_f32(unsigned short h) {
  union { float f; unsigned int u; } v; v.u = ((unsigned int)h) << 16;
  return v.f;
}

// ---------------------------------------------------------------------------
// Wcat[t][0:128]  = We1[t] - We1[131+t]   (A part: xi @ (W1a - W1b))
// Wcat[t][128:256]= We1[131+t]            (B part: xj @ W1b)
__global__ __launch_bounds__(256) void wcat_kernel(const float* __restrict__ We1,
                                                   float* __restrict__ Wcat) {
  int n = blockIdx.x * 256 + threadIdx.x;
  if (n >= 131 * 256) return;
  int t = n >> 8, cc = n & 255;
  float v;
  if (cc < C) v = We1[t * C + cc] - We1[(131 + t) * C + cc];
  else        v = We1[(131 + t) * C + (cc - C)];
  Wcat[n] = v;
}

// ---------------------------------------------------------------------------
// WbigT[c][k] = (Wp @ Wcat_feat)[k][c] as bf16 hi/lo.  4 k-rows per block.
__global__ __launch_bounds__(256) void wbig_kernel(const float* __restrict__ Wp,
                                                   const float* __restrict__ Wcat,
                                                   unsigned short* __restrict__ wbT_hi,
                                                   unsigned short* __restrict__ wbT_lo) {
  __shared__ float wp_lds[4][128];
  const int tid = threadIdx.x;
  const int k0 = blockIdx.x * 4;
  for (int l = tid; l < 4 * 128; l += 256) {
    int r = l >> 7, f = l & 127;
    wp_lds[r][f] = Wp[(k0 + r) * C + f];
  }
  __syncthreads();
  float acc[4] = {0.f, 0.f, 0.f, 0.f};
  #pragma unroll 4
  for (int f = 0; f < 128; ++f) {
    float wv = Wcat[f * 256 + tid];
    #pragma unroll
    for (int r = 0; r < 4; ++r) acc[r] = fmaf(wp_lds[r][f], wv, acc[r]);
  }
  #pragma unroll
  for (int r = 0; r < 4; ++r) {
    unsigned short h = f32_to_bf16_rne(acc[r]);
    wbT_hi[(size_t)tid * TOK + k0 + r] = h;
    wbT_lo[(size_t)tid * TOK + k0 + r] = f32_to_bf16_rne(acc[r] - bf16_to_f32(h));
  }
}

// cb[c] = bp @ Wcat_feat[.][c] + (c<128 ? be1[c] : 0)
__global__ __launch_bounds__(256) void cb_kernel(const float* __restrict__ bp,
                                                 const float* __restrict__ Wcat,
                                                 const float* __restrict__ be1,
                                                 float* __restrict__ cb) {
  __shared__ float bp_lds[128];
  int tid = threadIdx.x;
  if (tid < 128) bp_lds[tid] = bp[tid];
  __syncthreads();
  float a = (tid < 128) ? be1[tid] : 0.f;
  #pragma unroll 4
  for (int f = 0; f < 128; ++f) a = fmaf(bp_lds[f], Wcat[f * 256 + tid], a);
  cb[tid] = a;
}

// ---------------------------------------------------------------------------
// We2 (fp32 [k][n]) -> transposed bf16 hi/lo [n][k] for MFMA B-fragment loads.
__global__ __launch_bounds__(256) void we2t_kernel(const float* __restrict__ We2,
                                                   unsigned short* __restrict__ hi,
                                                   unsigned short* __restrict__ lo) {
  int e = blockIdx.x * 256 + threadIdx.x;
  if (e >= C * C) return;
  int n = e >> 7, k = e & 127;
  float w = We2[k * C + n];
  unsigned short h = f32_to_bf16_rne(w);
  hi[n * C + k] = h;
  lo[n * C + k] = f32_to_bf16_rne(w - bf16_to_f32(h));
}

// ---------------------------------------------------------------------------
// T[row][c] = tok[row] @ Wbig + (bias added later in ab12 via cb).
// rows 0..1535 = ctx tokens, 1536..1791 = pred tokens. Split-bf16 MFMA GEMM,
// M-tile 64, N-tile 128, K=1024 in 8 chunks of 128. A hi/lo + B-hi in LDS
// (XOR-swizzled 16B chunks), B-lo streamed from global.
__global__ __launch_bounds__(256) void t12_mfma_kernel(const float* __restrict__ ctx_tok,
                                                       const float* __restrict__ pred_tok,
                                                       const unsigned short* __restrict__ wbT_hi,
                                                       const unsigned short* __restrict__ wbT_lo,
                                                       float* __restrict__ T) {
  __shared__ unsigned short ahi[64 * 128];   // 16 KB
  __shared__ unsigned short alo[64 * 128];   // 16 KB
  __shared__ unsigned short bhi[128 * 128];  // 32 KB
  const int tid = threadIdx.x;
  const int r0 = blockIdx.x * 64;
  const int n0 = blockIdx.y * 128;
  const float* src = (r0 < B_ * P_) ? (ctx_tok + (size_t)r0 * TOK)
                                    : (pred_tok + (size_t)(r0 - B_ * P_) * TOK);
  const int lane = tid & 63, w = tid >> 6;
  const int m = lane & 15, quad = lane >> 4;

  f32x4 acc[8];
  #pragma unroll
  for (int nt = 0; nt < 8; ++nt) acc[nt] = (f32x4){0.f, 0.f, 0.f, 0.f};

  #pragma unroll 1
  for (int kc = 0; kc < 8; ++kc) {
    __syncthreads();
    // stage A chunk: 64 rows x 128 k, fp32 -> bf16 hi/lo
    #pragma unroll
    for (int i = 0; i < 4; ++i) {
      int task = tid + 256 * i;           // 0..1023
      int r = task >> 4, c = task & 15;
      const float* sp = src + (size_t)r * TOK + kc * 128 + c * 8;
      f32x4 a0 = *(const f32x4*)sp;
      f32x4 a1 = *(const f32x4*)(sp + 4);
      float vals[8] = {a0.x, a0.y, a0.z, a0.w, a1.x, a1.y, a1.z, a1.w};
      union { unsigned short s[8]; f32x4 v; } oh, ol;
      #pragma unroll
      for (int e = 0; e < 8; ++e) {
        unsigned short h = f32_to_bf16_rne(vals[e]);
        oh.s[e] = h;
        ol.s[e] = f32_to_bf16_rne(vals[e] - bf16_to_f32(h));
      }
      int dst = (r * 16 + (c ^ (r & 15))) * 8;
      *(f32x4*)(ahi + dst) = oh.v;
      *(f32x4*)(alo + dst) = ol.v;
    }
    // stage B-hi chunk: 128 n x 128 k bf16
    #pragma unroll
    for (int i = 0; i < 8; ++i) {
      int task = tid + 256 * i;           // 0..2047
      int n = task >> 4, c = task & 15;
      f32x4 v = *(const f32x4*)(wbT_hi + (size_t)(n0 + n) * TOK + kc * 128 + c * 8);
      *(f32x4*)(bhi + (n * 16 + (c ^ (n & 15))) * 8) = v;
    }
    __syncthreads();
    #pragma unroll
    for (int ks = 0; ks < 4; ++ks) {
      int c0 = ks * 4 + quad;
      int aoff = ((w * 16 + m) * 16 + (c0 ^ m)) * 8;
      bf16x8 av  = *(const bf16x8*)(ahi + aoff);
      bf16x8 av2 = *(const bf16x8*)(alo + aoff);
      #pragma unroll
      for (int nt = 0; nt < 8; ++nt) {
        int n = nt * 16 + m;
        bf16x8 bh = *(const bf16x8*)(bhi + (n * 16 + (c0 ^ m)) * 8);
        bf16x8 bl = *(const bf16x8*)(wbT_lo + (size_t)(n0 + n) * TOK + kc * 128 + c0 * 8);
        acc[nt] = __builtin_amdgcn_mfma_f32_16x16x32_bf16(av, bh, acc[nt], 0, 0, 0);
        acc[nt] = __builtin_amdgcn_mfma_f32_16x16x32_bf16(av, bl, acc[nt], 0, 0, 0);
        acc[nt] = __builtin_amdgcn_mfma_f32_16x16x32_bf16(av2, bh, acc[nt], 0, 0, 0);
      }
    }
  }
  // epilogue: D row = quad*4+reg, col = lane&15 within tile
  #pragma unroll
  for (int nt = 0; nt < 8; ++nt) {
    int col = n0 + nt * 16 + m;
    #pragma unroll
    for (int reg = 0; reg < 4; ++reg) {
      int row = r0 + w * 16 + quad * 4 + reg;
      T[(size_t)row * 256 + col] = acc[nt][reg];
    }
  }
}

// ---------------------------------------------------------------------------
// Stage-1/2 AB assembly: AB[n][c] = T[trow(n)][c] + xyz(n).Wcat_xyz[c] + cb[c].
__global__ __launch_bounds__(256) void ab12_kernel(const float* __restrict__ T,
                                                   const float* __restrict__ xyz_all,
                                                   const float* __restrict__ Wcat,
                                                   const float* __restrict__ cb,
                                                   int NPB, int row_off, int trow_off,
                                                   float* __restrict__ AB) {
  const int tid = threadIdx.x;
  const int base = blockIdx.x * 8;
  const float wx = Wcat[128 * 256 + tid];
  const float wy = Wcat[129 * 256 + tid];
  const float wz = Wcat[130 * 256 + tid];
  const float cbv = cb[tid];
  #pragma unroll
  for (int p = 0; p < 8; ++p) {
    int n = base + p;
    int b = n / NPB, loc = n % NPB;
    int trow = trow_off + b * (NPB / GS) + loc / GS;
    const float* xr = xyz_all + (size_t)(b * NALL + row_off + loc) * 3;
    float x = xr[0], y = xr[1], z = xr[2];
    float v = T[(size_t)trow * 256 + tid] + cbv;
    v = fmaf(x, wx, v);
    v = fmaf(y, wy, v);
    v = fmaf(z, wz, v);
    AB[(size_t)n * 256 + tid] = v;
  }
}

// ---------------------------------------------------------------------------
__global__ __launch_bounds__(64) void anchor_kernel(const float* __restrict__ cxyz,
                                                    float* __restrict__ anchor) {
  int b = blockIdx.x, d = blockIdx.y;
  float s = 0.f;
  for (int p = threadIdx.x; p < P_; p += 64) s += cxyz[(b * P_ + p) * 3 + d];
  for (int o = 32; o > 0; o >>= 1) s += __shfl_down(s, o);
  if (threadIdx.x == 0) anchor[b * 3 + d] = s * (1.0f / (float)P_);
}

// ---------------------------------------------------------------------------
__global__ __launch_bounds__(256) void build_ctx_kernel(const float* __restrict__ cxyz,
                                                        const float* __restrict__ noise,
                                                        float* __restrict__ xyz_all) {
  int n = blockIdx.x * 256 + threadIdx.x;
  if (n >= B_ * NCTX) return;
  int b = n / NCTX, i = n % NCTX, p = i / RC;
  float x = noise[n * 3 + 0], y = noise[n * 3 + 1], z = noise[n * 3 + 2];
  float s = 0.02f / (sqrtf(x * x + y * y + z * z) + 1e-6f);
  const float* c = &cxyz[(b * P_ + p) * 3];
  float* o = &xyz_all[(b * NALL + i) * 3];
  o[0] = c[0] + x * s;
  o[1] = c[1] + y * s;
  o[2] = c[2] + z * s;
}

__global__ __launch_bounds__(256) void build_pred_kernel(const float* __restrict__ anchor,
                                                         const float* __restrict__ noise,
                                                         float* __restrict__ xyz_all) {
  int n = blockIdx.x * 256 + threadIdx.x;
  if (n >= B_ * NPRD) return;
  int b = n / NPRD, i = n % NPRD;
  float x = noise[n * 3 + 0], y = noise[n * 3 + 1], z = noise[n * 3 + 2];
  float s = 0.05f / (sqrtf(x * x + y * y + z * z) + 1e-6f);
  const float* a = &anchor[b * 3];
  float* o = &xyz_all[(b * NALL + NCTX + i) * 3];
  o[0] = a[0] + x * s;
  o[1] = a[1] + y * s;
  o[2] = a[2] + z * s;
}

// ---------------------------------------------------------------------------
// Bounding sphere per 12-point group: centroid + (inflated) max radius.
__global__ __launch_bounds__(64) void group_bounds_kernel(const float* __restrict__ xyz_all,
                                                          int NG,
                                                          float4* __restrict__ grp) {
  int g = blockIdx.x * 64 + threadIdx.x;
  int b = blockIdx.y;
  if (g >= NG) return;
  const float* base = xyz_all + (size_t)b * NALL * 3 + (size_t)g * GS * 3;
  float cx = 0.f, cy = 0.f, cz = 0.f;
  #pragma unroll
  for (int j = 0; j < GS; ++j) {
    cx += base[j * 3 + 0]; cy += base[j * 3 + 1]; cz += base[j * 3 + 2];
  }
  const float inv = 1.0f / (float)GS;
  cx *= inv; cy *= inv; cz *= inv;
  float r2 = 0.f;
  #pragma unroll
  for (int j = 0; j < GS; ++j) {
    float dx = base[j * 3 + 0] - cx, dy = base[j * 3 + 1] - cy, dz = base[j * 3 + 2] - cz;
    r2 = fmaxf(r2, dx * dx + dy * dy + dz * dz);
  }
  grp[b * NG + g] = make_float4(cx, cy, cz, sqrtf(r2) * 1.001f + 1e-6f);
}

// ---------------------------------------------------------------------------
// Group-pruned exact kNN (k=8), one wave per group of 12 queries.
// Phase 1: own-group top-8 -> wave threshold t (true 8th-NN d2 <= t).
// Phase 2: ballot-compact relevant groups into LDS glist (sphere test).
// Phase 3: cooperative scan — 64 lanes tile candidates into LDS, owner lanes
// (0..11) consume via broadcast reads with strict-< sorted insert.
// Exclusion is provably safe: excluded points have d2 >= t >= final bd[7].
__global__ __launch_bounds__(64) void knn_group_kernel(const float* __restrict__ xyz_all,
                                                       const float4* __restrict__ grp,
                                                       int NG, int Npg,
                                                       int* __restrict__ idx_out) {
  __shared__ int   glist[NG3];
  __shared__ float4 tile[64];
  __shared__ int   tilei[64];
  const int p = blockIdx.x;
  const int b = blockIdx.y;
  const int lane = threadIdx.x;
  const float* base = xyz_all + (size_t)b * NALL * 3;
  const bool owner = lane < GS;
  const int qloc = p * GS + lane;

  float qx = 0.f, qy = 0.f, qz = 0.f, sqi = 0.f;
  if (owner) {
    qx = base[qloc * 3 + 0]; qy = base[qloc * 3 + 1]; qz = base[qloc * 3 + 2];
    sqi = qx * qx + qy * qy + qz * qz;
  }

  float bd[KNN];
  int   bi[KNN];
  #pragma unroll
  for (int u = 0; u < KNN; ++u) { bd[u] = 3e38f; bi[u] = 0x7fffffff; }

  // ---- phase 1: own group ----
  #pragma unroll 1
  for (int j = 0; j < GS; ++j) {
    int jloc = p * GS + j;
    float x = base[jloc * 3 + 0], y = base[jloc * 3 + 1], z = base[jloc * 3 + 2];
    float sj = x * x + y * y + z * z;
    float d2 = sqi + sj - 2.0f * (qx * x + qy * y + qz * z);
    if (owner && jloc != qloc && d2 < bd[KNN - 1]) {
      bd[KNN - 1] = d2; bi[KNN - 1] = jloc;
      #pragma unroll
      for (int u = KNN - 1; u > 0; --u) {
        if (bd[u] < bd[u - 1]) {
          float td = bd[u]; bd[u] = bd[u - 1]; bd[u - 1] = td;
          int   ti = bi[u]; bi[u] = bi[u - 1]; bi[u - 1] = ti;
        }
      }
    }
  }

  // ---- wave threshold ----
  float t = owner ? bd[KNN - 1] : 0.f;
  #pragma unroll
  for (int mm = 1; mm < 64; mm <<= 1) t = fmaxf(t, __shfl_xor(t, mm));
  float r = sqrtf(fmaxf(t, 0.f)) * 1.001f + 1e-6f;

  const float4 gp = grp[b * NG + p];
  const float rlim = r + gp.w;

  // ---- phase 2: ballot-compact relevant groups ----
  int ng = 0;
  #pragma unroll 1
  for (int gs0 = 0; gs0 < NG; gs0 += 64) {
    int g = gs0 + lane;
    bool ok = false;
    if (g < NG && g != p) {
      float4 gq = grp[b * NG + g];
      float dx = gq.x - gp.x, dy = gq.y - gp.y, dz = gq.z - gp.z;
      float lim = rlim + gq.w;
      ok = (dx * dx + dy * dy + dz * dz) < lim * lim * 1.001f;
    }
    unsigned long long mask = __ballot(ok);
    if (ok) glist[ng + (int)__popcll(mask & ((1ull << lane) - 1ull))] = g;
    ng += (int)__popcll(mask);
  }
  __syncthreads();

  // ---- phase 3: cooperative tiled scan ----
  const int total = ng * GS;
  #pragma unroll 1
  for (int cs = 0; cs < total; cs += 64) {
    int ci = cs + lane;
    __syncthreads();
    if (ci < total) {
      int gg = glist[ci / GS];
      int j  = ci % GS;
      int jloc = gg * GS + j;
      float x = base[jloc * 3 + 0], y = base[jloc * 3 + 1], z = base[jloc * 3 + 2];
      tile[lane] = make_float4(x, y, z, x * x + y * y + z * z);
      tilei[lane] = jloc;
    }
    __syncthreads();
    int nj = min(64, total - cs);
    #pragma unroll 1
    for (int jj = 0; jj < nj; ++jj) {
      float4 tt = tile[jj];
      int ti0 = tilei[jj];
      float d2 = sqi + tt.w - 2.0f * (qx * tt.x + qy * tt.y + qz * tt.z);
      if (owner && d2 < bd[KNN - 1]) {
        bd[KNN - 1] = d2; bi[KNN - 1] = ti0;
        #pragma unroll
        for (int u = KNN - 1; u > 0; --u) {
          if (bd[u] < bd[u - 1]) {
            float td = bd[u]; bd[u] = bd[u - 1]; bd[u - 1] = td;
            int   ti = bi[u]; bi[u] = bi[u - 1]; bi[u - 1] = ti;
          }
        }
      }
    }
  }

  if (owner) {
    int gid = b * Npg + qloc;
    #pragma unroll
    for (int u = 0; u < KNN; ++u) idx_out[gid * KNN + u] = b * Npg + bi[u];
  }
}

// ---------------------------------------------------------------------------
// Packed thread-per-query kNN for the 12-point prediction graphs (stage 2).
__global__ __launch_bounds__(256) void knn_small_kernel(const float* __restrict__ xyz_all,
                                                        int* __restrict__ idx_out) {
  int q = blockIdx.x * 256 + threadIdx.x;
  if (q >= B_ * M_ * RP) return;
  int gr = q / RP, qi = q % RP;
  int b = gr / M_, w = gr % M_;
  const float* base = xyz_all + (size_t)(b * NALL + NCTX + w * RP) * 3;

  float cx[RP], cy[RP], cz[RP], cs[RP];
  #pragma unroll
  for (int j = 0; j < RP; ++j) {
    cx[j] = base[j * 3 + 0]; cy[j] = base[j * 3 + 1]; cz[j] = base[j * 3 + 2];
    cs[j] = cx[j] * cx[j] + cy[j] * cy[j] + cz[j] * cz[j];
  }
  float qx = cx[0], qy = cy[0], qz = cz[0], sqi = cs[0];
  #pragma unroll
  for (int j = 0; j < RP; ++j) {
    if (j == qi) { qx = cx[j]; qy = cy[j]; qz = cz[j]; sqi = cs[j]; }
  }

  float bd[KNN];
  int   bi[KNN];
  #pragma unroll
  for (int u = 0; u < KNN; ++u) { bd[u] = 3e38f; bi[u] = 0; }

  #pragma unroll
  for (int j = 0; j < RP; ++j) {
    float d2 = sqi + cs[j] - 2.0f * (qx * cx[j] + qy * cy[j] + qz * cz[j]);
    if (j != qi && d2 < bd[KNN - 1]) {
      bd[KNN - 1] = d2; bi[KNN - 1] = j;
      #pragma unroll
      for (int u = KNN - 1; u > 0; --u) {
        if (bd[u] < bd[u - 1]) {
          float td = bd[u]; bd[u] = bd[u - 1]; bd[u - 1] = td;
          int   ti = bi[u]; bi[u] = bi[u - 1]; bi[u - 1] = ti;
        }
      }
    }
  }
  #pragma unroll
  for (int u = 0; u < KNN; ++u) idx_out[q * KNN + u] = gr * RP + bi[u];
}

// ---------------------------------------------------------------------------
// Stage-3 precompute: AB[g][0:128] = x_g@(W1a-W1b)+be1 ; AB[g][128:256] = x_g@W1b
// x_g = [feat_in(128), xyz(3)].
__global__ __launch_bounds__(256) void precompute_kernel(const float* __restrict__ feat,
                                                         const float* __restrict__ xyz_all,
                                                         const float* __restrict__ Wcat,
                                                         const float* __restrict__ be1,
                                                         float* __restrict__ AB) {
  __shared__ float x_lds[8][132];
  const int tid = threadIdx.x;
  const int base = blockIdx.x * 8;
  for (int l = tid; l < 8 * 131; l += 256) {
    int pt = l / 131, t = l % 131;
    int g = base + pt;
    int b = g / NALL, loc = g % NALL;
    float v;
    if (t < C) v = feat[(size_t)g * C + t];
    else       v = xyz_all[(size_t)(b * NALL + loc) * 3 + (t - C)];
    x_lds[pt][t] = v;
  }
  __syncthreads();
  float acc[8] = {0.f, 0.f, 0.f, 0.f, 0.f, 0.f, 0.f, 0.f};
  #pragma unroll 1
  for (int t = 0; t < 131; ++t) {
    float wv = Wcat[t * 256 + tid];
    #pragma unroll
    for (int p = 0; p < 8; ++p) acc[p] = fmaf(x_lds[p][t], wv, acc[p]);
  }
  float bias = (tid < C) ? be1[tid] : 0.0f;
  #pragma unroll
  for (int p = 0; p < 8; ++p) AB[(size_t)(base + p) * 256 + tid] = acc[p] + bias;
}

// ---------------------------------------------------------------------------
// MFMA EdgeConv core (unchanged from round 3; split-bf16, 3 MFMAs, ~2^-16 err).
__global__ __launch_bounds__(256) void conv_mfma_kernel(const float* __restrict__ AB,
                                                        const int* __restrict__ idx,
                                                        const unsigned short* __restrict__ w2hi_g,
                                                        const unsigned short* __restrict__ w2lo_g,
                                                        const float* __restrict__ be2,
                                                        float* __restrict__ feat_out,
                                                        int NPB, int row_off) {
  __shared__ unsigned short hhi[64 * 128];    // 16 KB
  __shared__ unsigned short hlo[64 * 128];    // 16 KB
  __shared__ unsigned short w2hi[128 * 128];  // 32 KB
  const int tid = threadIdx.x;
  const int base = blockIdx.x * 8;

  #pragma unroll
  for (int i = 0; i < 8; ++i) {
    int q = tid + 256 * i;
    int n = q >> 4, c = q & 15;
    f32x4 v = *(const f32x4*)(w2hi_g + n * 128 + c * 8);
    *(f32x4*)(w2hi + (n * 16 + (c ^ (n & 15))) * 8) = v;
  }

  #pragma unroll
  for (int i = 0; i < 4; ++i) {
    int task = tid + 256 * i;
    int r = task >> 4, c = task & 15;
    int p = r >> 3, nb = r & 7;
    int g = base + p;
    int j = idx[g * KNN + nb];
    const float* aP = AB + (size_t)g * 256 + c * 8;
    const float* bP = AB + (size_t)j * 256 + 128 + c * 8;
    f32x4 a0 = *(const f32x4*)aP;
    f32x4 a1 = *(const f32x4*)(aP + 4);
    f32x4 b0 = *(const f32x4*)bP;
    f32x4 b1 = *(const f32x4*)(bP + 4);
    float hv[8] = {a0.x + b0.x, a0.y + b0.y, a0.z + b0.z, a0.w + b0.w,
                   a1.x + b1.x, a1.y + b1.y, a1.z + b1.z, a1.w + b1.w};
    union { unsigned short s[8]; f32x4 v; } oh, ol;
    #pragma unroll
    for (int e = 0; e < 8; ++e) {
      float h = fmaxf(hv[e], 0.0f);
      unsigned short x = f32_to_bf16_rne(h);
      oh.s[e] = x;
      ol.s[e] = f32_to_bf16_rne(h - bf16_to_f32(x));
    }
    int dst = (r * 16 + (c ^ (r & 15))) * 8;
    *(f32x4*)(hhi + dst) = oh.v;
    *(f32x4*)(hlo + dst) = ol.v;
  }
  __syncthreads();

  const int lane = tid & 63, w = tid >> 6;
  const int m = lane & 15, quad = lane >> 4;
  f32x4 acc[8];
  #pragma unroll
  for (int nt = 0; nt < 8; ++nt) acc[nt] = (f32x4){0.f, 0.f, 0.f, 0.f};

  #pragma unroll 1
  for (int ks = 0; ks < 4; ++ks) {
    int c0 = ks * 4 + quad;
    int rowA = w * 16 + m;
    int aoff = (rowA * 16 + (c0 ^ m)) * 8;
    bf16x8 ahi = *(const bf16x8*)(hhi + aoff);
    bf16x8 alo = *(const bf16x8*)(hlo + aoff);
    #pragma unroll
    for (int nt = 0; nt < 8; ++nt) {
      int n = nt * 16 + m;
      bf16x8 bhi = *(const bf16x8*)(w2hi + (n * 16 + (c0 ^ m)) * 8);
      bf16x8 blo = *(const bf16x8*)(w2lo_g + n * 128 + c0 * 8);
      acc[nt] = __builtin_amdgcn_mfma_f32_16x16x32_bf16(ahi, bhi, acc[nt], 0, 0, 0);
      acc[nt] = __builtin_amdgcn_mfma_f32_16x16x32_bf16(ahi, blo, acc[nt], 0, 0, 0);
      acc[nt] = __builtin_amdgcn_mfma_f32_16x16x32_bf16(alo, bhi, acc[nt], 0, 0, 0);
    }
  }

  int pt = 2 * w + (quad >> 1);
  int g = base + pt;
  int b = g / NPB, loc = g % NPB;
  float* orow = feat_out + (size_t)(b * NALL + row_off + loc) * C;
  bool writer = (quad & 1) == 0;
  #pragma unroll
  for (int nt = 0; nt < 8; ++nt) {
    float v = fmaxf(fmaxf(acc[nt].x, acc[nt].y), fmaxf(acc[nt].z, acc[nt].w));
    v = fmaxf(v, __shfl_xor(v, 16));
    if (writer) {
      int col = nt * 16 + m;
      orow[col] = v + be2[col];
    }
  }
}

// ---------------------------------------------------------------------------
// offset MLP: out_row = xyz_in_row + (relu(f@W1+b1) @ W2 + b2).
__global__ __launch_bounds__(256) void offset_kernel(const float* __restrict__ feat,
                                                     const float* __restrict__ W1,
                                                     const float* __restrict__ b1,
                                                     const float* __restrict__ W2,
                                                     const float* __restrict__ b2,
                                                     const float* __restrict__ xyz_in,
                                                     float* __restrict__ xyz_out,
                                                     int NPB, int row_off) {
  __shared__ float w1c[64 * C];
  __shared__ float f_lds[16][C];
  __shared__ float wred[4][3];
  const int tid = threadIdx.x;
  const int base = blockIdx.x * 16;
  const int p = tid >> 7;
  const int cc = tid & 127;
  const int wave = tid >> 6, lane = tid & 63;

  for (int l = tid; l < 16 * C; l += 256) {
    int pt = l >> 7, t = l & 127;
    int g = base + pt;
    int b = g / NPB, loc = g % NPB;
    f_lds[pt][t] = feat[(size_t)(b * NALL + row_off + loc) * C + t];
  }

  float s[8];
  #pragma unroll
  for (int pp = 0; pp < 8; ++pp) s[pp] = 0.f;

  for (int kk = 0; kk < 2; ++kk) {
    __syncthreads();
    for (int l = tid * 4; l < 64 * C; l += 1024)
      *(float4*)&w1c[l] = *(const float4*)&W1[kk * 64 * C + l];
    __syncthreads();
    #pragma unroll
    for (int pp = 0; pp < 8; ++pp) {
      const float* f = &f_lds[pp * 2 + p][kk * 64];
      float acc = s[pp];
      #pragma unroll 4
      for (int t = 0; t < 64; ++t) acc = fmaf(f[t], w1c[t * C + cc], acc);
      s[pp] = acc;
    }
  }

  float b1v = b1[cc];
  float w20 = W2[cc * 3 + 0], w21 = W2[cc * 3 + 1], w22 = W2[cc * 3 + 2];
  float b20 = b2[0], b21 = b2[1], b22 = b2[2];

  #pragma unroll 1
  for (int pp = 0; pp < 8; ++pp) {
    float h = fmaxf(s[pp] + b1v, 0.0f);
    float p0 = h * w20, p1 = h * w21, p2 = h * w22;
    for (int o = 32; o > 0; o >>= 1) {
      p0 += __shfl_down(p0, o);
      p1 += __shfl_down(p1, o);
      p2 += __shfl_down(p2, o);
    }
    if (lane == 0) { wred[wave][0] = p0; wred[wave][1] = p1; wred[wave][2] = p2; }
    __syncthreads();
    if (tid < 2) {
      int g = base + pp * 2 + tid;
      int b = g / NPB, loc = g % NPB;
      int row = (b * NALL + row_off + loc) * 3;
      float o0 = wred[tid * 2][0] + wred[tid * 2 + 1][0] + b20;
      float o1 = wred[tid * 2][1] + wred[tid * 2 + 1][1] + b21;
      float o2 = wred[tid * 2][2] + wred[tid * 2 + 1][2] + b22;
      xyz_out[row + 0] = xyz_in[row + 0] + o0;
      xyz_out[row + 1] = xyz_in[row + 1] + o1;
      xyz_out[row + 2] = xyz_in[row + 2] + o2;
    }
    __syncthreads();
  }
}

// ---------------------------------------------------------------------------
extern "C" void kernel_launch(void* const* d_in, const int* in_sizes, int n_in,
                              void* d_out, int out_size, void* d_ws, size_t ws_size,
                              hipStream_t stream) {
  (void)in_sizes; (void)n_in; (void)out_size; (void)ws_size;
  const float* ctx_xyz   = (const float*)d_in[0];
  const float* ctx_tok   = (const float*)d_in[1];
  const float* pred_tok  = (const float*)d_in[2];
  const float* noise_ctx = (const float*)d_in[3];
  const float* noise_prd = (const float*)d_in[4];
  const float* Wp  = (const float*)d_in[5];
  const float* bp  = (const float*)d_in[6];
  const float* We1 = (const float*)d_in[7];
  const float* be1 = (const float*)d_in[8];
  const float* We2 = (const float*)d_in[9];
  const float* be2 = (const float*)d_in[10];
  const float* Wc1 = (const float*)d_in[11];
  const float* bc1 = (const float*)d_in[12];
  const float* Wc2 = (const float*)d_in[13];
  const float* bc2 = (const float*)d_in[14];
  const float* Wq1 = (const float*)d_in[15];
  const float* bq1 = (const float*)d_in[16];
  const float* Wq2 = (const float*)d_in[17];
  const float* bq2 = (const float*)d_in[18];
  const float* Wf1 = (const float*)d_in[19];
  const float* bf1 = (const float*)d_in[20];
  const float* Wf2 = (const float*)d_in[21];
  const float* bf2 = (const float*)d_in[22];
  float* out = (float*)d_out;

  // workspace layout (floats)
  float* ws        = (float*)d_ws;
  float* T         = ws;                          // 1792*256    = 458752
  float* anchor    = T + TROWS * 256;             // 16
  float* xyz_all   = anchor + 16;                 // B*NALL*3    = 64512
  float* feat_in   = xyz_all + B_ * NALL * 3;     // B*NALL*C    = 2752512
  float* feat_out  = feat_in + B_ * NALL * C;     // B*NALL*C    = 2752512
  float* AB        = feat_out + B_ * NALL * C;    // B*NALL*256  = 5505024
  float* Wcat      = AB + B_ * NALL * 256;        // 131*256     = 33536
  float* cb        = Wcat + 131 * 256;            // 256
  int*   idx1      = (int*)(cb + 256);            // B*NCTX*8    = 147456
  int*   idx2      = idx1 + B_ * NCTX * KNN;      // B*NPRD*8    = 24576
  int*   idx3      = idx2 + B_ * NPRD * KNN;      // B*NALL*8    = 172032
  unsigned short* we2hi = (unsigned short*)(idx3 + B_ * NALL * KNN); // 16384
  unsigned short* we2lo = we2hi + C * C;                             // 16384
  float4* grp      = (float4*)(we2lo + C * C);    // B*NG3 float4 = 7168 floats
  // wbT aliases AB: fully consumed by t12_mfma before the first AB write.
  unsigned short* wbT_hi = (unsigned short*)AB;   // 256*1024 ushorts
  unsigned short* wbT_lo = wbT_hi + 256 * TOK;    // 256*1024 ushorts

  // prep
  wcat_kernel<<<131, 256, 0, stream>>>(We1, Wcat);
  wbig_kernel<<<TOK / 4, 256, 0, stream>>>(Wp, Wcat, wbT_hi, wbT_lo);
  cb_kernel<<<1, 256, 0, stream>>>(bp, Wcat, be1, cb);
  we2t_kernel<<<(C * C) / 256, 256, 0, stream>>>(We2, we2hi, we2lo);
  anchor_kernel<<<dim3(B_, 3), 64, 0, stream>>>(ctx_xyz, anchor);
  build_ctx_kernel<<<(B_ * NCTX) / 256, 256, 0, stream>>>(ctx_xyz, noise_ctx, xyz_all);
  build_pred_kernel<<<(B_ * NPRD + 255) / 256, 256, 0, stream>>>(anchor, noise_prd, xyz_all);

  // token GEMM: T = [ctx_tok; pred_tok] @ Wbig  (1792 x 256, K=1024)
  t12_mfma_kernel<<<dim3(TROWS / 64, 2), 256, 0, stream>>>(ctx_tok, pred_tok, wbT_hi, wbT_lo, T);

  // ---- stage 1: context branch ----
  group_bounds_kernel<<<dim3((NG1 + 63) / 64, B_), 64, 0, stream>>>(xyz_all, NG1, grp);
  knn_group_kernel<<<dim3(NG1, B_), 64, 0, stream>>>(xyz_all, grp, NG1, NCTX, idx1);
  ab12_kernel<<<(B_ * NCTX) / 8, 256, 0, stream>>>(T, xyz_all, Wcat, cb, NCTX, 0, 0, AB);
  conv_mfma_kernel<<<(B_ * NCTX) / 8, 256, 0, stream>>>(AB, idx1, we2hi, we2lo, be2, feat_in, NCTX, 0);
  offset_kernel<<<(B_ * NCTX) / 16, 256, 0, stream>>>(feat_in, Wc1, bc1, Wc2, bc2,
                                                      xyz_all, xyz_all, NCTX, 0);

  // ---- stage 2: prediction branch ----
  knn_small_kernel<<<(B_ * M_ * RP + 255) / 256, 256, 0, stream>>>(xyz_all, idx2);
  ab12_kernel<<<(B_ * NPRD) / 8, 256, 0, stream>>>(T, xyz_all, Wcat, cb, NPRD, NCTX, B_ * P_, AB);
  conv_mfma_kernel<<<(B_ * NPRD) / 8, 256, 0, stream>>>(AB, idx2, we2hi, we2lo, be2, feat_in, NPRD, NCTX);
  offset_kernel<<<(B_ * NPRD) / 16, 256, 0, stream>>>(feat_in, Wq1, bq1, Wq2, bq2,
                                                      xyz_all, xyz_all, NPRD, NCTX);

  // ---- stage 3: global refinement ----
  group_bounds_kernel<<<dim3((NG3 + 63) / 64, B_), 64, 0, stream>>>(xyz_all, NG3, grp);
  knn_group_kernel<<<dim3(NG3, B_), 64, 0, stream>>>(xyz_all, grp, NG3, NALL, idx3);
  precompute_kernel<<<(B_ * NALL) / 8, 256, 0, stream>>>(feat_in, xyz_all, Wcat, be1, AB);
  conv_mfma_kernel<<<(B_ * NALL) / 8, 256, 0, stream>>>(AB, idx3, we2hi, we2lo, be2, feat_out, NALL, 0);
  offset_kernel<<<(B_ * NALL) / 16, 256, 0, stream>>>(feat_out, Wf1, bf1, Wf2, bf2,
                                                      xyz_all, out, NALL, 0);
}

// Round 6
// 661.562 us; speedup vs baseline: 2.6520x; 1.0037x over previous
//
#include <hip/hip_runtime.h>
#include <math.h>

// Problem constants (from setup_inputs; k==8 is fixed by the harness inputs).
constexpr int B_   = 4;
constexpr int P_   = 384;
constexpr int M_   = 64;
constexpr int TOK  = 1024;
constexpr int C    = 128;
constexpr int RC   = 12;
constexpr int RP   = 12;
constexpr int KNN  = 8;
constexpr int GS   = 12;           // group size (both ctx clusters and pred rings)
constexpr int NCTX = P_ * RC;      // 4608 ctx points per batch
constexpr int NPRD = M_ * RP;      // 768 pred points per batch
constexpr int NALL = NCTX + NPRD;  // 5376
constexpr int NG1  = NCTX / GS;    // 384 groups, stage 1
constexpr int NG3  = NALL / GS;    // 448 groups, stage 3
constexpr int TROWS = B_ * P_ + B_ * M_;  // 1792 token rows (ctx then pred)

typedef __attribute__((ext_vector_type(8))) short bf16x8;
typedef __attribute__((ext_vector_type(4))) float f32x4;

__device__ inline unsigned short f32_to_bf16_rne(float x) {
  union { float f; unsigned int u; } v; v.f = x;
  unsigned int r = v.u + 0x7fffu + ((v.u >> 16) & 1u);
  return (unsigned short)(r >> 16);
}
__device__ inline float bf16_to_f32(unsigned short h) {
  union { float f; unsigned int u; } v; v.u = ((unsigned int)h) << 16;
  return v.f;
}

// ---------------------------------------------------------------------------
// Wcat[t][0:128]  = We1[t] - We1[131+t]   (A part: xi @ (W1a - W1b))
// Wcat[t][128:256]= We1[131+t]            (B part: xj @ W1b)
__global__ __launch_bounds__(256) void wcat_kernel(const float* __restrict__ We1,
                                                   float* __restrict__ Wcat) {
  int n = blockIdx.x * 256 + threadIdx.x;
  if (n >= 131 * 256) return;
  int t = n >> 8, cc = n & 255;
  float v;
  if (cc < C) v = We1[t * C + cc] - We1[(131 + t) * C + cc];
  else        v = We1[(131 + t) * C + (cc - C)];
  Wcat[n] = v;
}

// ---------------------------------------------------------------------------
// WbigT[c][k] = (Wp @ Wcat_feat)[k][c] as bf16 hi/lo.  4 k-rows per block.
__global__ __launch_bounds__(256) void wbig_kernel(const float* __restrict__ Wp,
                                                   const float* __restrict__ Wcat,
                                                   unsigned short* __restrict__ wbT_hi,
                                                   unsigned short* __restrict__ wbT_lo) {
  __shared__ float wp_lds[4][128];
  const int tid = threadIdx.x;
  const int k0 = blockIdx.x * 4;
  for (int l = tid; l < 4 * 128; l += 256) {
    int r = l >> 7, f = l & 127;
    wp_lds[r][f] = Wp[(k0 + r) * C + f];
  }
  __syncthreads();
  float acc[4] = {0.f, 0.f, 0.f, 0.f};
  #pragma unroll 4
  for (int f = 0; f < 128; ++f) {
    float wv = Wcat[f * 256 + tid];
    #pragma unroll
    for (int r = 0; r < 4; ++r) acc[r] = fmaf(wp_lds[r][f], wv, acc[r]);
  }
  #pragma unroll
  for (int r = 0; r < 4; ++r) {
    unsigned short h = f32_to_bf16_rne(acc[r]);
    wbT_hi[(size_t)tid * TOK + k0 + r] = h;
    wbT_lo[(size_t)tid * TOK + k0 + r] = f32_to_bf16_rne(acc[r] - bf16_to_f32(h));
  }
}

// cb[c] = bp @ Wcat_feat[.][c] + (c<128 ? be1[c] : 0)
__global__ __launch_bounds__(256) void cb_kernel(const float* __restrict__ bp,
                                                 const float* __restrict__ Wcat,
                                                 const float* __restrict__ be1,
                                                 float* __restrict__ cb) {
  __shared__ float bp_lds[128];
  int tid = threadIdx.x;
  if (tid < 128) bp_lds[tid] = bp[tid];
  __syncthreads();
  float a = (tid < 128) ? be1[tid] : 0.f;
  #pragma unroll 4
  for (int f = 0; f < 128; ++f) a = fmaf(bp_lds[f], Wcat[f * 256 + tid], a);
  cb[tid] = a;
}

// ---------------------------------------------------------------------------
// We2 (fp32 [k][n]) -> transposed bf16 hi/lo [n][k] for MFMA B-fragment loads.
__global__ __launch_bounds__(256) void we2t_kernel(const float* __restrict__ We2,
                                                   unsigned short* __restrict__ hi,
                                                   unsigned short* __restrict__ lo) {
  int e = blockIdx.x * 256 + threadIdx.x;
  if (e >= C * C) return;
  int n = e >> 7, k = e & 127;
  float w = We2[k * C + n];
  unsigned short h = f32_to_bf16_rne(w);
  hi[n * C + k] = h;
  lo[n * C + k] = f32_to_bf16_rne(w - bf16_to_f32(h));
}

// ---------------------------------------------------------------------------
// T[row][c] = tok[row] @ Wbig. Split-bf16 MFMA GEMM (see round 5).
__global__ __launch_bounds__(256) void t12_mfma_kernel(const float* __restrict__ ctx_tok,
                                                       const float* __restrict__ pred_tok,
                                                       const unsigned short* __restrict__ wbT_hi,
                                                       const unsigned short* __restrict__ wbT_lo,
                                                       float* __restrict__ T) {
  __shared__ unsigned short ahi[64 * 128];   // 16 KB
  __shared__ unsigned short alo[64 * 128];   // 16 KB
  __shared__ unsigned short bhi[128 * 128];  // 32 KB
  const int tid = threadIdx.x;
  const int r0 = blockIdx.x * 64;
  const int n0 = blockIdx.y * 128;
  const float* src = (r0 < B_ * P_) ? (ctx_tok + (size_t)r0 * TOK)
                                    : (pred_tok + (size_t)(r0 - B_ * P_) * TOK);
  const int lane = tid & 63, w = tid >> 6;
  const int m = lane & 15, quad = lane >> 4;

  f32x4 acc[8];
  #pragma unroll
  for (int nt = 0; nt < 8; ++nt) acc[nt] = (f32x4){0.f, 0.f, 0.f, 0.f};

  #pragma unroll 1
  for (int kc = 0; kc < 8; ++kc) {
    __syncthreads();
    #pragma unroll
    for (int i = 0; i < 4; ++i) {
      int task = tid + 256 * i;           // 0..1023
      int r = task >> 4, c = task & 15;
      const float* sp = src + (size_t)r * TOK + kc * 128 + c * 8;
      f32x4 a0 = *(const f32x4*)sp;
      f32x4 a1 = *(const f32x4*)(sp + 4);
      float vals[8] = {a0.x, a0.y, a0.z, a0.w, a1.x, a1.y, a1.z, a1.w};
      union { unsigned short s[8]; f32x4 v; } oh, ol;
      #pragma unroll
      for (int e = 0; e < 8; ++e) {
        unsigned short h = f32_to_bf16_rne(vals[e]);
        oh.s[e] = h;
        ol.s[e] = f32_to_bf16_rne(vals[e] - bf16_to_f32(h));
      }
      int dst = (r * 16 + (c ^ (r & 15))) * 8;
      *(f32x4*)(ahi + dst) = oh.v;
      *(f32x4*)(alo + dst) = ol.v;
    }
    #pragma unroll
    for (int i = 0; i < 8; ++i) {
      int task = tid + 256 * i;           // 0..2047
      int n = task >> 4, c = task & 15;
      f32x4 v = *(const f32x4*)(wbT_hi + (size_t)(n0 + n) * TOK + kc * 128 + c * 8);
      *(f32x4*)(bhi + (n * 16 + (c ^ (n & 15))) * 8) = v;
    }
    __syncthreads();
    #pragma unroll
    for (int ks = 0; ks < 4; ++ks) {
      int c0 = ks * 4 + quad;
      int aoff = ((w * 16 + m) * 16 + (c0 ^ m)) * 8;
      bf16x8 av  = *(const bf16x8*)(ahi + aoff);
      bf16x8 av2 = *(const bf16x8*)(alo + aoff);
      #pragma unroll
      for (int nt = 0; nt < 8; ++nt) {
        int n = nt * 16 + m;
        bf16x8 bh = *(const bf16x8*)(bhi + (n * 16 + (c0 ^ m)) * 8);
        bf16x8 bl = *(const bf16x8*)(wbT_lo + (size_t)(n0 + n) * TOK + kc * 128 + c0 * 8);
        acc[nt] = __builtin_amdgcn_mfma_f32_16x16x32_bf16(av, bh, acc[nt], 0, 0, 0);
        acc[nt] = __builtin_amdgcn_mfma_f32_16x16x32_bf16(av, bl, acc[nt], 0, 0, 0);
        acc[nt] = __builtin_amdgcn_mfma_f32_16x16x32_bf16(av2, bh, acc[nt], 0, 0, 0);
      }
    }
  }
  #pragma unroll
  for (int nt = 0; nt < 8; ++nt) {
    int col = n0 + nt * 16 + m;
    #pragma unroll
    for (int reg = 0; reg < 4; ++reg) {
      int row = r0 + w * 16 + quad * 4 + reg;
      T[(size_t)row * 256 + col] = acc[nt][reg];
    }
  }
}

// ---------------------------------------------------------------------------
// Stage-1/2 AB assembly: AB[n][c] = T[trow(n)][c] + xyz(n).Wcat_xyz[c] + cb[c].
__global__ __launch_bounds__(256) void ab12_kernel(const float* __restrict__ T,
                                                   const float* __restrict__ xyz_all,
                                                   const float* __restrict__ Wcat,
                                                   const float* __restrict__ cb,
                                                   int NPB, int row_off, int trow_off,
                                                   float* __restrict__ AB) {
  const int tid = threadIdx.x;
  const int base = blockIdx.x * 8;
  const float wx = Wcat[128 * 256 + tid];
  const float wy = Wcat[129 * 256 + tid];
  const float wz = Wcat[130 * 256 + tid];
  const float cbv = cb[tid];
  #pragma unroll
  for (int p = 0; p < 8; ++p) {
    int n = base + p;
    int b = n / NPB, loc = n % NPB;
    int trow = trow_off + b * (NPB / GS) + loc / GS;
    const float* xr = xyz_all + (size_t)(b * NALL + row_off + loc) * 3;
    float x = xr[0], y = xr[1], z = xr[2];
    float v = T[(size_t)trow * 256 + tid] + cbv;
    v = fmaf(x, wx, v);
    v = fmaf(y, wy, v);
    v = fmaf(z, wz, v);
    AB[(size_t)n * 256 + tid] = v;
  }
}

// ---------------------------------------------------------------------------
// anchor: one 256-thread block; wave w = batch b; same per-dim summation order
// as before (lane-strided partials + shfl_down reduce) -> bit-identical result.
__global__ __launch_bounds__(256) void anchor_kernel(const float* __restrict__ cxyz,
                                                     float* __restrict__ anchor) {
  const int w = threadIdx.x >> 6, lane = threadIdx.x & 63;
  float ax = 0.f, ay = 0.f, az = 0.f;
  for (int p = lane; p < P_; p += 64) {
    const float* c = &cxyz[(w * P_ + p) * 3];
    ax += c[0]; ay += c[1]; az += c[2];
  }
  for (int o = 32; o > 0; o >>= 1) {
    ax += __shfl_down(ax, o);
    ay += __shfl_down(ay, o);
    az += __shfl_down(az, o);
  }
  if (lane == 0) {
    anchor[w * 3 + 0] = ax * (1.0f / (float)P_);
    anchor[w * 3 + 1] = ay * (1.0f / (float)P_);
    anchor[w * 3 + 2] = az * (1.0f / (float)P_);
  }
}

// ---------------------------------------------------------------------------
__global__ __launch_bounds__(256) void build_ctx_kernel(const float* __restrict__ cxyz,
                                                        const float* __restrict__ noise,
                                                        float* __restrict__ xyz_all) {
  int n = blockIdx.x * 256 + threadIdx.x;
  if (n >= B_ * NCTX) return;
  int b = n / NCTX, i = n % NCTX, p = i / RC;
  float x = noise[n * 3 + 0], y = noise[n * 3 + 1], z = noise[n * 3 + 2];
  float s = 0.02f / (sqrtf(x * x + y * y + z * z) + 1e-6f);
  const float* c = &cxyz[(b * P_ + p) * 3];
  float* o = &xyz_all[(b * NALL + i) * 3];
  o[0] = c[0] + x * s;
  o[1] = c[1] + y * s;
  o[2] = c[2] + z * s;
}

__global__ __launch_bounds__(256) void build_pred_kernel(const float* __restrict__ anchor,
                                                         const float* __restrict__ noise,
                                                         float* __restrict__ xyz_all) {
  int n = blockIdx.x * 256 + threadIdx.x;
  if (n >= B_ * NPRD) return;
  int b = n / NPRD, i = n % NPRD;
  float x = noise[n * 3 + 0], y = noise[n * 3 + 1], z = noise[n * 3 + 2];
  float s = 0.05f / (sqrtf(x * x + y * y + z * z) + 1e-6f);
  const float* a = &anchor[b * 3];
  float* o = &xyz_all[(b * NALL + NCTX + i) * 3];
  o[0] = a[0] + x * s;
  o[1] = a[1] + y * s;
  o[2] = a[2] + z * s;
}

// ---------------------------------------------------------------------------
// Bounding sphere per 12-point group (256-thread blocks now).
__global__ __launch_bounds__(256) void group_bounds_kernel(const float* __restrict__ xyz_all,
                                                           int NG,
                                                           float4* __restrict__ grp) {
  int g = blockIdx.x * 256 + threadIdx.x;
  int b = blockIdx.y;
  if (g >= NG) return;
  const float* base = xyz_all + (size_t)b * NALL * 3 + (size_t)g * GS * 3;
  float cx = 0.f, cy = 0.f, cz = 0.f;
  #pragma unroll
  for (int j = 0; j < GS; ++j) {
    cx += base[j * 3 + 0]; cy += base[j * 3 + 1]; cz += base[j * 3 + 2];
  }
  const float inv = 1.0f / (float)GS;
  cx *= inv; cy *= inv; cz *= inv;
  float r2 = 0.f;
  #pragma unroll
  for (int j = 0; j < GS; ++j) {
    float dx = base[j * 3 + 0] - cx, dy = base[j * 3 + 1] - cy, dz = base[j * 3 + 2] - cz;
    r2 = fmaxf(r2, dx * dx + dy * dy + dz * dz);
  }
  grp[b * NG + g] = make_float4(cx, cy, cz, sqrtf(r2) * 1.001f + 1e-6f);
}

// ---------------------------------------------------------------------------
// Group-pruned exact kNN, reshaped: 256-thread blocks, 4 groups per block,
// one group per WAVE with wave-private LDS slices (no barriers needed).
// Algorithm and arithmetic identical to round 5 -> identical neighbor sets.
__global__ __launch_bounds__(256) void knn_group_kernel(const float* __restrict__ xyz_all,
                                                        const float4* __restrict__ grp,
                                                        int NG, int Npg,
                                                        int* __restrict__ idx_out) {
  __shared__ float4 own[4][GS];      // own-group point cache
  __shared__ int    gl[4][NG3];      // relevant-group list
  __shared__ float4 tile[4][64];     // candidate tile
  __shared__ int    tilei[4][64];
  const int b = blockIdx.y;
  const int w = threadIdx.x >> 6, lane = threadIdx.x & 63;
  const int p = blockIdx.x * 4 + w;
  if (p >= NG) return;               // whole-wave exit; no barriers in kernel
  const float* base = xyz_all + (size_t)b * NALL * 3;
  const bool owner = lane < GS;
  const int qloc = p * GS + lane;

  // stage own group's 12 points (x,y,z,|.|^2) into wave-private LDS
  if (owner) {
    float x = base[qloc * 3 + 0], y = base[qloc * 3 + 1], z = base[qloc * 3 + 2];
    own[w][lane] = make_float4(x, y, z, x * x + y * y + z * z);
  }
  float qx = 0.f, qy = 0.f, qz = 0.f, sqi = 0.f;
  if (owner) {
    float4 q = own[w][lane];
    qx = q.x; qy = q.y; qz = q.z; sqi = q.w;
  }

  float bd[KNN];
  int   bi[KNN];
  #pragma unroll
  for (int u = 0; u < KNN; ++u) { bd[u] = 3e38f; bi[u] = 0x7fffffff; }

  // ---- phase 1: own group ----
  #pragma unroll 1
  for (int j = 0; j < GS; ++j) {
    float4 cj = own[w][j];
    float d2 = sqi + cj.w - 2.0f * (qx * cj.x + qy * cj.y + qz * cj.z);
    if (owner && j != lane && d2 < bd[KNN - 1]) {
      bd[KNN - 1] = d2; bi[KNN - 1] = p * GS + j;
      #pragma unroll
      for (int u = KNN - 1; u > 0; --u) {
        if (bd[u] < bd[u - 1]) {
          float td = bd[u]; bd[u] = bd[u - 1]; bd[u - 1] = td;
          int   ti = bi[u]; bi[u] = bi[u - 1]; bi[u - 1] = ti;
        }
      }
    }
  }

  // ---- wave threshold ----
  float t = owner ? bd[KNN - 1] : 0.f;
  #pragma unroll
  for (int mm = 1; mm < 64; mm <<= 1) t = fmaxf(t, __shfl_xor(t, mm));
  float r = sqrtf(fmaxf(t, 0.f)) * 1.001f + 1e-6f;

  const float4 gp = grp[b * NG + p];
  const float rlim = r + gp.w;

  // ---- phase 2: ballot-compact relevant groups ----
  int ng = 0;
  #pragma unroll 1
  for (int gs0 = 0; gs0 < NG; gs0 += 64) {
    int g = gs0 + lane;
    bool ok = false;
    if (g < NG && g != p) {
      float4 gq = grp[b * NG + g];
      float dx = gq.x - gp.x, dy = gq.y - gp.y, dz = gq.z - gp.z;
      float lim = rlim + gq.w;
      ok = (dx * dx + dy * dy + dz * dz) < lim * lim * 1.001f;
    }
    unsigned long long mask = __ballot(ok);
    if (ok) gl[w][ng + (int)__popcll(mask & ((1ull << lane) - 1ull))] = g;
    ng += (int)__popcll(mask);
  }

  // ---- phase 3: cooperative tiled scan (wave-private tile) ----
  const int total = ng * GS;
  #pragma unroll 1
  for (int cs = 0; cs < total; cs += 64) {
    int ci = cs + lane;
    if (ci < total) {
      int gg = gl[w][ci / GS];
      int j  = ci % GS;
      int jloc = gg * GS + j;
      float x = base[jloc * 3 + 0], y = base[jloc * 3 + 1], z = base[jloc * 3 + 2];
      tile[w][lane] = make_float4(x, y, z, x * x + y * y + z * z);
      tilei[w][lane] = jloc;
    }
    int nj = min(64, total - cs);
    #pragma unroll 1
    for (int jj = 0; jj < nj; ++jj) {
      float4 tt = tile[w][jj];
      int ti0 = tilei[w][jj];
      float d2 = sqi + tt.w - 2.0f * (qx * tt.x + qy * tt.y + qz * tt.z);
      if (owner && d2 < bd[KNN - 1]) {
        bd[KNN - 1] = d2; bi[KNN - 1] = ti0;
        #pragma unroll
        for (int u = KNN - 1; u > 0; --u) {
          if (bd[u] < bd[u - 1]) {
            float td = bd[u]; bd[u] = bd[u - 1]; bd[u - 1] = td;
            int   ti = bi[u]; bi[u] = bi[u - 1]; bi[u - 1] = ti;
          }
        }
      }
    }
  }

  if (owner) {
    int gid = b * Npg + qloc;
    #pragma unroll
    for (int u = 0; u < KNN; ++u) idx_out[gid * KNN + u] = b * Npg + bi[u];
  }
}

// ---------------------------------------------------------------------------
// Packed thread-per-query kNN for the 12-point prediction graphs (stage 2).
__global__ __launch_bounds__(256) void knn_small_kernel(const float* __restrict__ xyz_all,
                                                        int* __restrict__ idx_out) {
  int q = blockIdx.x * 256 + threadIdx.x;
  if (q >= B_ * M_ * RP) return;
  int gr = q / RP, qi = q % RP;
  int b = gr / M_, w = gr % M_;
  const float* base = xyz_all + (size_t)(b * NALL + NCTX + w * RP) * 3;

  float cx[RP], cy[RP], cz[RP], cs[RP];
  #pragma unroll
  for (int j = 0; j < RP; ++j) {
    cx[j] = base[j * 3 + 0]; cy[j] = base[j * 3 + 1]; cz[j] = base[j * 3 + 2];
    cs[j] = cx[j] * cx[j] + cy[j] * cy[j] + cz[j] * cz[j];
  }
  float qx = cx[0], qy = cy[0], qz = cz[0], sqi = cs[0];
  #pragma unroll
  for (int j = 0; j < RP; ++j) {
    if (j == qi) { qx = cx[j]; qy = cy[j]; qz = cz[j]; sqi = cs[j]; }
  }

  float bd[KNN];
  int   bi[KNN];
  #pragma unroll
  for (int u = 0; u < KNN; ++u) { bd[u] = 3e38f; bi[u] = 0; }

  #pragma unroll
  for (int j = 0; j < RP; ++j) {
    float d2 = sqi + cs[j] - 2.0f * (qx * cx[j] + qy * cy[j] + qz * cz[j]);
    if (j != qi && d2 < bd[KNN - 1]) {
      bd[KNN - 1] = d2; bi[KNN - 1] = j;
      #pragma unroll
      for (int u = KNN - 1; u > 0; --u) {
        if (bd[u] < bd[u - 1]) {
          float td = bd[u]; bd[u] = bd[u - 1]; bd[u - 1] = td;
          int   ti = bi[u]; bi[u] = bi[u - 1]; bi[u - 1] = ti;
        }
      }
    }
  }
  #pragma unroll
  for (int u = 0; u < KNN; ++u) idx_out[q * KNN + u] = gr * RP + bi[u];
}

// ---------------------------------------------------------------------------
// Stage-3 precompute: AB[g][0:128] = x_g@(W1a-W1b)+be1 ; AB[g][128:256] = x_g@W1b
__global__ __launch_bounds__(256) void precompute_kernel(const float* __restrict__ feat,
                                                         const float* __restrict__ xyz_all,
                                                         const float* __restrict__ Wcat,
                                                         const float* __restrict__ be1,
                                                         float* __restrict__ AB) {
  __shared__ float x_lds[8][132];
  const int tid = threadIdx.x;
  const int base = blockIdx.x * 8;
  for (int l = tid; l < 8 * 131; l += 256) {
    int pt = l / 131, t = l % 131;
    int g = base + pt;
    int b = g / NALL, loc = g % NALL;
    float v;
    if (t < C) v = feat[(size_t)g * C + t];
    else       v = xyz_all[(size_t)(b * NALL + loc) * 3 + (t - C)];
    x_lds[pt][t] = v;
  }
  __syncthreads();
  float acc[8] = {0.f, 0.f, 0.f, 0.f, 0.f, 0.f, 0.f, 0.f};
  #pragma unroll 1
  for (int t = 0; t < 131; ++t) {
    float wv = Wcat[t * 256 + tid];
    #pragma unroll
    for (int p = 0; p < 8; ++p) acc[p] = fmaf(x_lds[p][t], wv, acc[p]);
  }
  float bias = (tid < C) ? be1[tid] : 0.0f;
  #pragma unroll
  for (int p = 0; p < 8; ++p) AB[(size_t)(base + p) * 256 + tid] = acc[p] + bias;
}

// ---------------------------------------------------------------------------
// MFMA EdgeConv core (split-bf16, 3 MFMAs, ~2^-16 err).
__global__ __launch_bounds__(256) void conv_mfma_kernel(const float* __restrict__ AB,
                                                        const int* __restrict__ idx,
                                                        const unsigned short* __restrict__ w2hi_g,
                                                        const unsigned short* __restrict__ w2lo_g,
                                                        const float* __restrict__ be2,
                                                        float* __restrict__ feat_out,
                                                        int NPB, int row_off) {
  __shared__ unsigned short hhi[64 * 128];    // 16 KB
  __shared__ unsigned short hlo[64 * 128];    // 16 KB
  __shared__ unsigned short w2hi[128 * 128];  // 32 KB
  const int tid = threadIdx.x;
  const int base = blockIdx.x * 8;

  #pragma unroll
  for (int i = 0; i < 8; ++i) {
    int q = tid + 256 * i;
    int n = q >> 4, c = q & 15;
    f32x4 v = *(const f32x4*)(w2hi_g + n * 128 + c * 8);
    *(f32x4*)(w2hi + (n * 16 + (c ^ (n & 15))) * 8) = v;
  }

  #pragma unroll
  for (int i = 0; i < 4; ++i) {
    int task = tid + 256 * i;
    int r = task >> 4, c = task & 15;
    int p = r >> 3, nb = r & 7;
    int g = base + p;
    int j = idx[g * KNN + nb];
    const float* aP = AB + (size_t)g * 256 + c * 8;
    const float* bP = AB + (size_t)j * 256 + 128 + c * 8;
    f32x4 a0 = *(const f32x4*)aP;
    f32x4 a1 = *(const f32x4*)(aP + 4);
    f32x4 b0 = *(const f32x4*)bP;
    f32x4 b1 = *(const f32x4*)(bP + 4);
    float hv[8] = {a0.x + b0.x, a0.y + b0.y, a0.z + b0.z, a0.w + b0.w,
                   a1.x + b1.x, a1.y + b1.y, a1.z + b1.z, a1.w + b1.w};
    union { unsigned short s[8]; f32x4 v; } oh, ol;
    #pragma unroll
    for (int e = 0; e < 8; ++e) {
      float h = fmaxf(hv[e], 0.0f);
      unsigned short x = f32_to_bf16_rne(h);
      oh.s[e] = x;
      ol.s[e] = f32_to_bf16_rne(h - bf16_to_f32(x));
    }
    int dst = (r * 16 + (c ^ (r & 15))) * 8;
    *(f32x4*)(hhi + dst) = oh.v;
    *(f32x4*)(hlo + dst) = ol.v;
  }
  __syncthreads();

  const int lane = tid & 63, w = tid >> 6;
  const int m = lane & 15, quad = lane >> 4;
  f32x4 acc[8];
  #pragma unroll
  for (int nt = 0; nt < 8; ++nt) acc[nt] = (f32x4){0.f, 0.f, 0.f, 0.f};

  #pragma unroll 1
  for (int ks = 0; ks < 4; ++ks) {
    int c0 = ks * 4 + quad;
    int rowA = w * 16 + m;
    int aoff = (rowA * 16 + (c0 ^ m)) * 8;
    bf16x8 ahi = *(const bf16x8*)(hhi + aoff);
    bf16x8 alo = *(const bf16x8*)(hlo + aoff);
    #pragma unroll
    for (int nt = 0; nt < 8; ++nt) {
      int n = nt * 16 + m;
      bf16x8 bhi = *(const bf16x8*)(w2hi + (n * 16 + (c0 ^ m)) * 8);
      bf16x8 blo = *(const bf16x8*)(w2lo_g + n * 128 + c0 * 8);
      acc[nt] = __builtin_amdgcn_mfma_f32_16x16x32_bf16(ahi, bhi, acc[nt], 0, 0, 0);
      acc[nt] = __builtin_amdgcn_mfma_f32_16x16x32_bf16(ahi, blo, acc[nt], 0, 0, 0);
      acc[nt] = __builtin_amdgcn_mfma_f32_16x16x32_bf16(alo, bhi, acc[nt], 0, 0, 0);
    }
  }

  int pt = 2 * w + (quad >> 1);
  int g = base + pt;
  int b = g / NPB, loc = g % NPB;
  float* orow = feat_out + (size_t)(b * NALL + row_off + loc) * C;
  bool writer = (quad & 1) == 0;
  #pragma unroll
  for (int nt = 0; nt < 8; ++nt) {
    float v = fmaxf(fmaxf(acc[nt].x, acc[nt].y), fmaxf(acc[nt].z, acc[nt].w));
    v = fmaxf(v, __shfl_xor(v, 16));
    if (writer) {
      int col = nt * 16 + m;
      orow[col] = v + be2[col];
    }
  }
}

// ---------------------------------------------------------------------------
// offset MLP: out_row = xyz_in_row + (relu(f@W1+b1) @ W2 + b2).
__global__ __launch_bounds__(256) void offset_kernel(const float* __restrict__ feat,
                                                     const float* __restrict__ W1,
                                                     const float* __restrict__ b1,
                                                     const float* __restrict__ W2,
                                                     const float* __restrict__ b2,
                                                     const float* __restrict__ xyz_in,
                                                     float* __restrict__ xyz_out,
                                                     int NPB, int row_off) {
  __shared__ float w1c[64 * C];
  __shared__ float f_lds[16][C];
  __shared__ float wred[4][3];
  const int tid = threadIdx.x;
  const int base = blockIdx.x * 16;
  const int p = tid >> 7;
  const int cc = tid & 127;
  const int wave = tid >> 6, lane = tid & 63;

  for (int l = tid; l < 16 * C; l += 256) {
    int pt = l >> 7, t = l & 127;
    int g = base + pt;
    int b = g / NPB, loc = g % NPB;
    f_lds[pt][t] = feat[(size_t)(b * NALL + row_off + loc) * C + t];
  }

  float s[8];
  #pragma unroll
  for (int pp = 0; pp < 8; ++pp) s[pp] = 0.f;

  for (int kk = 0; kk < 2; ++kk) {
    __syncthreads();
    for (int l = tid * 4; l < 64 * C; l += 1024)
      *(float4*)&w1c[l] = *(const float4*)&W1[kk * 64 * C + l];
    __syncthreads();
    #pragma unroll
    for (int pp = 0; pp < 8; ++pp) {
      const float* f = &f_lds[pp * 2 + p][kk * 64];
      float acc = s[pp];
      #pragma unroll 4
      for (int t = 0; t < 64; ++t) acc = fmaf(f[t], w1c[t * C + cc], acc);
      s[pp] = acc;
    }
  }

  float b1v = b1[cc];
  float w20 = W2[cc * 3 + 0], w21 = W2[cc * 3 + 1], w22 = W2[cc * 3 + 2];
  float b20 = b2[0], b21 = b2[1], b22 = b2[2];

  #pragma unroll 1
  for (int pp = 0; pp < 8; ++pp) {
    float h = fmaxf(s[pp] + b1v, 0.0f);
    float p0 = h * w20, p1 = h * w21, p2 = h * w22;
    for (int o = 32; o > 0; o >>= 1) {
      p0 += __shfl_down(p0, o);
      p1 += __shfl_down(p1, o);
      p2 += __shfl_down(p2, o);
    }
    if (lane == 0) { wred[wave][0] = p0; wred[wave][1] = p1; wred[wave][2] = p2; }
    __syncthreads();
    if (tid < 2) {
      int g = base + pp * 2 + tid;
      int b = g / NPB, loc = g % NPB;
      int row = (b * NALL + row_off + loc) * 3;
      float o0 = wred[tid * 2][0] + wred[tid * 2 + 1][0] + b20;
      float o1 = wred[tid * 2][1] + wred[tid * 2 + 1][1] + b21;
      float o2 = wred[tid * 2][2] + wred[tid * 2 + 1][2] + b22;
      xyz_out[row + 0] = xyz_in[row + 0] + o0;
      xyz_out[row + 1] = xyz_in[row + 1] + o1;
      xyz_out[row + 2] = xyz_in[row + 2] + o2;
    }
    __syncthreads();
  }
}

// ---------------------------------------------------------------------------
extern "C" void kernel_launch(void* const* d_in, const int* in_sizes, int n_in,
                              void* d_out, int out_size, void* d_ws, size_t ws_size,
                              hipStream_t stream) {
  (void)in_sizes; (void)n_in; (void)out_size; (void)ws_size;
  const float* ctx_xyz   = (const float*)d_in[0];
  const float* ctx_tok   = (const float*)d_in[1];
  const float* pred_tok  = (const float*)d_in[2];
  const float* noise_ctx = (const float*)d_in[3];
  const float* noise_prd = (const float*)d_in[4];
  const float* Wp  = (const float*)d_in[5];
  const float* bp  = (const float*)d_in[6];
  const float* We1 = (const float*)d_in[7];
  const float* be1 = (const float*)d_in[8];
  const float* We2 = (const float*)d_in[9];
  const float* be2 = (const float*)d_in[10];
  const float* Wc1 = (const float*)d_in[11];
  const float* bc1 = (const float*)d_in[12];
  const float* Wc2 = (const float*)d_in[13];
  const float* bc2 = (const float*)d_in[14];
  const float* Wq1 = (const float*)d_in[15];
  const float* bq1 = (const float*)d_in[16];
  const float* Wq2 = (const float*)d_in[17];
  const float* bq2 = (const float*)d_in[18];
  const float* Wf1 = (const float*)d_in[19];
  const float* bf1 = (const float*)d_in[20];
  const float* Wf2 = (const float*)d_in[21];
  const float* bf2 = (const float*)d_in[22];
  float* out = (float*)d_out;

  // workspace layout (floats)
  float* ws        = (float*)d_ws;
  float* T         = ws;                          // 1792*256    = 458752
  float* anchor    = T + TROWS * 256;             // 16
  float* xyz_all   = anchor + 16;                 // B*NALL*3    = 64512
  float* feat_in   = xyz_all + B_ * NALL * 3;     // B*NALL*C    = 2752512
  float* feat_out  = feat_in + B_ * NALL * C;     // B*NALL*C    = 2752512
  float* AB        = feat_out + B_ * NALL * C;    // B*NALL*256  = 5505024
  float* Wcat      = AB + B_ * NALL * 256;        // 131*256     = 33536
  float* cb        = Wcat + 131 * 256;            // 256
  int*   idx1      = (int*)(cb + 256);            // B*NCTX*8    = 147456
  int*   idx2      = idx1 + B_ * NCTX * KNN;      // B*NPRD*8    = 24576
  int*   idx3      = idx2 + B_ * NPRD * KNN;      // B*NALL*8    = 172032
  unsigned short* we2hi = (unsigned short*)(idx3 + B_ * NALL * KNN); // 16384
  unsigned short* we2lo = we2hi + C * C;                             // 16384
  float4* grp      = (float4*)(we2lo + C * C);    // B*NG3 float4 = 7168 floats
  // wbT aliases AB: fully consumed by t12_mfma before the first AB write.
  unsigned short* wbT_hi = (unsigned short*)AB;   // 256*1024 ushorts
  unsigned short* wbT_lo = wbT_hi + 256 * TOK;    // 256*1024 ushorts

  // prep
  wcat_kernel<<<131, 256, 0, stream>>>(We1, Wcat);
  wbig_kernel<<<TOK / 4, 256, 0, stream>>>(Wp, Wcat, wbT_hi, wbT_lo);
  cb_kernel<<<1, 256, 0, stream>>>(bp, Wcat, be1, cb);
  we2t_kernel<<<(C * C) / 256, 256, 0, stream>>>(We2, we2hi, we2lo);
  anchor_kernel<<<1, 256, 0, stream>>>(ctx_xyz, anchor);
  build_ctx_kernel<<<(B_ * NCTX) / 256, 256, 0, stream>>>(ctx_xyz, noise_ctx, xyz_all);
  build_pred_kernel<<<(B_ * NPRD + 255) / 256, 256, 0, stream>>>(anchor, noise_prd, xyz_all);

  // token GEMM: T = [ctx_tok; pred_tok] @ Wbig  (1792 x 256, K=1024)
  t12_mfma_kernel<<<dim3(TROWS / 64, 2), 256, 0, stream>>>(ctx_tok, pred_tok, wbT_hi, wbT_lo, T);

  // ---- stage 1: context branch ----
  group_bounds_kernel<<<dim3((NG1 + 255) / 256, B_), 256, 0, stream>>>(xyz_all, NG1, grp);
  knn_group_kernel<<<dim3((NG1 + 3) / 4, B_), 256, 0, stream>>>(xyz_all, grp, NG1, NCTX, idx1);
  ab12_kernel<<<(B_ * NCTX) / 8, 256, 0, stream>>>(T, xyz_all, Wcat, cb, NCTX, 0, 0, AB);
  conv_mfma_kernel<<<(B_ * NCTX) / 8, 256, 0, stream>>>(AB, idx1, we2hi, we2lo, be2, feat_in, NCTX, 0);
  offset_kernel<<<(B_ * NCTX) / 16, 256, 0, stream>>>(feat_in, Wc1, bc1, Wc2, bc2,
                                                      xyz_all, xyz_all, NCTX, 0);

  // ---- stage 2: prediction branch ----
  knn_small_kernel<<<(B_ * M_ * RP + 255) / 256, 256, 0, stream>>>(xyz_all, idx2);
  ab12_kernel<<<(B_ * NPRD) / 8, 256, 0, stream>>>(T, xyz_all, Wcat, cb, NPRD, NCTX, B_ * P_, AB);
  conv_mfma_kernel<<<(B_ * NPRD) / 8, 256, 0, stream>>>(AB, idx2, we2hi, we2lo, be2, feat_in, NPRD, NCTX);
  offset_kernel<<<(B_ * NPRD) / 16, 256, 0, stream>>>(feat_in, Wq1, bq1, Wq2, bq2,
                                                      xyz_all, xyz_all, NPRD, NCTX);

  // ---- stage 3: global refinement ----
  group_bounds_kernel<<<dim3((NG3 + 255) / 256, B_), 256, 0, stream>>>(xyz_all, NG3, grp);
  knn_group_kernel<<<dim3((NG3 + 3) / 4, B_), 256, 0, stream>>>(xyz_all, grp, NG3, NALL, idx3);
  precompute_kernel<<<(B_ * NALL) / 8, 256, 0, stream>>>(feat_in, xyz_all, Wcat, be1, AB);
  conv_mfma_kernel<<<(B_ * NALL) / 8, 256, 0, stream>>>(AB, idx3, we2hi, we2lo, be2, feat_out, NALL, 0);
  offset_kernel<<<(B_ * NALL) / 16, 256, 0, stream>>>(feat_out, Wf1, bf1, Wf2, bf2,
                                                      xyz_all, out, NALL, 0);
}

// Round 7
// 644.548 us; speedup vs baseline: 2.7220x; 1.0264x over previous
//
#include <hip/hip_runtime.h>
#include <math.h>

// Problem constants (from setup_inputs; k==8 is fixed by the harness inputs).
constexpr int B_   = 4;
constexpr int P_   = 384;
constexpr int M_   = 64;
constexpr int TOK  = 1024;
constexpr int C    = 128;
constexpr int RC   = 12;
constexpr int RP   = 12;
constexpr int KNN  = 8;
constexpr int GS   = 12;           // group size (both ctx clusters and pred rings)
constexpr int NCTX = P_ * RC;      // 4608 ctx points per batch
constexpr int NPRD = M_ * RP;      // 768 pred points per batch
constexpr int NALL = NCTX + NPRD;  // 5376
constexpr int NG1  = NCTX / GS;    // 384 groups, stage 1
constexpr int NG3  = NALL / GS;    // 448 groups, stage 3
constexpr int TROWS = B_ * P_ + B_ * M_;  // 1792 token rows (ctx then pred)

// fused-grid split points
constexpr int AB1_BLOCKS  = (B_ * NCTX) / 8;   // 2304
constexpr int KNN1_BLOCKS = B_ * (NG1 / 4);    // 384
constexpr int AB2_BLOCKS  = (B_ * NPRD) / 8;   // 384
constexpr int KNS_BLOCKS  = (B_ * M_ * RP) / 256; // 12
constexpr int PRE3_BLOCKS = (B_ * NALL) / 8;   // 2688
constexpr int KNN3_BLOCKS = B_ * (NG3 / 4);    // 448

typedef __attribute__((ext_vector_type(8))) short bf16x8;
typedef __attribute__((ext_vector_type(4))) float f32x4;

__device__ inline unsigned short f32_to_bf16_rne(float x) {
  union { float f; unsigned int u; } v; v.f = x;
  unsigned int r = v.u + 0x7fffu + ((v.u >> 16) & 1u);
  return (unsigned short)(r >> 16);
}
__device__ inline float bf16_to_f32(unsigned short h) {
  union { float f; unsigned int u; } v; v.u = ((unsigned int)h) << 16;
  return v.f;
}

// ---------------------------------------------------------------------------
// Wcat[t][0:128]  = We1[t] - We1[131+t]   (A part: xi @ (W1a - W1b))
// Wcat[t][128:256]= We1[131+t]            (B part: xj @ W1b)
__global__ __launch_bounds__(256) void wcat_kernel(const float* __restrict__ We1,
                                                   float* __restrict__ Wcat) {
  int n = blockIdx.x * 256 + threadIdx.x;
  if (n >= 131 * 256) return;
  int t = n >> 8, cc = n & 255;
  float v;
  if (cc < C) v = We1[t * C + cc] - We1[(131 + t) * C + cc];
  else        v = We1[(131 + t) * C + (cc - C)];
  Wcat[n] = v;
}

// ---------------------------------------------------------------------------
// WbigT[c][k] = (Wp @ Wcat_feat)[k][c] as bf16 hi/lo.  4 k-rows per block.
__global__ __launch_bounds__(256) void wbig_kernel(const float* __restrict__ Wp,
                                                   const float* __restrict__ Wcat,
                                                   unsigned short* __restrict__ wbT_hi,
                                                   unsigned short* __restrict__ wbT_lo) {
  __shared__ float wp_lds[4][128];
  const int tid = threadIdx.x;
  const int k0 = blockIdx.x * 4;
  for (int l = tid; l < 4 * 128; l += 256) {
    int r = l >> 7, f = l & 127;
    wp_lds[r][f] = Wp[(k0 + r) * C + f];
  }
  __syncthreads();
  float acc[4] = {0.f, 0.f, 0.f, 0.f};
  #pragma unroll 4
  for (int f = 0; f < 128; ++f) {
    float wv = Wcat[f * 256 + tid];
    #pragma unroll
    for (int r = 0; r < 4; ++r) acc[r] = fmaf(wp_lds[r][f], wv, acc[r]);
  }
  #pragma unroll
  for (int r = 0; r < 4; ++r) {
    unsigned short h = f32_to_bf16_rne(acc[r]);
    wbT_hi[(size_t)tid * TOK + k0 + r] = h;
    wbT_lo[(size_t)tid * TOK + k0 + r] = f32_to_bf16_rne(acc[r] - bf16_to_f32(h));
  }
}

// cb[c] = bp @ Wcat_feat[.][c] + (c<128 ? be1[c] : 0)
__global__ __launch_bounds__(256) void cb_kernel(const float* __restrict__ bp,
                                                 const float* __restrict__ Wcat,
                                                 const float* __restrict__ be1,
                                                 float* __restrict__ cb) {
  __shared__ float bp_lds[128];
  int tid = threadIdx.x;
  if (tid < 128) bp_lds[tid] = bp[tid];
  __syncthreads();
  float a = (tid < 128) ? be1[tid] : 0.f;
  #pragma unroll 4
  for (int f = 0; f < 128; ++f) a = fmaf(bp_lds[f], Wcat[f * 256 + tid], a);
  cb[tid] = a;
}

// ---------------------------------------------------------------------------
// We2 (fp32 [k][n]) -> transposed bf16 hi/lo [n][k] for MFMA B-fragment loads.
__global__ __launch_bounds__(256) void we2t_kernel(const float* __restrict__ We2,
                                                   unsigned short* __restrict__ hi,
                                                   unsigned short* __restrict__ lo) {
  int e = blockIdx.x * 256 + threadIdx.x;
  if (e >= C * C) return;
  int n = e >> 7, k = e & 127;
  float w = We2[k * C + n];
  unsigned short h = f32_to_bf16_rne(w);
  hi[n * C + k] = h;
  lo[n * C + k] = f32_to_bf16_rne(w - bf16_to_f32(h));
}

// ---------------------------------------------------------------------------
// T[row][c] = tok[row] @ Wbig. Split-bf16 MFMA GEMM.
__global__ __launch_bounds__(256) void t12_mfma_kernel(const float* __restrict__ ctx_tok,
                                                       const float* __restrict__ pred_tok,
                                                       const unsigned short* __restrict__ wbT_hi,
                                                       const unsigned short* __restrict__ wbT_lo,
                                                       float* __restrict__ T) {
  __shared__ unsigned short ahi[64 * 128];   // 16 KB
  __shared__ unsigned short alo[64 * 128];   // 16 KB
  __shared__ unsigned short bhi[128 * 128];  // 32 KB
  const int tid = threadIdx.x;
  const int r0 = blockIdx.x * 64;
  const int n0 = blockIdx.y * 128;
  const float* src = (r0 < B_ * P_) ? (ctx_tok + (size_t)r0 * TOK)
                                    : (pred_tok + (size_t)(r0 - B_ * P_) * TOK);
  const int lane = tid & 63, w = tid >> 6;
  const int m = lane & 15, quad = lane >> 4;

  f32x4 acc[8];
  #pragma unroll
  for (int nt = 0; nt < 8; ++nt) acc[nt] = (f32x4){0.f, 0.f, 0.f, 0.f};

  #pragma unroll 1
  for (int kc = 0; kc < 8; ++kc) {
    __syncthreads();
    #pragma unroll
    for (int i = 0; i < 4; ++i) {
      int task = tid + 256 * i;           // 0..1023
      int r = task >> 4, c = task & 15;
      const float* sp = src + (size_t)r * TOK + kc * 128 + c * 8;
      f32x4 a0 = *(const f32x4*)sp;
      f32x4 a1 = *(const f32x4*)(sp + 4);
      float vals[8] = {a0.x, a0.y, a0.z, a0.w, a1.x, a1.y, a1.z, a1.w};
      union { unsigned short s[8]; f32x4 v; } oh, ol;
      #pragma unroll
      for (int e = 0; e < 8; ++e) {
        unsigned short h = f32_to_bf16_rne(vals[e]);
        oh.s[e] = h;
        ol.s[e] = f32_to_bf16_rne(vals[e] - bf16_to_f32(h));
      }
      int dst = (r * 16 + (c ^ (r & 15))) * 8;
      *(f32x4*)(ahi + dst) = oh.v;
      *(f32x4*)(alo + dst) = ol.v;
    }
    #pragma unroll
    for (int i = 0; i < 8; ++i) {
      int task = tid + 256 * i;           // 0..2047
      int n = task >> 4, c = task & 15;
      f32x4 v = *(const f32x4*)(wbT_hi + (size_t)(n0 + n) * TOK + kc * 128 + c * 8);
      *(f32x4*)(bhi + (n * 16 + (c ^ (n & 15))) * 8) = v;
    }
    __syncthreads();
    #pragma unroll
    for (int ks = 0; ks < 4; ++ks) {
      int c0 = ks * 4 + quad;
      int aoff = ((w * 16 + m) * 16 + (c0 ^ m)) * 8;
      bf16x8 av  = *(const bf16x8*)(ahi + aoff);
      bf16x8 av2 = *(const bf16x8*)(alo + aoff);
      #pragma unroll
      for (int nt = 0; nt < 8; ++nt) {
        int n = nt * 16 + m;
        bf16x8 bh = *(const bf16x8*)(bhi + (n * 16 + (c0 ^ m)) * 8);
        bf16x8 bl = *(const bf16x8*)(wbT_lo + (size_t)(n0 + n) * TOK + kc * 128 + c0 * 8);
        acc[nt] = __builtin_amdgcn_mfma_f32_16x16x32_bf16(av, bh, acc[nt], 0, 0, 0);
        acc[nt] = __builtin_amdgcn_mfma_f32_16x16x32_bf16(av, bl, acc[nt], 0, 0, 0);
        acc[nt] = __builtin_amdgcn_mfma_f32_16x16x32_bf16(av2, bh, acc[nt], 0, 0, 0);
      }
    }
  }
  #pragma unroll
  for (int nt = 0; nt < 8; ++nt) {
    int col = n0 + nt * 16 + m;
    #pragma unroll
    for (int reg = 0; reg < 4; ++reg) {
      int row = r0 + w * 16 + quad * 4 + reg;
      T[(size_t)row * 256 + col] = acc[nt][reg];
    }
  }
}

// ---------------------------------------------------------------------------
// anchor: one 256-thread block; wave w = batch b (same reduce order as before).
__global__ __launch_bounds__(256) void anchor_kernel(const float* __restrict__ cxyz,
                                                     float* __restrict__ anchor) {
  const int w = threadIdx.x >> 6, lane = threadIdx.x & 63;
  float ax = 0.f, ay = 0.f, az = 0.f;
  for (int p = lane; p < P_; p += 64) {
    const float* c = &cxyz[(w * P_ + p) * 3];
    ax += c[0]; ay += c[1]; az += c[2];
  }
  for (int o = 32; o > 0; o >>= 1) {
    ax += __shfl_down(ax, o);
    ay += __shfl_down(ay, o);
    az += __shfl_down(az, o);
  }
  if (lane == 0) {
    anchor[w * 3 + 0] = ax * (1.0f / (float)P_);
    anchor[w * 3 + 1] = ay * (1.0f / (float)P_);
    anchor[w * 3 + 2] = az * (1.0f / (float)P_);
  }
}

// ---------------------------------------------------------------------------
// build_ctx also zero-inits the per-group max-offset radius array (used by knn3).
__global__ __launch_bounds__(256) void build_ctx_kernel(const float* __restrict__ cxyz,
                                                        const float* __restrict__ noise,
                                                        float* __restrict__ xyz_all,
                                                        int* __restrict__ radmax) {
  int n = blockIdx.x * 256 + threadIdx.x;
  if (n < B_ * NG3) radmax[n] = 0;      // float 0.0 bits
  if (n >= B_ * NCTX) return;
  int b = n / NCTX, i = n % NCTX, p = i / RC;
  float x = noise[n * 3 + 0], y = noise[n * 3 + 1], z = noise[n * 3 + 2];
  float s = 0.02f / (sqrtf(x * x + y * y + z * z) + 1e-6f);
  const float* c = &cxyz[(b * P_ + p) * 3];
  float* o = &xyz_all[(b * NALL + i) * 3];
  o[0] = c[0] + x * s;
  o[1] = c[1] + y * s;
  o[2] = c[2] + z * s;
}

__global__ __launch_bounds__(256) void build_pred_kernel(const float* __restrict__ anchor,
                                                         const float* __restrict__ noise,
                                                         float* __restrict__ xyz_all) {
  int n = blockIdx.x * 256 + threadIdx.x;
  if (n >= B_ * NPRD) return;
  int b = n / NPRD, i = n % NPRD;
  float x = noise[n * 3 + 0], y = noise[n * 3 + 1], z = noise[n * 3 + 2];
  float s = 0.05f / (sqrtf(x * x + y * y + z * z) + 1e-6f);
  const float* a = &anchor[b * 3];
  float* o = &xyz_all[(b * NALL + NCTX + i) * 3];
  o[0] = a[0] + x * s;
  o[1] = a[1] + y * s;
  o[2] = a[2] + z * s;
}

// ---------------------------------------------------------------------------
// Wave-level group-pruned exact kNN body (one wave handles one group of 12
// queries). Identical 3-phase algorithm to rounds 4-6 (exact; excluded points
// provably satisfy d2 >= t >= final bd[7]); spheres are now ANALYTIC:
//   stage 1: center ctx_xyz[g], radius 0.0201 (noise ring radius <= 0.02)
//   stage 3: ctx groups: center ctx_xyz[g], radius 0.0201 + maxoff(g)
//            pred groups: center anchor,    radius 0.0501 + maxoff(g)
// where maxoff = per-group max |offset| accumulated by offset kernels.
template <int STAGE>
__device__ __forceinline__ void knn_wave_body(
    const float* __restrict__ xyz_all, const float* __restrict__ ctx_xyz,
    const float* __restrict__ anchor, const int* __restrict__ radmax,
    int b, int p, int lane,
    float4* own, int* gl, float4* tile, int* tilei,
    int* __restrict__ idx_out) {
  const int NG  = (STAGE == 1) ? NG1 : NG3;
  const int Npg = (STAGE == 1) ? NCTX : NALL;
  const float* base = xyz_all + (size_t)b * NALL * 3;
  const float* cxb  = ctx_xyz + (size_t)b * P_ * 3;
  const bool owner = lane < GS;
  const int qloc = p * GS + lane;

  // sphere fetch
  auto sph = [&](int g) -> float4 {
    float4 c;
    float rad;
    if (STAGE == 1) {
      c = make_float4(cxb[g * 3 + 0], cxb[g * 3 + 1], cxb[g * 3 + 2], 0.f);
      rad = 0.0201f;
    } else {
      float moff = __int_as_float(radmax[b * NG3 + g]);
      if (g < NG1) {
        c = make_float4(cxb[g * 3 + 0], cxb[g * 3 + 1], cxb[g * 3 + 2], 0.f);
        rad = 0.0201f + moff * 1.0002f + 1e-6f;
      } else {
        c = make_float4(anchor[b * 3 + 0], anchor[b * 3 + 1], anchor[b * 3 + 2], 0.f);
        rad = 0.0501f + moff * 1.0002f + 1e-6f;
      }
    }
    c.w = rad;
    return c;
  };

  // stage own group's 12 points into wave-private LDS
  if (owner) {
    float x = base[qloc * 3 + 0], y = base[qloc * 3 + 1], z = base[qloc * 3 + 2];
    own[lane] = make_float4(x, y, z, x * x + y * y + z * z);
  }
  float qx = 0.f, qy = 0.f, qz = 0.f, sqi = 0.f;
  if (owner) {
    float4 q = own[lane];
    qx = q.x; qy = q.y; qz = q.z; sqi = q.w;
  }

  float bd[KNN];
  int   bi[KNN];
  #pragma unroll
  for (int u = 0; u < KNN; ++u) { bd[u] = 3e38f; bi[u] = 0x7fffffff; }

  // ---- phase 1: own group ----
  #pragma unroll 1
  for (int j = 0; j < GS; ++j) {
    float4 cj = own[j];
    float d2 = sqi + cj.w - 2.0f * (qx * cj.x + qy * cj.y + qz * cj.z);
    if (owner && j != lane && d2 < bd[KNN - 1]) {
      bd[KNN - 1] = d2; bi[KNN - 1] = p * GS + j;
      #pragma unroll
      for (int u = KNN - 1; u > 0; --u) {
        if (bd[u] < bd[u - 1]) {
          float td = bd[u]; bd[u] = bd[u - 1]; bd[u - 1] = td;
          int   ti = bi[u]; bi[u] = bi[u - 1]; bi[u - 1] = ti;
        }
      }
    }
  }

  // ---- wave threshold ----
  float t = owner ? bd[KNN - 1] : 0.f;
  #pragma unroll
  for (int mm = 1; mm < 64; mm <<= 1) t = fmaxf(t, __shfl_xor(t, mm));
  float r = sqrtf(fmaxf(t, 0.f)) * 1.001f + 1e-6f;

  const float4 gp = sph(p);
  const float rlim = r + gp.w;

  // ---- phase 2: ballot-compact relevant groups ----
  int ng = 0;
  #pragma unroll 1
  for (int gs0 = 0; gs0 < NG; gs0 += 64) {
    int g = gs0 + lane;
    bool ok = false;
    if (g < NG && g != p) {
      float4 gq = sph(g);
      float dx = gq.x - gp.x, dy = gq.y - gp.y, dz = gq.z - gp.z;
      float lim = rlim + gq.w;
      ok = (dx * dx + dy * dy + dz * dz) < lim * lim * 1.001f;
    }
    unsigned long long mask = __ballot(ok);
    if (ok) gl[ng + (int)__popcll(mask & ((1ull << lane) - 1ull))] = g;
    ng += (int)__popcll(mask);
  }

  // ---- phase 3: cooperative tiled scan (wave-private tile) ----
  const int total = ng * GS;
  #pragma unroll 1
  for (int cs = 0; cs < total; cs += 64) {
    int ci = cs + lane;
    if (ci < total) {
      int gg = gl[ci / GS];
      int j  = ci % GS;
      int jloc = gg * GS + j;
      float x = base[jloc * 3 + 0], y = base[jloc * 3 + 1], z = base[jloc * 3 + 2];
      tile[lane] = make_float4(x, y, z, x * x + y * y + z * z);
      tilei[lane] = jloc;
    }
    int nj = min(64, total - cs);
    #pragma unroll 1
    for (int jj = 0; jj < nj; ++jj) {
      float4 tt = tile[jj];
      int ti0 = tilei[jj];
      float d2 = sqi + tt.w - 2.0f * (qx * tt.x + qy * tt.y + qz * tt.z);
      if (owner && d2 < bd[KNN - 1]) {
        bd[KNN - 1] = d2; bi[KNN - 1] = ti0;
        #pragma unroll
        for (int u = KNN - 1; u > 0; --u) {
          if (bd[u] < bd[u - 1]) {
            float td = bd[u]; bd[u] = bd[u - 1]; bd[u - 1] = td;
            int   ti = bi[u]; bi[u] = bi[u - 1]; bi[u - 1] = ti;
          }
        }
      }
    }
  }

  if (owner) {
    int gid = b * Npg + qloc;
    #pragma unroll
    for (int u = 0; u < KNN; ++u) idx_out[gid * KNN + u] = b * Npg + bi[u];
  }
}

// ---------------------------------------------------------------------------
// FUSED: stage-1 AB assembly (blocks [0, AB1_BLOCKS)) + stage-1 kNN (rest).
__global__ __launch_bounds__(256) void ab12_knn1_kernel(
    const float* __restrict__ T, const float* __restrict__ xyz_all,
    const float* __restrict__ Wcat, const float* __restrict__ cb,
    const float* __restrict__ ctx_xyz,
    float* __restrict__ AB, int* __restrict__ idx1) {
  __shared__ float4 own[4][GS];
  __shared__ int    gl[4][NG1];
  __shared__ float4 tile[4][64];
  __shared__ int    tilei[4][64];
  const int tid = threadIdx.x;
  if (blockIdx.x < AB1_BLOCKS) {
    const int base = blockIdx.x * 8;
    const float wx = Wcat[128 * 256 + tid];
    const float wy = Wcat[129 * 256 + tid];
    const float wz = Wcat[130 * 256 + tid];
    const float cbv = cb[tid];
    #pragma unroll
    for (int p = 0; p < 8; ++p) {
      int n = base + p;
      int b = n / NCTX, loc = n % NCTX;
      int trow = b * (NCTX / GS) + loc / GS;
      const float* xr = xyz_all + (size_t)(b * NALL + loc) * 3;
      float x = xr[0], y = xr[1], z = xr[2];
      float v = T[(size_t)trow * 256 + tid] + cbv;
      v = fmaf(x, wx, v);
      v = fmaf(y, wy, v);
      v = fmaf(z, wz, v);
      AB[(size_t)n * 256 + tid] = v;
    }
  } else {
    int kblk = blockIdx.x - AB1_BLOCKS;
    int w = tid >> 6, lane = tid & 63;
    int b = kblk / (NG1 / 4);
    int p = (kblk % (NG1 / 4)) * 4 + w;
    knn_wave_body<1>(xyz_all, ctx_xyz, nullptr, nullptr, b, p, lane,
                     own[w], gl[w], tile[w], tilei[w], idx1);
  }
}

// ---------------------------------------------------------------------------
// FUSED: stage-2 AB assembly (blocks [0, AB2_BLOCKS)) + stage-2 small kNN.
__global__ __launch_bounds__(256) void ab12_knn2_kernel(
    const float* __restrict__ T, const float* __restrict__ xyz_all,
    const float* __restrict__ Wcat, const float* __restrict__ cb,
    float* __restrict__ AB, int* __restrict__ idx2) {
  const int tid = threadIdx.x;
  if (blockIdx.x < AB2_BLOCKS) {
    const int base = blockIdx.x * 8;
    const float wx = Wcat[128 * 256 + tid];
    const float wy = Wcat[129 * 256 + tid];
    const float wz = Wcat[130 * 256 + tid];
    const float cbv = cb[tid];
    #pragma unroll
    for (int p = 0; p < 8; ++p) {
      int n = base + p;
      int b = n / NPRD, loc = n % NPRD;
      int trow = B_ * P_ + b * (NPRD / GS) + loc / GS;
      const float* xr = xyz_all + (size_t)(b * NALL + NCTX + loc) * 3;
      float x = xr[0], y = xr[1], z = xr[2];
      float v = T[(size_t)trow * 256 + tid] + cbv;
      v = fmaf(x, wx, v);
      v = fmaf(y, wy, v);
      v = fmaf(z, wz, v);
      AB[(size_t)n * 256 + tid] = v;
    }
  } else {
    int q = (blockIdx.x - AB2_BLOCKS) * 256 + tid;
    int gr = q / RP, qi = q % RP;
    int b = gr / M_, w = gr % M_;
    const float* base = xyz_all + (size_t)(b * NALL + NCTX + w * RP) * 3;
    float cx[RP], cy[RP], cz[RP], cs[RP];
    #pragma unroll
    for (int j = 0; j < RP; ++j) {
      cx[j] = base[j * 3 + 0]; cy[j] = base[j * 3 + 1]; cz[j] = base[j * 3 + 2];
      cs[j] = cx[j] * cx[j] + cy[j] * cy[j] + cz[j] * cz[j];
    }
    float qx = cx[0], qy = cy[0], qz = cz[0], sqi = cs[0];
    #pragma unroll
    for (int j = 0; j < RP; ++j) {
      if (j == qi) { qx = cx[j]; qy = cy[j]; qz = cz[j]; sqi = cs[j]; }
    }
    float bd[KNN];
    int   bi[KNN];
    #pragma unroll
    for (int u = 0; u < KNN; ++u) { bd[u] = 3e38f; bi[u] = 0; }
    #pragma unroll
    for (int j = 0; j < RP; ++j) {
      float d2 = sqi + cs[j] - 2.0f * (qx * cx[j] + qy * cy[j] + qz * cz[j]);
      if (j != qi && d2 < bd[KNN - 1]) {
        bd[KNN - 1] = d2; bi[KNN - 1] = j;
        #pragma unroll
        for (int u = KNN - 1; u > 0; --u) {
          if (bd[u] < bd[u - 1]) {
            float td = bd[u]; bd[u] = bd[u - 1]; bd[u - 1] = td;
            int   ti = bi[u]; bi[u] = bi[u - 1]; bi[u - 1] = ti;
          }
        }
      }
    }
    #pragma unroll
    for (int u = 0; u < KNN; ++u) idx2[q * KNN + u] = gr * RP + bi[u];
  }
}

// ---------------------------------------------------------------------------
// FUSED: stage-3 precompute (blocks [0, PRE3_BLOCKS)) + stage-3 kNN (rest).
// (The two are independent: precompute reads feat_in+xyz, kNN reads xyz+radmax.)
__global__ __launch_bounds__(256) void pre3_knn3_kernel(
    const float* __restrict__ feat, const float* __restrict__ xyz_all,
    const float* __restrict__ Wcat, const float* __restrict__ be1,
    const float* __restrict__ ctx_xyz, const float* __restrict__ anchor,
    const int* __restrict__ radmax,
    float* __restrict__ AB, int* __restrict__ idx3) {
  __shared__ float x_lds[8][132];
  __shared__ float4 own[4][GS];
  __shared__ int    gl[4][NG3];
  __shared__ float4 tile[4][64];
  __shared__ int    tilei[4][64];
  const int tid = threadIdx.x;
  if (blockIdx.x < PRE3_BLOCKS) {
    const int base = blockIdx.x * 8;
    for (int l = tid; l < 8 * 131; l += 256) {
      int pt = l / 131, t = l % 131;
      int g = base + pt;
      int b = g / NALL, loc = g % NALL;
      float v;
      if (t < C) v = feat[(size_t)g * C + t];
      else       v = xyz_all[(size_t)(b * NALL + loc) * 3 + (t - C)];
      x_lds[pt][t] = v;
    }
    __syncthreads();
    float acc[8] = {0.f, 0.f, 0.f, 0.f, 0.f, 0.f, 0.f, 0.f};
    #pragma unroll 1
    for (int t = 0; t < 131; ++t) {
      float wv = Wcat[t * 256 + tid];
      #pragma unroll
      for (int p = 0; p < 8; ++p) acc[p] = fmaf(x_lds[p][t], wv, acc[p]);
    }
    float bias = (tid < C) ? be1[tid] : 0.0f;
    #pragma unroll
    for (int p = 0; p < 8; ++p) AB[(size_t)(base + p) * 256 + tid] = acc[p] + bias;
  } else {
    int kblk = blockIdx.x - PRE3_BLOCKS;
    int w = tid >> 6, lane = tid & 63;
    int b = kblk / (NG3 / 4);
    int p = (kblk % (NG3 / 4)) * 4 + w;
    knn_wave_body<3>(xyz_all, ctx_xyz, anchor, radmax, b, p, lane,
                     own[w], gl[w], tile[w], tilei[w], idx3);
  }
}

// ---------------------------------------------------------------------------
// MFMA EdgeConv core (split-bf16, 3 MFMAs, ~2^-16 err).
__global__ __launch_bounds__(256) void conv_mfma_kernel(const float* __restrict__ AB,
                                                        const int* __restrict__ idx,
                                                        const unsigned short* __restrict__ w2hi_g,
                                                        const unsigned short* __restrict__ w2lo_g,
                                                        const float* __restrict__ be2,
                                                        float* __restrict__ feat_out,
                                                        int NPB, int row_off) {
  __shared__ unsigned short hhi[64 * 128];    // 16 KB
  __shared__ unsigned short hlo[64 * 128];    // 16 KB
  __shared__ unsigned short w2hi[128 * 128];  // 32 KB
  const int tid = threadIdx.x;
  const int base = blockIdx.x * 8;

  #pragma unroll
  for (int i = 0; i < 8; ++i) {
    int q = tid + 256 * i;
    int n = q >> 4, c = q & 15;
    f32x4 v = *(const f32x4*)(w2hi_g + n * 128 + c * 8);
    *(f32x4*)(w2hi + (n * 16 + (c ^ (n & 15))) * 8) = v;
  }

  #pragma unroll
  for (int i = 0; i < 4; ++i) {
    int task = tid + 256 * i;
    int r = task >> 4, c = task & 15;
    int p = r >> 3, nb = r & 7;
    int g = base + p;
    int j = idx[g * KNN + nb];
    const float* aP = AB + (size_t)g * 256 + c * 8;
    const float* bP = AB + (size_t)j * 256 + 128 + c * 8;
    f32x4 a0 = *(const f32x4*)aP;
    f32x4 a1 = *(const f32x4*)(aP + 4);
    f32x4 b0 = *(const f32x4*)bP;
    f32x4 b1 = *(const f32x4*)(bP + 4);
    float hv[8] = {a0.x + b0.x, a0.y + b0.y, a0.z + b0.z, a0.w + b0.w,
                   a1.x + b1.x, a1.y + b1.y, a1.z + b1.z, a1.w + b1.w};
    union { unsigned short s[8]; f32x4 v; } oh, ol;
    #pragma unroll
    for (int e = 0; e < 8; ++e) {
      float h = fmaxf(hv[e], 0.0f);
      unsigned short x = f32_to_bf16_rne(h);
      oh.s[e] = x;
      ol.s[e] = f32_to_bf16_rne(h - bf16_to_f32(x));
    }
    int dst = (r * 16 + (c ^ (r & 15))) * 8;
    *(f32x4*)(hhi + dst) = oh.v;
    *(f32x4*)(hlo + dst) = ol.v;
  }
  __syncthreads();

  const int lane = tid & 63, w = tid >> 6;
  const int m = lane & 15, quad = lane >> 4;
  f32x4 acc[8];
  #pragma unroll
  for (int nt = 0; nt < 8; ++nt) acc[nt] = (f32x4){0.f, 0.f, 0.f, 0.f};

  #pragma unroll 1
  for (int ks = 0; ks < 4; ++ks) {
    int c0 = ks * 4 + quad;
    int rowA = w * 16 + m;
    int aoff = (rowA * 16 + (c0 ^ m)) * 8;
    bf16x8 ahi = *(const bf16x8*)(hhi + aoff);
    bf16x8 alo = *(const bf16x8*)(hlo + aoff);
    #pragma unroll
    for (int nt = 0; nt < 8; ++nt) {
      int n = nt * 16 + m;
      bf16x8 bhi = *(const bf16x8*)(w2hi + (n * 16 + (c0 ^ m)) * 8);
      bf16x8 blo = *(const bf16x8*)(w2lo_g + n * 128 + c0 * 8);
      acc[nt] = __builtin_amdgcn_mfma_f32_16x16x32_bf16(ahi, bhi, acc[nt], 0, 0, 0);
      acc[nt] = __builtin_amdgcn_mfma_f32_16x16x32_bf16(ahi, blo, acc[nt], 0, 0, 0);
      acc[nt] = __builtin_amdgcn_mfma_f32_16x16x32_bf16(alo, bhi, acc[nt], 0, 0, 0);
    }
  }

  int pt = 2 * w + (quad >> 1);
  int g = base + pt;
  int b = g / NPB, loc = g % NPB;
  float* orow = feat_out + (size_t)(b * NALL + row_off + loc) * C;
  bool writer = (quad & 1) == 0;
  #pragma unroll
  for (int nt = 0; nt < 8; ++nt) {
    float v = fmaxf(fmaxf(acc[nt].x, acc[nt].y), fmaxf(acc[nt].z, acc[nt].w));
    v = fmaxf(v, __shfl_xor(v, 16));
    if (writer) {
      int col = nt * 16 + m;
      orow[col] = v + be2[col];
    }
  }
}

// ---------------------------------------------------------------------------
// offset MLP: out_row = xyz_in_row + (relu(f@W1+b1) @ W2 + b2).
// Optionally accumulates per-group max |offset| into radmax (for knn3 bounds).
__global__ __launch_bounds__(256) void offset_kernel(const float* __restrict__ feat,
                                                     const float* __restrict__ W1,
                                                     const float* __restrict__ b1,
                                                     const float* __restrict__ W2,
                                                     const float* __restrict__ b2,
                                                     const float* __restrict__ xyz_in,
                                                     float* __restrict__ xyz_out,
                                                     int NPB, int row_off,
                                                     int* __restrict__ radmax) {
  __shared__ float w1c[64 * C];
  __shared__ float f_lds[16][C];
  __shared__ float wred[4][3];
  const int tid = threadIdx.x;
  const int base = blockIdx.x * 16;
  const int p = tid >> 7;
  const int cc = tid & 127;
  const int wave = tid >> 6, lane = tid & 63;

  for (int l = tid; l < 16 * C; l += 256) {
    int pt = l >> 7, t = l & 127;
    int g = base + pt;
    int b = g / NPB, loc = g % NPB;
    f_lds[pt][t] = feat[(size_t)(b * NALL + row_off + loc) * C + t];
  }

  float s[8];
  #pragma unroll
  for (int pp = 0; pp < 8; ++pp) s[pp] = 0.f;

  for (int kk = 0; kk < 2; ++kk) {
    __syncthreads();
    for (int l = tid * 4; l < 64 * C; l += 1024)
      *(float4*)&w1c[l] = *(const float4*)&W1[kk * 64 * C + l];
    __syncthreads();
    #pragma unroll
    for (int pp = 0; pp < 8; ++pp) {
      const float* f = &f_lds[pp * 2 + p][kk * 64];
      float acc = s[pp];
      #pragma unroll 4
      for (int t = 0; t < 64; ++t) acc = fmaf(f[t], w1c[t * C + cc], acc);
      s[pp] = acc;
    }
  }

  float b1v = b1[cc];
  float w20 = W2[cc * 3 + 0], w21 = W2[cc * 3 + 1], w22 = W2[cc * 3 + 2];
  float b20 = b2[0], b21 = b2[1], b22 = b2[2];

  #pragma unroll 1
  for (int pp = 0; pp < 8; ++pp) {
    float h = fmaxf(s[pp] + b1v, 0.0f);
    float p0 = h * w20, p1 = h * w21, p2 = h * w22;
    for (int o = 32; o > 0; o >>= 1) {
      p0 += __shfl_down(p0, o);
      p1 += __shfl_down(p1, o);
      p2 += __shfl_down(p2, o);
    }
    if (lane == 0) { wred[wave][0] = p0; wred[wave][1] = p1; wred[wave][2] = p2; }
    __syncthreads();
    if (tid < 2) {
      int g = base + pp * 2 + tid;
      int b = g / NPB, loc = g % NPB;
      int row = (b * NALL + row_off + loc) * 3;
      float o0 = wred[tid * 2][0] + wred[tid * 2 + 1][0] + b20;
      float o1 = wred[tid * 2][1] + wred[tid * 2 + 1][1] + b21;
      float o2 = wred[tid * 2][2] + wred[tid * 2 + 1][2] + b22;
      xyz_out[row + 0] = xyz_in[row + 0] + o0;
      xyz_out[row + 1] = xyz_in[row + 1] + o1;
      xyz_out[row + 2] = xyz_in[row + 2] + o2;
      if (radmax != nullptr) {
        float mag = sqrtf(o0 * o0 + o1 * o1 + o2 * o2);
        atomicMax(radmax + b * NG3 + (row_off + loc) / GS, __float_as_int(mag));
      }
    }
    __syncthreads();
  }
}

// ---------------------------------------------------------------------------
extern "C" void kernel_launch(void* const* d_in, const int* in_sizes, int n_in,
                              void* d_out, int out_size, void* d_ws, size_t ws_size,
                              hipStream_t stream) {
  (void)in_sizes; (void)n_in; (void)out_size; (void)ws_size;
  const float* ctx_xyz   = (const float*)d_in[0];
  const float* ctx_tok   = (const float*)d_in[1];
  const float* pred_tok  = (const float*)d_in[2];
  const float* noise_ctx = (const float*)d_in[3];
  const float* noise_prd = (const float*)d_in[4];
  const float* Wp  = (const float*)d_in[5];
  const float* bp  = (const float*)d_in[6];
  const float* We1 = (const float*)d_in[7];
  const float* be1 = (const float*)d_in[8];
  const float* We2 = (const float*)d_in[9];
  const float* be2 = (const float*)d_in[10];
  const float* Wc1 = (const float*)d_in[11];
  const float* bc1 = (const float*)d_in[12];
  const float* Wc2 = (const float*)d_in[13];
  const float* bc2 = (const float*)d_in[14];
  const float* Wq1 = (const float*)d_in[15];
  const float* bq1 = (const float*)d_in[16];
  const float* Wq2 = (const float*)d_in[17];
  const float* bq2 = (const float*)d_in[18];
  const float* Wf1 = (const float*)d_in[19];
  const float* bf1 = (const float*)d_in[20];
  const float* Wf2 = (const float*)d_in[21];
  const float* bf2 = (const float*)d_in[22];
  float* out = (float*)d_out;

  // workspace layout (floats)
  float* ws        = (float*)d_ws;
  float* T         = ws;                          // 1792*256    = 458752
  float* anchor    = T + TROWS * 256;             // 16
  float* xyz_all   = anchor + 16;                 // B*NALL*3    = 64512
  float* feat_in   = xyz_all + B_ * NALL * 3;     // B*NALL*C    = 2752512
  float* feat_out  = feat_in + B_ * NALL * C;     // B*NALL*C    = 2752512
  float* AB        = feat_out + B_ * NALL * C;    // B*NALL*256  = 5505024
  float* Wcat      = AB + B_ * NALL * 256;        // 131*256     = 33536
  float* cb        = Wcat + 131 * 256;            // 256
  int*   idx1      = (int*)(cb + 256);            // B*NCTX*8    = 147456
  int*   idx2      = idx1 + B_ * NCTX * KNN;      // B*NPRD*8    = 24576
  int*   idx3      = idx2 + B_ * NPRD * KNN;      // B*NALL*8    = 172032
  unsigned short* we2hi = (unsigned short*)(idx3 + B_ * NALL * KNN); // 16384
  unsigned short* we2lo = we2hi + C * C;                             // 16384
  int*   radmax    = (int*)(we2lo + C * C);       // B*NG3       = 1792 ints
  // wbT aliases AB: fully consumed by t12_mfma before the first AB write.
  unsigned short* wbT_hi = (unsigned short*)AB;   // 256*1024 ushorts
  unsigned short* wbT_lo = wbT_hi + 256 * TOK;    // 256*1024 ushorts

  // prep
  wcat_kernel<<<131, 256, 0, stream>>>(We1, Wcat);
  wbig_kernel<<<TOK / 4, 256, 0, stream>>>(Wp, Wcat, wbT_hi, wbT_lo);
  cb_kernel<<<1, 256, 0, stream>>>(bp, Wcat, be1, cb);
  we2t_kernel<<<(C * C) / 256, 256, 0, stream>>>(We2, we2hi, we2lo);
  anchor_kernel<<<1, 256, 0, stream>>>(ctx_xyz, anchor);
  build_ctx_kernel<<<(B_ * NCTX) / 256, 256, 0, stream>>>(ctx_xyz, noise_ctx, xyz_all, radmax);
  build_pred_kernel<<<(B_ * NPRD + 255) / 256, 256, 0, stream>>>(anchor, noise_prd, xyz_all);

  // token GEMM: T = [ctx_tok; pred_tok] @ Wbig  (1792 x 256, K=1024)
  t12_mfma_kernel<<<dim3(TROWS / 64, 2), 256, 0, stream>>>(ctx_tok, pred_tok, wbT_hi, wbT_lo, T);

  // ---- stage 1: context branch ----
  ab12_knn1_kernel<<<AB1_BLOCKS + KNN1_BLOCKS, 256, 0, stream>>>(T, xyz_all, Wcat, cb,
                                                                 ctx_xyz, AB, idx1);
  conv_mfma_kernel<<<(B_ * NCTX) / 8, 256, 0, stream>>>(AB, idx1, we2hi, we2lo, be2, feat_in, NCTX, 0);
  offset_kernel<<<(B_ * NCTX) / 16, 256, 0, stream>>>(feat_in, Wc1, bc1, Wc2, bc2,
                                                      xyz_all, xyz_all, NCTX, 0, radmax);

  // ---- stage 2: prediction branch ----
  ab12_knn2_kernel<<<AB2_BLOCKS + KNS_BLOCKS, 256, 0, stream>>>(T, xyz_all, Wcat, cb, AB, idx2);
  conv_mfma_kernel<<<(B_ * NPRD) / 8, 256, 0, stream>>>(AB, idx2, we2hi, we2lo, be2, feat_in, NPRD, NCTX);
  offset_kernel<<<(B_ * NPRD) / 16, 256, 0, stream>>>(feat_in, Wq1, bq1, Wq2, bq2,
                                                      xyz_all, xyz_all, NPRD, NCTX, radmax);

  // ---- stage 3: global refinement ----
  pre3_knn3_kernel<<<PRE3_BLOCKS + KNN3_BLOCKS, 256, 0, stream>>>(feat_in, xyz_all, Wcat, be1,
                                                                  ctx_xyz, anchor, radmax,
                                                                  AB, idx3);
  conv_mfma_kernel<<<(B_ * NALL) / 8, 256, 0, stream>>>(AB, idx3, we2hi, we2lo, be2, feat_out, NALL, 0);
  offset_kernel<<<(B_ * NALL) / 16, 256, 0, stream>>>(feat_out, Wf1, bf1, Wf2, bf2,
                                                      xyz_all, out, NALL, 0, nullptr);
}

// Round 8
// 559.006 us; speedup vs baseline: 3.1386x; 1.1530x over previous
//
#include <hip/hip_runtime.h>
#include <math.h>

// Problem constants (from setup_inputs; k==8 is fixed by the harness inputs).
constexpr int B_   = 4;
constexpr int P_   = 384;
constexpr int M_   = 64;
constexpr int TOK  = 1024;
constexpr int C    = 128;
constexpr int RC   = 12;
constexpr int RP   = 12;
constexpr int KNN  = 8;
constexpr int GS   = 12;           // group size (both ctx clusters and pred rings)
constexpr int NCTX = P_ * RC;      // 4608 ctx points per batch
constexpr int NPRD = M_ * RP;      // 768 pred points per batch
constexpr int NALL = NCTX + NPRD;  // 5376
constexpr int NG1  = NCTX / GS;    // 384 groups, stage 1
constexpr int NG3  = NALL / GS;    // 448 groups, stage 3
constexpr int TROWS = B_ * P_ + B_ * M_;  // 1792 token rows (ctx then pred)

// fused-grid split points
constexpr int AB1_BLOCKS   = (B_ * NCTX) / 8;      // 2304
constexpr int KNN1_BLOCKS  = B_ * (NG1 / 4);       // 384
constexpr int AB2_BLOCKS   = (B_ * NPRD) / 8;      // 384
constexpr int KNS_BLOCKS   = (B_ * M_ * RP) / 256; // 12
constexpr int PRE3_BLOCKS  = (B_ * NALL) / 8;      // 2688
constexpr int KNN3C_BLOCKS = B_ * (NG1 / 4);       // 384 (ctx groups, wave-per-group)
constexpr int KNN3P_BLOCKS = (B_ * NPRD) / 4;      // 768 (pred queries, wave-per-query)

typedef __attribute__((ext_vector_type(8))) short bf16x8;
typedef __attribute__((ext_vector_type(4))) float f32x4;

__device__ inline unsigned short f32_to_bf16_rne(float x) {
  union { float f; unsigned int u; } v; v.f = x;
  unsigned int r = v.u + 0x7fffu + ((v.u >> 16) & 1u);
  return (unsigned short)(r >> 16);
}
__device__ inline float bf16_to_f32(unsigned short h) {
  union { float f; unsigned int u; } v; v.u = ((unsigned int)h) << 16;
  return v.f;
}

// ---------------------------------------------------------------------------
// FUSED prep1: Wcat build | We2 transpose | anchor.
// Wcat[t][0:128] = We1[t]-We1[131+t]; Wcat[t][128:256] = We1[131+t].
__global__ __launch_bounds__(256) void prep1_kernel(const float* __restrict__ We1,
                                                    const float* __restrict__ We2,
                                                    const float* __restrict__ cxyz,
                                                    float* __restrict__ Wcat,
                                                    unsigned short* __restrict__ we2hi,
                                                    unsigned short* __restrict__ we2lo,
                                                    float* __restrict__ anchor) {
  const int tid = threadIdx.x;
  if (blockIdx.x < 131) {
    int n = blockIdx.x * 256 + tid;
    int t = n >> 8, cc = n & 255;
    float v;
    if (cc < C) v = We1[t * C + cc] - We1[(131 + t) * C + cc];
    else        v = We1[(131 + t) * C + (cc - C)];
    Wcat[n] = v;
  } else if (blockIdx.x < 195) {
    int e = (blockIdx.x - 131) * 256 + tid;
    int n = e >> 7, k = e & 127;
    float w = We2[k * C + n];
    unsigned short h = f32_to_bf16_rne(w);
    we2hi[n * C + k] = h;
    we2lo[n * C + k] = f32_to_bf16_rne(w - bf16_to_f32(h));
  } else {
    const int w = tid >> 6, lane = tid & 63;
    float ax = 0.f, ay = 0.f, az = 0.f;
    for (int p = lane; p < P_; p += 64) {
      const float* c = &cxyz[(w * P_ + p) * 3];
      ax += c[0]; ay += c[1]; az += c[2];
    }
    for (int o = 32; o > 0; o >>= 1) {
      ax += __shfl_down(ax, o);
      ay += __shfl_down(ay, o);
      az += __shfl_down(az, o);
    }
    if (lane == 0) {
      anchor[w * 3 + 0] = ax * (1.0f / (float)P_);
      anchor[w * 3 + 1] = ay * (1.0f / (float)P_);
      anchor[w * 3 + 2] = az * (1.0f / (float)P_);
    }
  }
}

// ---------------------------------------------------------------------------
// FUSED prep2: WbigT = (Wp @ Wcat_feat)^T bf16 hi/lo | cb vector.
__global__ __launch_bounds__(256) void prep2_kernel(const float* __restrict__ Wp,
                                                    const float* __restrict__ bp,
                                                    const float* __restrict__ Wcat,
                                                    const float* __restrict__ be1,
                                                    unsigned short* __restrict__ wbT_hi,
                                                    unsigned short* __restrict__ wbT_lo,
                                                    float* __restrict__ cb) {
  __shared__ float s_lds[4][128];
  const int tid = threadIdx.x;
  if (blockIdx.x < TOK / 4) {
    const int k0 = blockIdx.x * 4;
    for (int l = tid; l < 4 * 128; l += 256) {
      int r = l >> 7, f = l & 127;
      s_lds[r][f] = Wp[(k0 + r) * C + f];
    }
    __syncthreads();
    float acc[4] = {0.f, 0.f, 0.f, 0.f};
    #pragma unroll 4
    for (int f = 0; f < 128; ++f) {
      float wv = Wcat[f * 256 + tid];
      #pragma unroll
      for (int r = 0; r < 4; ++r) acc[r] = fmaf(s_lds[r][f], wv, acc[r]);
    }
    #pragma unroll
    for (int r = 0; r < 4; ++r) {
      unsigned short h = f32_to_bf16_rne(acc[r]);
      wbT_hi[(size_t)tid * TOK + k0 + r] = h;
      wbT_lo[(size_t)tid * TOK + k0 + r] = f32_to_bf16_rne(acc[r] - bf16_to_f32(h));
    }
  } else {
    if (tid < 128) s_lds[0][tid] = bp[tid];
    __syncthreads();
    float a = (tid < 128) ? be1[tid] : 0.f;
    #pragma unroll 4
    for (int f = 0; f < 128; ++f) a = fmaf(s_lds[0][f], Wcat[f * 256 + tid], a);
    cb[tid] = a;
  }
}

// ---------------------------------------------------------------------------
// FUSED geometry build: ctx points (+radmax zero-init) | pred points.
__global__ __launch_bounds__(256) void build_all_kernel(const float* __restrict__ cxyz,
                                                        const float* __restrict__ noise_c,
                                                        const float* __restrict__ noise_p,
                                                        const float* __restrict__ anchor,
                                                        float* __restrict__ xyz_all,
                                                        int* __restrict__ radmax) {
  if (blockIdx.x < 72) {
    int n = blockIdx.x * 256 + threadIdx.x;
    if (n < B_ * NG3) radmax[n] = 0;      // float 0.0 bits
    int b = n / NCTX, i = n % NCTX, p = i / RC;
    float x = noise_c[n * 3 + 0], y = noise_c[n * 3 + 1], z = noise_c[n * 3 + 2];
    float s = 0.02f / (sqrtf(x * x + y * y + z * z) + 1e-6f);
    const float* c = &cxyz[(b * P_ + p) * 3];
    float* o = &xyz_all[(b * NALL + i) * 3];
    o[0] = c[0] + x * s;
    o[1] = c[1] + y * s;
    o[2] = c[2] + z * s;
  } else {
    int n = (blockIdx.x - 72) * 256 + threadIdx.x;
    int b = n / NPRD, i = n % NPRD;
    float x = noise_p[n * 3 + 0], y = noise_p[n * 3 + 1], z = noise_p[n * 3 + 2];
    float s = 0.05f / (sqrtf(x * x + y * y + z * z) + 1e-6f);
    const float* a = &anchor[b * 3];
    float* o = &xyz_all[(b * NALL + NCTX + i) * 3];
    o[0] = a[0] + x * s;
    o[1] = a[1] + y * s;
    o[2] = a[2] + z * s;
  }
}

// ---------------------------------------------------------------------------
// T[row][c] = tok[row] @ Wbig. Split-bf16 MFMA GEMM.
__global__ __launch_bounds__(256) void t12_mfma_kernel(const float* __restrict__ ctx_tok,
                                                       const float* __restrict__ pred_tok,
                                                       const unsigned short* __restrict__ wbT_hi,
                                                       const unsigned short* __restrict__ wbT_lo,
                                                       float* __restrict__ T) {
  __shared__ unsigned short ahi[64 * 128];   // 16 KB
  __shared__ unsigned short alo[64 * 128];   // 16 KB
  __shared__ unsigned short bhi[128 * 128];  // 32 KB
  const int tid = threadIdx.x;
  const int r0 = blockIdx.x * 64;
  const int n0 = blockIdx.y * 128;
  const float* src = (r0 < B_ * P_) ? (ctx_tok + (size_t)r0 * TOK)
                                    : (pred_tok + (size_t)(r0 - B_ * P_) * TOK);
  const int lane = tid & 63, w = tid >> 6;
  const int m = lane & 15, quad = lane >> 4;

  f32x4 acc[8];
  #pragma unroll
  for (int nt = 0; nt < 8; ++nt) acc[nt] = (f32x4){0.f, 0.f, 0.f, 0.f};

  #pragma unroll 1
  for (int kc = 0; kc < 8; ++kc) {
    __syncthreads();
    #pragma unroll
    for (int i = 0; i < 4; ++i) {
      int task = tid + 256 * i;           // 0..1023
      int r = task >> 4, c = task & 15;
      const float* sp = src + (size_t)r * TOK + kc * 128 + c * 8;
      f32x4 a0 = *(const f32x4*)sp;
      f32x4 a1 = *(const f32x4*)(sp + 4);
      float vals[8] = {a0.x, a0.y, a0.z, a0.w, a1.x, a1.y, a1.z, a1.w};
      union { unsigned short s[8]; f32x4 v; } oh, ol;
      #pragma unroll
      for (int e = 0; e < 8; ++e) {
        unsigned short h = f32_to_bf16_rne(vals[e]);
        oh.s[e] = h;
        ol.s[e] = f32_to_bf16_rne(vals[e] - bf16_to_f32(h));
      }
      int dst = (r * 16 + (c ^ (r & 15))) * 8;
      *(f32x4*)(ahi + dst) = oh.v;
      *(f32x4*)(alo + dst) = ol.v;
    }
    #pragma unroll
    for (int i = 0; i < 8; ++i) {
      int task = tid + 256 * i;           // 0..2047
      int n = task >> 4, c = task & 15;
      f32x4 v = *(const f32x4*)(wbT_hi + (size_t)(n0 + n) * TOK + kc * 128 + c * 8);
      *(f32x4*)(bhi + (n * 16 + (c ^ (n & 15))) * 8) = v;
    }
    __syncthreads();
    #pragma unroll
    for (int ks = 0; ks < 4; ++ks) {
      int c0 = ks * 4 + quad;
      int aoff = ((w * 16 + m) * 16 + (c0 ^ m)) * 8;
      bf16x8 av  = *(const bf16x8*)(ahi + aoff);
      bf16x8 av2 = *(const bf16x8*)(alo + aoff);
      #pragma unroll
      for (int nt = 0; nt < 8; ++nt) {
        int n = nt * 16 + m;
        bf16x8 bh = *(const bf16x8*)(bhi + (n * 16 + (c0 ^ m)) * 8);
        bf16x8 bl = *(const bf16x8*)(wbT_lo + (size_t)(n0 + n) * TOK + kc * 128 + c0 * 8);
        acc[nt] = __builtin_amdgcn_mfma_f32_16x16x32_bf16(av, bh, acc[nt], 0, 0, 0);
        acc[nt] = __builtin_amdgcn_mfma_f32_16x16x32_bf16(av, bl, acc[nt], 0, 0, 0);
        acc[nt] = __builtin_amdgcn_mfma_f32_16x16x32_bf16(av2, bh, acc[nt], 0, 0, 0);
      }
    }
  }
  #pragma unroll
  for (int nt = 0; nt < 8; ++nt) {
    int col = n0 + nt * 16 + m;
    #pragma unroll
    for (int reg = 0; reg < 4; ++reg) {
      int row = r0 + w * 16 + quad * 4 + reg;
      T[(size_t)row * 256 + col] = acc[nt][reg];
    }
  }
}

// ---------------------------------------------------------------------------
// Wave-per-group kNN body for CTX groups (light: phase-3 list nearly empty).
template <int STAGE>
__device__ __forceinline__ void knn_wave_body(
    const float* __restrict__ xyz_all, const float* __restrict__ ctx_xyz,
    const float* __restrict__ anchor, const int* __restrict__ radmax,
    int b, int p, int lane,
    float4* own, int* gl, float4* tile, int* tilei,
    int* __restrict__ idx_out) {
  const int NG  = (STAGE == 1) ? NG1 : NG3;
  const int Npg = (STAGE == 1) ? NCTX : NALL;
  const float* base = xyz_all + (size_t)b * NALL * 3;
  const float* cxb  = ctx_xyz + (size_t)b * P_ * 3;
  const bool owner = lane < GS;
  const int qloc = p * GS + lane;

  auto sph = [&](int g) -> float4 {
    float4 c;
    float rad;
    if (STAGE == 1) {
      c = make_float4(cxb[g * 3 + 0], cxb[g * 3 + 1], cxb[g * 3 + 2], 0.f);
      rad = 0.0201f;
    } else {
      float moff = __int_as_float(radmax[b * NG3 + g]);
      if (g < NG1) {
        c = make_float4(cxb[g * 3 + 0], cxb[g * 3 + 1], cxb[g * 3 + 2], 0.f);
        rad = 0.0201f + moff * 1.0002f + 1e-6f;
      } else {
        c = make_float4(anchor[b * 3 + 0], anchor[b * 3 + 1], anchor[b * 3 + 2], 0.f);
        rad = 0.0501f + moff * 1.0002f + 1e-6f;
      }
    }
    c.w = rad;
    return c;
  };

  if (owner) {
    float x = base[qloc * 3 + 0], y = base[qloc * 3 + 1], z = base[qloc * 3 + 2];
    own[lane] = make_float4(x, y, z, x * x + y * y + z * z);
  }
  float qx = 0.f, qy = 0.f, qz = 0.f, sqi = 0.f;
  if (owner) {
    float4 q = own[lane];
    qx = q.x; qy = q.y; qz = q.z; sqi = q.w;
  }

  float bd[KNN];
  int   bi[KNN];
  #pragma unroll
  for (int u = 0; u < KNN; ++u) { bd[u] = 3e38f; bi[u] = 0x7fffffff; }

  #pragma unroll 1
  for (int j = 0; j < GS; ++j) {
    float4 cj = own[j];
    float d2 = sqi + cj.w - 2.0f * (qx * cj.x + qy * cj.y + qz * cj.z);
    if (owner && j != lane && d2 < bd[KNN - 1]) {
      bd[KNN - 1] = d2; bi[KNN - 1] = p * GS + j;
      #pragma unroll
      for (int u = KNN - 1; u > 0; --u) {
        if (bd[u] < bd[u - 1]) {
          float td = bd[u]; bd[u] = bd[u - 1]; bd[u - 1] = td;
          int   ti = bi[u]; bi[u] = bi[u - 1]; bi[u - 1] = ti;
        }
      }
    }
  }

  float t = owner ? bd[KNN - 1] : 0.f;
  #pragma unroll
  for (int mm = 1; mm < 64; mm <<= 1) t = fmaxf(t, __shfl_xor(t, mm));
  float r = sqrtf(fmaxf(t, 0.f)) * 1.001f + 1e-6f;

  const float4 gp = sph(p);
  const float rlim = r + gp.w;

  int ng = 0;
  #pragma unroll 1
  for (int gs0 = 0; gs0 < NG; gs0 += 64) {
    int g = gs0 + lane;
    bool ok = false;
    if (g < NG && g != p) {
      float4 gq = sph(g);
      float dx = gq.x - gp.x, dy = gq.y - gp.y, dz = gq.z - gp.z;
      float lim = rlim + gq.w;
      ok = (dx * dx + dy * dy + dz * dz) < lim * lim * 1.001f;
    }
    unsigned long long mask = __ballot(ok);
    if (ok) gl[ng + (int)__popcll(mask & ((1ull << lane) - 1ull))] = g;
    ng += (int)__popcll(mask);
  }

  const int total = ng * GS;
  #pragma unroll 1
  for (int cs = 0; cs < total; cs += 64) {
    int ci = cs + lane;
    if (ci < total) {
      int gg = gl[ci / GS];
      int j  = ci % GS;
      int jloc = gg * GS + j;
      float x = base[jloc * 3 + 0], y = base[jloc * 3 + 1], z = base[jloc * 3 + 2];
      tile[lane] = make_float4(x, y, z, x * x + y * y + z * z);
      tilei[lane] = jloc;
    }
    int nj = min(64, total - cs);
    #pragma unroll 1
    for (int jj = 0; jj < nj; ++jj) {
      float4 tt = tile[jj];
      int ti0 = tilei[jj];
      float d2 = sqi + tt.w - 2.0f * (qx * tt.x + qy * tt.y + qz * tt.z);
      if (owner && d2 < bd[KNN - 1]) {
        bd[KNN - 1] = d2; bi[KNN - 1] = ti0;
        #pragma unroll
        for (int u = KNN - 1; u > 0; --u) {
          if (bd[u] < bd[u - 1]) {
            float td = bd[u]; bd[u] = bd[u - 1]; bd[u - 1] = td;
            int   ti = bi[u]; bi[u] = bi[u - 1]; bi[u - 1] = ti;
          }
        }
      }
    }
  }

  if (owner) {
    int gid = b * Npg + qloc;
    #pragma unroll
    for (int u = 0; u < KNN; ++u) idx_out[gid * KNN + u] = b * Npg + bi[u];
  }
}

// ---------------------------------------------------------------------------
// Wave-per-QUERY kNN for stage-3 PRED points (the heavy overlapping blob).
// Lane-partitioned candidate scan (independent loads, pipelined) + wave merge.
// Exact: threshold t = 8th-best within own group; point-vs-sphere pruning with
// inflation; excluded points have d2 >= t >= final bd[7] (strict-< immune).
__device__ __forceinline__ void knn3_pred_wave(
    const float* __restrict__ xyz_all, const float* __restrict__ ctx_xyz,
    const float* __restrict__ anchor, const int* __restrict__ radmax,
    int b, int q, int lane, int* gl, int* __restrict__ idx_out) {
  const float* base = xyz_all + (size_t)b * NALL * 3;
  const float* cxb  = ctx_xyz + (size_t)b * P_ * 3;
  const int qloc = NCTX + q;
  const int p = NG1 + q / GS;

  const float qx = base[qloc * 3 + 0], qy = base[qloc * 3 + 1], qz = base[qloc * 3 + 2];
  const float sqi = qx * qx + qy * qy + qz * qz;

  // phase 1: own group, one candidate per lane (lanes 0..11)
  float dcur = 3e38f;
  int   icur = 0x7fffffff;
  if (lane < GS) {
    int jloc = p * GS + lane;
    if (jloc != qloc) {
      float x = base[jloc * 3 + 0], y = base[jloc * 3 + 1], z = base[jloc * 3 + 2];
      dcur = sqi + (x * x + y * y + z * z) - 2.0f * (qx * x + qy * y + qz * z);
      icur = jloc;
    }
  }
  // t = 8th smallest via 8 rounds of wave pop-min
  float t = 3e38f;
  #pragma unroll 1
  for (int r8 = 0; r8 < KNN; ++r8) {
    float d = dcur; int i = icur;
    #pragma unroll
    for (int mm = 1; mm < 64; mm <<= 1) {
      float od = __shfl_xor(d, mm);
      int   oi = __shfl_xor(i, mm);
      if (od < d || (od == d && oi < i)) { d = od; i = oi; }
    }
    t = d;
    if (icur == i) { dcur = 3e38f; icur = 0x7fffffff; }
  }
  float r = sqrtf(fmaxf(t, 0.f)) * 1.001f + 1e-6f;

  // phase 2: ballot-compact groups whose sphere intersects ball(q, r).
  // Own group included (always passes); self candidate skipped in phase 3.
  int ng = 0;
  #pragma unroll 1
  for (int gs0 = 0; gs0 < NG3; gs0 += 64) {
    int g = gs0 + lane;
    bool ok = false;
    if (g < NG3) {
      float cx, cy, cz, rad;
      float moff = __int_as_float(radmax[b * NG3 + g]) * 1.0002f + 1e-6f;
      if (g < NG1) {
        cx = cxb[g * 3 + 0]; cy = cxb[g * 3 + 1]; cz = cxb[g * 3 + 2];
        rad = 0.0201f + moff;
      } else {
        cx = anchor[b * 3 + 0]; cy = anchor[b * 3 + 1]; cz = anchor[b * 3 + 2];
        rad = 0.0501f + moff;
      }
      float dx = cx - qx, dy = cy - qy, dz = cz - qz;
      float lim = r + rad;
      ok = (dx * dx + dy * dy + dz * dz) < lim * lim * 1.001f;
    }
    unsigned long long mask = __ballot(ok);
    if (ok) gl[ng + (int)__popcll(mask & ((1ull << lane) - 1ull))] = g;
    ng += (int)__popcll(mask);
  }

  // phase 3: lane-partitioned scan, per-lane top-8 (ascending jloc per lane).
  float bd[KNN];
  int   bi[KNN];
  #pragma unroll
  for (int u = 0; u < KNN; ++u) { bd[u] = 3e38f; bi[u] = 0x7fffffff; }
  const int total = ng * GS;
  #pragma unroll 2
  for (int ci = lane; ci < total; ci += 64) {
    int gg = gl[ci / GS];
    int j  = ci % GS;
    int jloc = gg * GS + j;
    float x = base[jloc * 3 + 0], y = base[jloc * 3 + 1], z = base[jloc * 3 + 2];
    float d2 = sqi + (x * x + y * y + z * z) - 2.0f * (qx * x + qy * y + qz * z);
    if (jloc != qloc && d2 < bd[KNN - 1]) {
      bd[KNN - 1] = d2; bi[KNN - 1] = jloc;
      #pragma unroll
      for (int u = KNN - 1; u > 0; --u) {
        if (bd[u] < bd[u - 1]) {
          float td = bd[u]; bd[u] = bd[u - 1]; bd[u - 1] = td;
          int   ti = bi[u]; bi[u] = bi[u - 1]; bi[u - 1] = ti;
        }
      }
    }
  }

  // merge: 8 rounds of wave pop-min, tie-break smaller idx (stable).
  const int gid = b * NALL + qloc;
  #pragma unroll 1
  for (int r8 = 0; r8 < KNN; ++r8) {
    float d = bd[0]; int i = bi[0];
    #pragma unroll
    for (int mm = 1; mm < 64; mm <<= 1) {
      float od = __shfl_xor(d, mm);
      int   oi = __shfl_xor(i, mm);
      if (od < d || (od == d && oi < i)) { d = od; i = oi; }
    }
    if (lane == 0) idx_out[gid * KNN + r8] = b * NALL + i;
    if (bi[0] == i) {
      #pragma unroll
      for (int u = 0; u < KNN - 1; ++u) { bd[u] = bd[u + 1]; bi[u] = bi[u + 1]; }
      bd[KNN - 1] = 3e38f; bi[KNN - 1] = 0x7fffffff;
    }
  }
}

// ---------------------------------------------------------------------------
// FUSED: stage-1 AB assembly + stage-1 kNN (ctx groups only).
__global__ __launch_bounds__(256) void ab12_knn1_kernel(
    const float* __restrict__ T, const float* __restrict__ xyz_all,
    const float* __restrict__ Wcat, const float* __restrict__ cb,
    const float* __restrict__ ctx_xyz,
    float* __restrict__ AB, int* __restrict__ idx1) {
  __shared__ float4 own[4][GS];
  __shared__ int    gl[4][NG1];
  __shared__ float4 tile[4][64];
  __shared__ int    tilei[4][64];
  const int tid = threadIdx.x;
  if (blockIdx.x < AB1_BLOCKS) {
    const int base = blockIdx.x * 8;
    const float wx = Wcat[128 * 256 + tid];
    const float wy = Wcat[129 * 256 + tid];
    const float wz = Wcat[130 * 256 + tid];
    const float cbv = cb[tid];
    #pragma unroll
    for (int p = 0; p < 8; ++p) {
      int n = base + p;
      int b = n / NCTX, loc = n % NCTX;
      int trow = b * (NCTX / GS) + loc / GS;
      const float* xr = xyz_all + (size_t)(b * NALL + loc) * 3;
      float x = xr[0], y = xr[1], z = xr[2];
      float v = T[(size_t)trow * 256 + tid] + cbv;
      v = fmaf(x, wx, v);
      v = fmaf(y, wy, v);
      v = fmaf(z, wz, v);
      AB[(size_t)n * 256 + tid] = v;
    }
  } else {
    int kblk = blockIdx.x - AB1_BLOCKS;
    int w = tid >> 6, lane = tid & 63;
    int b = kblk / (NG1 / 4);
    int p = (kblk % (NG1 / 4)) * 4 + w;
    knn_wave_body<1>(xyz_all, ctx_xyz, nullptr, nullptr, b, p, lane,
                     own[w], gl[w], tile[w], tilei[w], idx1);
  }
}

// ---------------------------------------------------------------------------
// FUSED: stage-2 AB assembly + stage-2 small kNN.
__global__ __launch_bounds__(256) void ab12_knn2_kernel(
    const float* __restrict__ T, const float* __restrict__ xyz_all,
    const float* __restrict__ Wcat, const float* __restrict__ cb,
    float* __restrict__ AB, int* __restrict__ idx2) {
  const int tid = threadIdx.x;
  if (blockIdx.x < AB2_BLOCKS) {
    const int base = blockIdx.x * 8;
    const float wx = Wcat[128 * 256 + tid];
    const float wy = Wcat[129 * 256 + tid];
    const float wz = Wcat[130 * 256 + tid];
    const float cbv = cb[tid];
    #pragma unroll
    for (int p = 0; p < 8; ++p) {
      int n = base + p;
      int b = n / NPRD, loc = n % NPRD;
      int trow = B_ * P_ + b * (NPRD / GS) + loc / GS;
      const float* xr = xyz_all + (size_t)(b * NALL + NCTX + loc) * 3;
      float x = xr[0], y = xr[1], z = xr[2];
      float v = T[(size_t)trow * 256 + tid] + cbv;
      v = fmaf(x, wx, v);
      v = fmaf(y, wy, v);
      v = fmaf(z, wz, v);
      AB[(size_t)n * 256 + tid] = v;
    }
  } else {
    int q = (blockIdx.x - AB2_BLOCKS) * 256 + tid;
    int gr = q / RP, qi = q % RP;
    int b = gr / M_, w = gr % M_;
    const float* base = xyz_all + (size_t)(b * NALL + NCTX + w * RP) * 3;
    float cx[RP], cy[RP], cz[RP], cs[RP];
    #pragma unroll
    for (int j = 0; j < RP; ++j) {
      cx[j] = base[j * 3 + 0]; cy[j] = base[j * 3 + 1]; cz[j] = base[j * 3 + 2];
      cs[j] = cx[j] * cx[j] + cy[j] * cy[j] + cz[j] * cz[j];
    }
    float qx = cx[0], qy = cy[0], qz = cz[0], sqi = cs[0];
    #pragma unroll
    for (int j = 0; j < RP; ++j) {
      if (j == qi) { qx = cx[j]; qy = cy[j]; qz = cz[j]; sqi = cs[j]; }
    }
    float bd[KNN];
    int   bi[KNN];
    #pragma unroll
    for (int u = 0; u < KNN; ++u) { bd[u] = 3e38f; bi[u] = 0; }
    #pragma unroll
    for (int j = 0; j < RP; ++j) {
      float d2 = sqi + cs[j] - 2.0f * (qx * cx[j] + qy * cy[j] + qz * cz[j]);
      if (j != qi && d2 < bd[KNN - 1]) {
        bd[KNN - 1] = d2; bi[KNN - 1] = j;
        #pragma unroll
        for (int u = KNN - 1; u > 0; --u) {
          if (bd[u] < bd[u - 1]) {
            float td = bd[u]; bd[u] = bd[u - 1]; bd[u - 1] = td;
            int   ti = bi[u]; bi[u] = bi[u - 1]; bi[u - 1] = ti;
          }
        }
      }
    }
    #pragma unroll
    for (int u = 0; u < KNN; ++u) idx2[q * KNN + u] = gr * RP + bi[u];
  }
}

// ---------------------------------------------------------------------------
// FUSED: stage-3 precompute | ctx-group kNN | pred-query kNN.
__global__ __launch_bounds__(256) void pre3_knn3_kernel(
    const float* __restrict__ feat, const float* __restrict__ xyz_all,
    const float* __restrict__ Wcat, const float* __restrict__ be1,
    const float* __restrict__ ctx_xyz, const float* __restrict__ anchor,
    const int* __restrict__ radmax,
    float* __restrict__ AB, int* __restrict__ idx3) {
  __shared__ float x_lds[8][132];
  __shared__ float4 own[4][GS];
  __shared__ int    gl[4][NG3];
  __shared__ float4 tile[4][64];
  __shared__ int    tilei[4][64];
  const int tid = threadIdx.x;
  if (blockIdx.x < PRE3_BLOCKS) {
    const int base = blockIdx.x * 8;
    for (int l = tid; l < 8 * 131; l += 256) {
      int pt = l / 131, t = l % 131;
      int g = base + pt;
      int b = g / NALL, loc = g % NALL;
      float v;
      if (t < C) v = feat[(size_t)g * C + t];
      else       v = xyz_all[(size_t)(b * NALL + loc) * 3 + (t - C)];
      x_lds[pt][t] = v;
    }
    __syncthreads();
    float acc[8] = {0.f, 0.f, 0.f, 0.f, 0.f, 0.f, 0.f, 0.f};
    #pragma unroll 1
    for (int t = 0; t < 131; ++t) {
      float wv = Wcat[t * 256 + tid];
      #pragma unroll
      for (int p = 0; p < 8; ++p) acc[p] = fmaf(x_lds[p][t], wv, acc[p]);
    }
    float bias = (tid < C) ? be1[tid] : 0.0f;
    #pragma unroll
    for (int p = 0; p < 8; ++p) AB[(size_t)(base + p) * 256 + tid] = acc[p] + bias;
  } else if (blockIdx.x < PRE3_BLOCKS + KNN3C_BLOCKS) {
    int kblk = blockIdx.x - PRE3_BLOCKS;
    int w = tid >> 6, lane = tid & 63;
    int b = kblk / (NG1 / 4);
    int p = (kblk % (NG1 / 4)) * 4 + w;     // ctx groups only: p < NG1
    knn_wave_body<3>(xyz_all, ctx_xyz, anchor, radmax, b, p, lane,
                     own[w], gl[w], tile[w], tilei[w], idx3);
  } else {
    int kblk = blockIdx.x - PRE3_BLOCKS - KNN3C_BLOCKS;
    int w = tid >> 6, lane = tid & 63;
    int wid = kblk * 4 + w;                  // 0 .. B*NPRD-1
    int b = wid / NPRD, q = wid % NPRD;
    knn3_pred_wave(xyz_all, ctx_xyz, anchor, radmax, b, q, lane, gl[w], idx3);
  }
}

// ---------------------------------------------------------------------------
// MFMA EdgeConv core (split-bf16, 3 MFMAs, ~2^-16 err).
__global__ __launch_bounds__(256) void conv_mfma_kernel(const float* __restrict__ AB,
                                                        const int* __restrict__ idx,
                                                        const unsigned short* __restrict__ w2hi_g,
                                                        const unsigned short* __restrict__ w2lo_g,
                                                        const float* __restrict__ be2,
                                                        float* __restrict__ feat_out,
                                                        int NPB, int row_off) {
  __shared__ unsigned short hhi[64 * 128];    // 16 KB
  __shared__ unsigned short hlo[64 * 128];    // 16 KB
  __shared__ unsigned short w2hi[128 * 128];  // 32 KB
  const int tid = threadIdx.x;
  const int base = blockIdx.x * 8;

  #pragma unroll
  for (int i = 0; i < 8; ++i) {
    int q = tid + 256 * i;
    int n = q >> 4, c = q & 15;
    f32x4 v = *(const f32x4*)(w2hi_g + n * 128 + c * 8);
    *(f32x4*)(w2hi + (n * 16 + (c ^ (n & 15))) * 8) = v;
  }

  #pragma unroll
  for (int i = 0; i < 4; ++i) {
    int task = tid + 256 * i;
    int r = task >> 4, c = task & 15;
    int p = r >> 3, nb = r & 7;
    int g = base + p;
    int j = idx[g * KNN + nb];
    const float* aP = AB + (size_t)g * 256 + c * 8;
    const float* bP = AB + (size_t)j * 256 + 128 + c * 8;
    f32x4 a0 = *(const f32x4*)aP;
    f32x4 a1 = *(const f32x4*)(aP + 4);
    f32x4 b0 = *(const f32x4*)bP;
    f32x4 b1 = *(const f32x4*)(bP + 4);
    float hv[8] = {a0.x + b0.x, a0.y + b0.y, a0.z + b0.z, a0.w + b0.w,
                   a1.x + b1.x, a1.y + b1.y, a1.z + b1.z, a1.w + b1.w};
    union { unsigned short s[8]; f32x4 v; } oh, ol;
    #pragma unroll
    for (int e = 0; e < 8; ++e) {
      float h = fmaxf(hv[e], 0.0f);
      unsigned short x = f32_to_bf16_rne(h);
      oh.s[e] = x;
      ol.s[e] = f32_to_bf16_rne(h - bf16_to_f32(x));
    }
    int dst = (r * 16 + (c ^ (r & 15))) * 8;
    *(f32x4*)(hhi + dst) = oh.v;
    *(f32x4*)(hlo + dst) = ol.v;
  }
  __syncthreads();

  const int lane = tid & 63, w = tid >> 6;
  const int m = lane & 15, quad = lane >> 4;
  f32x4 acc[8];
  #pragma unroll
  for (int nt = 0; nt < 8; ++nt) acc[nt] = (f32x4){0.f, 0.f, 0.f, 0.f};

  #pragma unroll 1
  for (int ks = 0; ks < 4; ++ks) {
    int c0 = ks * 4 + quad;
    int rowA = w * 16 + m;
    int aoff = (rowA * 16 + (c0 ^ m)) * 8;
    bf16x8 ahi = *(const bf16x8*)(hhi + aoff);
    bf16x8 alo = *(const bf16x8*)(hlo + aoff);
    #pragma unroll
    for (int nt = 0; nt < 8; ++nt) {
      int n = nt * 16 + m;
      bf16x8 bhi = *(const bf16x8*)(w2hi + (n * 16 + (c0 ^ m)) * 8);
      bf16x8 blo = *(const bf16x8*)(w2lo_g + n * 128 + c0 * 8);
      acc[nt] = __builtin_amdgcn_mfma_f32_16x16x32_bf16(ahi, bhi, acc[nt], 0, 0, 0);
      acc[nt] = __builtin_amdgcn_mfma_f32_16x16x32_bf16(ahi, blo, acc[nt], 0, 0, 0);
      acc[nt] = __builtin_amdgcn_mfma_f32_16x16x32_bf16(alo, bhi, acc[nt], 0, 0, 0);
    }
  }

  int pt = 2 * w + (quad >> 1);
  int g = base + pt;
  int b = g / NPB, loc = g % NPB;
  float* orow = feat_out + (size_t)(b * NALL + row_off + loc) * C;
  bool writer = (quad & 1) == 0;
  #pragma unroll
  for (int nt = 0; nt < 8; ++nt) {
    float v = fmaxf(fmaxf(acc[nt].x, acc[nt].y), fmaxf(acc[nt].z, acc[nt].w));
    v = fmaxf(v, __shfl_xor(v, 16));
    if (writer) {
      int col = nt * 16 + m;
      orow[col] = v + be2[col];
    }
  }
}

// ---------------------------------------------------------------------------
// offset MLP: out_row = xyz_in_row + (relu(f@W1+b1) @ W2 + b2).
// Optionally accumulates per-group max |offset| into radmax (for knn3 bounds).
__global__ __launch_bounds__(256) void offset_kernel(const float* __restrict__ feat,
                                                     const float* __restrict__ W1,
                                                     const float* __restrict__ b1,
                                                     const float* __restrict__ W2,
                                                     const float* __restrict__ b2,
                                                     const float* __restrict__ xyz_in,
                                                     float* __restrict__ xyz_out,
                                                     int NPB, int row_off,
                                                     int* __restrict__ radmax) {
  __shared__ float w1c[64 * C];
  __shared__ float f_lds[16][C];
  __shared__ float wred[4][3];
  const int tid = threadIdx.x;
  const int base = blockIdx.x * 16;
  const int p = tid >> 7;
  const int cc = tid & 127;
  const int wave = tid >> 6, lane = tid & 63;

  for (int l = tid; l < 16 * C; l += 256) {
    int pt = l >> 7, t = l & 127;
    int g = base + pt;
    int b = g / NPB, loc = g % NPB;
    f_lds[pt][t] = feat[(size_t)(b * NALL + row_off + loc) * C + t];
  }

  float s[8];
  #pragma unroll
  for (int pp = 0; pp < 8; ++pp) s[pp] = 0.f;

  for (int kk = 0; kk < 2; ++kk) {
    __syncthreads();
    for (int l = tid * 4; l < 64 * C; l += 1024)
      *(float4*)&w1c[l] = *(const float4*)&W1[kk * 64 * C + l];
    __syncthreads();
    #pragma unroll
    for (int pp = 0; pp < 8; ++pp) {
      const float* f = &f_lds[pp * 2 + p][kk * 64];
      float acc = s[pp];
      #pragma unroll 4
      for (int t = 0; t < 64; ++t) acc = fmaf(f[t], w1c[t * C + cc], acc);
      s[pp] = acc;
    }
  }

  float b1v = b1[cc];
  float w20 = W2[cc * 3 + 0], w21 = W2[cc * 3 + 1], w22 = W2[cc * 3 + 2];
  float b20 = b2[0], b21 = b2[1], b22 = b2[2];

  #pragma unroll 1
  for (int pp = 0; pp < 8; ++pp) {
    float h = fmaxf(s[pp] + b1v, 0.0f);
    float p0 = h * w20, p1 = h * w21, p2 = h * w22;
    for (int o = 32; o > 0; o >>= 1) {
      p0 += __shfl_down(p0, o);
      p1 += __shfl_down(p1, o);
      p2 += __shfl_down(p2, o);
    }
    if (lane == 0) { wred[wave][0] = p0; wred[wave][1] = p1; wred[wave][2] = p2; }
    __syncthreads();
    if (tid < 2) {
      int g = base + pp * 2 + tid;
      int b = g / NPB, loc = g % NPB;
      int row = (b * NALL + row_off + loc) * 3;
      float o0 = wred[tid * 2][0] + wred[tid * 2 + 1][0] + b20;
      float o1 = wred[tid * 2][1] + wred[tid * 2 + 1][1] + b21;
      float o2 = wred[tid * 2][2] + wred[tid * 2 + 1][2] + b22;
      xyz_out[row + 0] = xyz_in[row + 0] + o0;
      xyz_out[row + 1] = xyz_in[row + 1] + o1;
      xyz_out[row + 2] = xyz_in[row + 2] + o2;
      if (radmax != nullptr) {
        float mag = sqrtf(o0 * o0 + o1 * o1 + o2 * o2);
        atomicMax(radmax + b * NG3 + (row_off + loc) / GS, __float_as_int(mag));
      }
    }
    __syncthreads();
  }
}

// ---------------------------------------------------------------------------
extern "C" void kernel_launch(void* const* d_in, const int* in_sizes, int n_in,
                              void* d_out, int out_size, void* d_ws, size_t ws_size,
                              hipStream_t stream) {
  (void)in_sizes; (void)n_in; (void)out_size; (void)ws_size;
  const float* ctx_xyz   = (const float*)d_in[0];
  const float* ctx_tok   = (const float*)d_in[1];
  const float* pred_tok  = (const float*)d_in[2];
  const float* noise_ctx = (const float*)d_in[3];
  const float* noise_prd = (const float*)d_in[4];
  const float* Wp  = (const float*)d_in[5];
  const float* bp  = (const float*)d_in[6];
  const float* We1 = (const float*)d_in[7];
  const float* be1 = (const float*)d_in[8];
  const float* We2 = (const float*)d_in[9];
  const float* be2 = (const float*)d_in[10];
  const float* Wc1 = (const float*)d_in[11];
  const float* bc1 = (const float*)d_in[12];
  const float* Wc2 = (const float*)d_in[13];
  const float* bc2 = (const float*)d_in[14];
  const float* Wq1 = (const float*)d_in[15];
  const float* bq1 = (const float*)d_in[16];
  const float* Wq2 = (const float*)d_in[17];
  const float* bq2 = (const float*)d_in[18];
  const float* Wf1 = (const float*)d_in[19];
  const float* bf1 = (const float*)d_in[20];
  const float* Wf2 = (const float*)d_in[21];
  const float* bf2 = (const float*)d_in[22];
  float* out = (float*)d_out;

  // workspace layout (floats)
  float* ws        = (float*)d_ws;
  float* T         = ws;                          // 1792*256    = 458752
  float* anchor    = T + TROWS * 256;             // 16
  float* xyz_all   = anchor + 16;                 // B*NALL*3    = 64512
  float* feat_in   = xyz_all + B_ * NALL * 3;     // B*NALL*C    = 2752512
  float* feat_out  = feat_in + B_ * NALL * C;     // B*NALL*C    = 2752512
  float* AB        = feat_out + B_ * NALL * C;    // B*NALL*256  = 5505024
  float* Wcat      = AB + B_ * NALL * 256;        // 131*256     = 33536
  float* cb        = Wcat + 131 * 256;            // 256
  int*   idx1      = (int*)(cb + 256);            // B*NCTX*8    = 147456
  int*   idx2      = idx1 + B_ * NCTX * KNN;      // B*NPRD*8    = 24576
  int*   idx3      = idx2 + B_ * NPRD * KNN;      // B*NALL*8    = 172032
  unsigned short* we2hi = (unsigned short*)(idx3 + B_ * NALL * KNN); // 16384
  unsigned short* we2lo = we2hi + C * C;                             // 16384
  int*   radmax    = (int*)(we2lo + C * C);       // B*NG3       = 1792 ints
  // wbT aliases AB: fully consumed by t12_mfma before the first AB write.
  unsigned short* wbT_hi = (unsigned short*)AB;   // 256*1024 ushorts
  unsigned short* wbT_lo = wbT_hi + 256 * TOK;    // 256*1024 ushorts

  // prep (fused)
  prep1_kernel<<<196, 256, 0, stream>>>(We1, We2, ctx_xyz, Wcat, we2hi, we2lo, anchor);
  prep2_kernel<<<TOK / 4 + 1, 256, 0, stream>>>(Wp, bp, Wcat, be1, wbT_hi, wbT_lo, cb);
  build_all_kernel<<<72 + 12, 256, 0, stream>>>(ctx_xyz, noise_ctx, noise_prd, anchor,
                                                xyz_all, radmax);

  // token GEMM: T = [ctx_tok; pred_tok] @ Wbig  (1792 x 256, K=1024)
  t12_mfma_kernel<<<dim3(TROWS / 64, 2), 256, 0, stream>>>(ctx_tok, pred_tok, wbT_hi, wbT_lo, T);

  // ---- stage 1: context branch ----
  ab12_knn1_kernel<<<AB1_BLOCKS + KNN1_BLOCKS, 256, 0, stream>>>(T, xyz_all, Wcat, cb,
                                                                 ctx_xyz, AB, idx1);
  conv_mfma_kernel<<<(B_ * NCTX) / 8, 256, 0, stream>>>(AB, idx1, we2hi, we2lo, be2, feat_in, NCTX, 0);
  offset_kernel<<<(B_ * NCTX) / 16, 256, 0, stream>>>(feat_in, Wc1, bc1, Wc2, bc2,
                                                      xyz_all, xyz_all, NCTX, 0, radmax);

  // ---- stage 2: prediction branch ----
  ab12_knn2_kernel<<<AB2_BLOCKS + KNS_BLOCKS, 256, 0, stream>>>(T, xyz_all, Wcat, cb, AB, idx2);
  conv_mfma_kernel<<<(B_ * NPRD) / 8, 256, 0, stream>>>(AB, idx2, we2hi, we2lo, be2, feat_in, NPRD, NCTX);
  offset_kernel<<<(B_ * NPRD) / 16, 256, 0, stream>>>(feat_in, Wq1, bq1, Wq2, bq2,
                                                      xyz_all, xyz_all, NPRD, NCTX, radmax);

  // ---- stage 3: global refinement ----
  pre3_knn3_kernel<<<PRE3_BLOCKS + KNN3C_BLOCKS + KNN3P_BLOCKS, 256, 0, stream>>>(
      feat_in, xyz_all, Wcat, be1, ctx_xyz, anchor, radmax, AB, idx3);
  conv_mfma_kernel<<<(B_ * NALL) / 8, 256, 0, stream>>>(AB, idx3, we2hi, we2lo, be2, feat_out, NALL, 0);
  offset_kernel<<<(B_ * NALL) / 16, 256, 0, stream>>>(feat_out, Wf1, bf1, Wf2, bf2,
                                                      xyz_all, out, NALL, 0, nullptr);
}

// Round 9
// 496.955 us; speedup vs baseline: 3.5305x; 1.1249x over previous
//
#include <hip/hip_runtime.h>
#include <math.h>

// Problem constants (from setup_inputs; k==8 is fixed by the harness inputs).
constexpr int B_   = 4;
constexpr int P_   = 384;
constexpr int M_   = 64;
constexpr int TOK  = 1024;
constexpr int C    = 128;
constexpr int RC   = 12;
constexpr int RP   = 12;
constexpr int KNN  = 8;
constexpr int GS   = 12;           // group size (both ctx clusters and pred rings)
constexpr int NCTX = P_ * RC;      // 4608 ctx points per batch
constexpr int NPRD = M_ * RP;      // 768 pred points per batch
constexpr int NALL = NCTX + NPRD;  // 5376
constexpr int NG1  = NCTX / GS;    // 384 groups, stage 1
constexpr int NG3  = NALL / GS;    // 448 groups, stage 3
constexpr int TROWS = B_ * P_ + B_ * M_;  // 1792 token rows (ctx then pred)
constexpr int KSPLIT = 4;          // t12 split-K factor

// fused-grid split points
constexpr int AB1_BLOCKS   = (B_ * NCTX) / 8;      // 2304
constexpr int KNN1_BLOCKS  = B_ * (NG1 / 4);       // 384
constexpr int AB2_BLOCKS   = (B_ * NPRD) / 8;      // 384
constexpr int KNS_BLOCKS   = (B_ * M_ * RP) / 256; // 12
constexpr int PRE3_BLOCKS  = (B_ * NALL) / 8;      // 2688
constexpr int KNN3C_BLOCKS = B_ * (NG1 / 4);       // 384 (ctx groups, wave-per-group)
constexpr int KNN3P_BLOCKS = (B_ * NPRD) / 4;      // 768 (pred queries, wave-per-query)

typedef __attribute__((ext_vector_type(8))) short bf16x8;
typedef __attribute__((ext_vector_type(4))) float f32x4;

__device__ inline unsigned short f32_to_bf16_rne(float x) {
  union { float f; unsigned int u; } v; v.f = x;
  unsigned int r = v.u + 0x7fffu + ((v.u >> 16) & 1u);
  return (unsigned short)(r >> 16);
}
__device__ inline float bf16_to_f32(unsigned short h) {
  union { float f; unsigned int u; } v; v.u = ((unsigned int)h) << 16;
  return v.f;
}

// ---------------------------------------------------------------------------
// FUSED prep1: Wcat build | We2 transpose | anchor.
__global__ __launch_bounds__(256) void prep1_kernel(const float* __restrict__ We1,
                                                    const float* __restrict__ We2,
                                                    const float* __restrict__ cxyz,
                                                    float* __restrict__ Wcat,
                                                    unsigned short* __restrict__ we2hi,
                                                    unsigned short* __restrict__ we2lo,
                                                    float* __restrict__ anchor) {
  const int tid = threadIdx.x;
  if (blockIdx.x < 131) {
    int n = blockIdx.x * 256 + tid;
    int t = n >> 8, cc = n & 255;
    float v;
    if (cc < C) v = We1[t * C + cc] - We1[(131 + t) * C + cc];
    else        v = We1[(131 + t) * C + (cc - C)];
    Wcat[n] = v;
  } else if (blockIdx.x < 195) {
    int e = (blockIdx.x - 131) * 256 + tid;
    int n = e >> 7, k = e & 127;
    float w = We2[k * C + n];
    unsigned short h = f32_to_bf16_rne(w);
    we2hi[n * C + k] = h;
    we2lo[n * C + k] = f32_to_bf16_rne(w - bf16_to_f32(h));
  } else {
    const int w = tid >> 6, lane = tid & 63;
    float ax = 0.f, ay = 0.f, az = 0.f;
    for (int p = lane; p < P_; p += 64) {
      const float* c = &cxyz[(w * P_ + p) * 3];
      ax += c[0]; ay += c[1]; az += c[2];
    }
    for (int o = 32; o > 0; o >>= 1) {
      ax += __shfl_down(ax, o);
      ay += __shfl_down(ay, o);
      az += __shfl_down(az, o);
    }
    if (lane == 0) {
      anchor[w * 3 + 0] = ax * (1.0f / (float)P_);
      anchor[w * 3 + 1] = ay * (1.0f / (float)P_);
      anchor[w * 3 + 2] = az * (1.0f / (float)P_);
    }
  }
}

// ---------------------------------------------------------------------------
// FUSED prep2: WbigT = (Wp @ Wcat_feat)^T bf16 hi/lo | cb vector.
__global__ __launch_bounds__(256) void prep2_kernel(const float* __restrict__ Wp,
                                                    const float* __restrict__ bp,
                                                    const float* __restrict__ Wcat,
                                                    const float* __restrict__ be1,
                                                    unsigned short* __restrict__ wbT_hi,
                                                    unsigned short* __restrict__ wbT_lo,
                                                    float* __restrict__ cb) {
  __shared__ float s_lds[4][128];
  const int tid = threadIdx.x;
  if (blockIdx.x < TOK / 4) {
    const int k0 = blockIdx.x * 4;
    for (int l = tid; l < 4 * 128; l += 256) {
      int r = l >> 7, f = l & 127;
      s_lds[r][f] = Wp[(k0 + r) * C + f];
    }
    __syncthreads();
    float acc[4] = {0.f, 0.f, 0.f, 0.f};
    #pragma unroll 4
    for (int f = 0; f < 128; ++f) {
      float wv = Wcat[f * 256 + tid];
      #pragma unroll
      for (int r = 0; r < 4; ++r) acc[r] = fmaf(s_lds[r][f], wv, acc[r]);
    }
    #pragma unroll
    for (int r = 0; r < 4; ++r) {
      unsigned short h = f32_to_bf16_rne(acc[r]);
      wbT_hi[(size_t)tid * TOK + k0 + r] = h;
      wbT_lo[(size_t)tid * TOK + k0 + r] = f32_to_bf16_rne(acc[r] - bf16_to_f32(h));
    }
  } else {
    if (tid < 128) s_lds[0][tid] = bp[tid];
    __syncthreads();
    float a = (tid < 128) ? be1[tid] : 0.f;
    #pragma unroll 4
    for (int f = 0; f < 128; ++f) a = fmaf(s_lds[0][f], Wcat[f * 256 + tid], a);
    cb[tid] = a;
  }
}

// ---------------------------------------------------------------------------
// FUSED geometry build: ctx points (+radmax zero-init) | pred points.
__global__ __launch_bounds__(256) void build_all_kernel(const float* __restrict__ cxyz,
                                                        const float* __restrict__ noise_c,
                                                        const float* __restrict__ noise_p,
                                                        const float* __restrict__ anchor,
                                                        float* __restrict__ xyz_all,
                                                        int* __restrict__ radmax) {
  if (blockIdx.x < 72) {
    int n = blockIdx.x * 256 + threadIdx.x;
    if (n < B_ * NG3) radmax[n] = 0;      // float 0.0 bits
    int b = n / NCTX, i = n % NCTX, p = i / RC;
    float x = noise_c[n * 3 + 0], y = noise_c[n * 3 + 1], z = noise_c[n * 3 + 2];
    float s = 0.02f / (sqrtf(x * x + y * y + z * z) + 1e-6f);
    const float* c = &cxyz[(b * P_ + p) * 3];
    float* o = &xyz_all[(b * NALL + i) * 3];
    o[0] = c[0] + x * s;
    o[1] = c[1] + y * s;
    o[2] = c[2] + z * s;
  } else {
    int n = (blockIdx.x - 72) * 256 + threadIdx.x;
    int b = n / NPRD, i = n % NPRD;
    float x = noise_p[n * 3 + 0], y = noise_p[n * 3 + 1], z = noise_p[n * 3 + 2];
    float s = 0.05f / (sqrtf(x * x + y * y + z * z) + 1e-6f);
    const float* a = &anchor[b * 3];
    float* o = &xyz_all[(b * NALL + NCTX + i) * 3];
    o[0] = a[0] + x * s;
    o[1] = a[1] + y * s;
    o[2] = a[2] + z * s;
  }
}

// ---------------------------------------------------------------------------
// Tpart[s][row][c] = tok[row] @ Wbig[kslice s]. Split-bf16 MFMA GEMM, split-K.
// Grid (TROWS/64, 2, KSPLIT): 224 blocks (was 56) and 2 serial K-chunks per
// block (was 8) -> latency-bound chain cut 4x, CU coverage 22% -> 88%.
__global__ __launch_bounds__(256) void t12_mfma_kernel(const float* __restrict__ ctx_tok,
                                                       const float* __restrict__ pred_tok,
                                                       const unsigned short* __restrict__ wbT_hi,
                                                       const unsigned short* __restrict__ wbT_lo,
                                                       float* __restrict__ Tpart) {
  __shared__ unsigned short ahi[64 * 128];   // 16 KB
  __shared__ unsigned short alo[64 * 128];   // 16 KB
  __shared__ unsigned short bhi[128 * 128];  // 32 KB
  const int tid = threadIdx.x;
  const int r0 = blockIdx.x * 64;
  const int n0 = blockIdx.y * 128;
  const int s  = blockIdx.z;
  const float* src = (r0 < B_ * P_) ? (ctx_tok + (size_t)r0 * TOK)
                                    : (pred_tok + (size_t)(r0 - B_ * P_) * TOK);
  const int lane = tid & 63, w = tid >> 6;
  const int m = lane & 15, quad = lane >> 4;

  f32x4 acc[8];
  #pragma unroll
  for (int nt = 0; nt < 8; ++nt) acc[nt] = (f32x4){0.f, 0.f, 0.f, 0.f};

  #pragma unroll 1
  for (int kc = s * (8 / KSPLIT); kc < (s + 1) * (8 / KSPLIT); ++kc) {
    __syncthreads();
    #pragma unroll
    for (int i = 0; i < 4; ++i) {
      int task = tid + 256 * i;           // 0..1023
      int r = task >> 4, c = task & 15;
      const float* sp = src + (size_t)r * TOK + kc * 128 + c * 8;
      f32x4 a0 = *(const f32x4*)sp;
      f32x4 a1 = *(const f32x4*)(sp + 4);
      float vals[8] = {a0.x, a0.y, a0.z, a0.w, a1.x, a1.y, a1.z, a1.w};
      union { unsigned short s2[8]; f32x4 v; } oh, ol;
      #pragma unroll
      for (int e = 0; e < 8; ++e) {
        unsigned short h = f32_to_bf16_rne(vals[e]);
        oh.s2[e] = h;
        ol.s2[e] = f32_to_bf16_rne(vals[e] - bf16_to_f32(h));
      }
      int dst = (r * 16 + (c ^ (r & 15))) * 8;
      *(f32x4*)(ahi + dst) = oh.v;
      *(f32x4*)(alo + dst) = ol.v;
    }
    #pragma unroll
    for (int i = 0; i < 8; ++i) {
      int task = tid + 256 * i;           // 0..2047
      int n = task >> 4, c = task & 15;
      f32x4 v = *(const f32x4*)(wbT_hi + (size_t)(n0 + n) * TOK + kc * 128 + c * 8);
      *(f32x4*)(bhi + (n * 16 + (c ^ (n & 15))) * 8) = v;
    }
    __syncthreads();
    #pragma unroll
    for (int ks = 0; ks < 4; ++ks) {
      int c0 = ks * 4 + quad;
      int aoff = ((w * 16 + m) * 16 + (c0 ^ m)) * 8;
      bf16x8 av  = *(const bf16x8*)(ahi + aoff);
      bf16x8 av2 = *(const bf16x8*)(alo + aoff);
      #pragma unroll
      for (int nt = 0; nt < 8; ++nt) {
        int n = nt * 16 + m;
        bf16x8 bh = *(const bf16x8*)(bhi + (n * 16 + (c0 ^ m)) * 8);
        bf16x8 bl = *(const bf16x8*)(wbT_lo + (size_t)(n0 + n) * TOK + kc * 128 + c0 * 8);
        acc[nt] = __builtin_amdgcn_mfma_f32_16x16x32_bf16(av, bh, acc[nt], 0, 0, 0);
        acc[nt] = __builtin_amdgcn_mfma_f32_16x16x32_bf16(av, bl, acc[nt], 0, 0, 0);
        acc[nt] = __builtin_amdgcn_mfma_f32_16x16x32_bf16(av2, bh, acc[nt], 0, 0, 0);
      }
    }
  }
  #pragma unroll
  for (int nt = 0; nt < 8; ++nt) {
    int col = n0 + nt * 16 + m;
    #pragma unroll
    for (int reg = 0; reg < 4; ++reg) {
      int row = r0 + w * 16 + quad * 4 + reg;
      Tpart[((size_t)s * TROWS + row) * 256 + col] = acc[nt][reg];
    }
  }
}

// ---------------------------------------------------------------------------
// Wave-per-group kNN body for CTX groups (light: phase-3 list nearly empty).
template <int STAGE>
__device__ __forceinline__ void knn_wave_body(
    const float* __restrict__ xyz_all, const float* __restrict__ ctx_xyz,
    const float* __restrict__ anchor, const int* __restrict__ radmax,
    int b, int p, int lane,
    float4* own, int* gl, float4* tile, int* tilei,
    int* __restrict__ idx_out) {
  const int NG  = (STAGE == 1) ? NG1 : NG3;
  const int Npg = (STAGE == 1) ? NCTX : NALL;
  const float* base = xyz_all + (size_t)b * NALL * 3;
  const float* cxb  = ctx_xyz + (size_t)b * P_ * 3;
  const bool owner = lane < GS;
  const int qloc = p * GS + lane;

  auto sph = [&](int g) -> float4 {
    float4 c;
    float rad;
    if (STAGE == 1) {
      c = make_float4(cxb[g * 3 + 0], cxb[g * 3 + 1], cxb[g * 3 + 2], 0.f);
      rad = 0.0201f;
    } else {
      float moff = __int_as_float(radmax[b * NG3 + g]);
      if (g < NG1) {
        c = make_float4(cxb[g * 3 + 0], cxb[g * 3 + 1], cxb[g * 3 + 2], 0.f);
        rad = 0.0201f + moff * 1.0002f + 1e-6f;
      } else {
        c = make_float4(anchor[b * 3 + 0], anchor[b * 3 + 1], anchor[b * 3 + 2], 0.f);
        rad = 0.0501f + moff * 1.0002f + 1e-6f;
      }
    }
    c.w = rad;
    return c;
  };

  if (owner) {
    float x = base[qloc * 3 + 0], y = base[qloc * 3 + 1], z = base[qloc * 3 + 2];
    own[lane] = make_float4(x, y, z, x * x + y * y + z * z);
  }
  float qx = 0.f, qy = 0.f, qz = 0.f, sqi = 0.f;
  if (owner) {
    float4 q = own[lane];
    qx = q.x; qy = q.y; qz = q.z; sqi = q.w;
  }

  float bd[KNN];
  int   bi[KNN];
  #pragma unroll
  for (int u = 0; u < KNN; ++u) { bd[u] = 3e38f; bi[u] = 0x7fffffff; }

  #pragma unroll 1
  for (int j = 0; j < GS; ++j) {
    float4 cj = own[j];
    float d2 = sqi + cj.w - 2.0f * (qx * cj.x + qy * cj.y + qz * cj.z);
    if (owner && j != lane && d2 < bd[KNN - 1]) {
      bd[KNN - 1] = d2; bi[KNN - 1] = p * GS + j;
      #pragma unroll
      for (int u = KNN - 1; u > 0; --u) {
        if (bd[u] < bd[u - 1]) {
          float td = bd[u]; bd[u] = bd[u - 1]; bd[u - 1] = td;
          int   ti = bi[u]; bi[u] = bi[u - 1]; bi[u - 1] = ti;
        }
      }
    }
  }

  float t = owner ? bd[KNN - 1] : 0.f;
  #pragma unroll
  for (int mm = 1; mm < 64; mm <<= 1) t = fmaxf(t, __shfl_xor(t, mm));
  float r = sqrtf(fmaxf(t, 0.f)) * 1.001f + 1e-6f;

  const float4 gp = sph(p);
  const float rlim = r + gp.w;

  int ng = 0;
  #pragma unroll 1
  for (int gs0 = 0; gs0 < NG; gs0 += 64) {
    int g = gs0 + lane;
    bool ok = false;
    if (g < NG && g != p) {
      float4 gq = sph(g);
      float dx = gq.x - gp.x, dy = gq.y - gp.y, dz = gq.z - gp.z;
      float lim = rlim + gq.w;
      ok = (dx * dx + dy * dy + dz * dz) < lim * lim * 1.001f;
    }
    unsigned long long mask = __ballot(ok);
    if (ok) gl[ng + (int)__popcll(mask & ((1ull << lane) - 1ull))] = g;
    ng += (int)__popcll(mask);
  }

  const int total = ng * GS;
  #pragma unroll 1
  for (int cs = 0; cs < total; cs += 64) {
    int ci = cs + lane;
    if (ci < total) {
      int gg = gl[ci / GS];
      int j  = ci % GS;
      int jloc = gg * GS + j;
      float x = base[jloc * 3 + 0], y = base[jloc * 3 + 1], z = base[jloc * 3 + 2];
      tile[lane] = make_float4(x, y, z, x * x + y * y + z * z);
      tilei[lane] = jloc;
    }
    int nj = min(64, total - cs);
    #pragma unroll 1
    for (int jj = 0; jj < nj; ++jj) {
      float4 tt = tile[jj];
      int ti0 = tilei[jj];
      float d2 = sqi + tt.w - 2.0f * (qx * tt.x + qy * tt.y + qz * tt.z);
      if (owner && d2 < bd[KNN - 1]) {
        bd[KNN - 1] = d2; bi[KNN - 1] = ti0;
        #pragma unroll
        for (int u = KNN - 1; u > 0; --u) {
          if (bd[u] < bd[u - 1]) {
            float td = bd[u]; bd[u] = bd[u - 1]; bd[u - 1] = td;
            int   ti = bi[u]; bi[u] = bi[u - 1]; bi[u - 1] = ti;
          }
        }
      }
    }
  }

  if (owner) {
    int gid = b * Npg + qloc;
    #pragma unroll
    for (int u = 0; u < KNN; ++u) idx_out[gid * KNN + u] = b * Npg + bi[u];
  }
}

// ---------------------------------------------------------------------------
// Wave-per-QUERY kNN for stage-3 PRED points (lane-partitioned scan + merge).
__device__ __forceinline__ void knn3_pred_wave(
    const float* __restrict__ xyz_all, const float* __restrict__ ctx_xyz,
    const float* __restrict__ anchor, const int* __restrict__ radmax,
    int b, int q, int lane, int* gl, int* __restrict__ idx_out) {
  const float* base = xyz_all + (size_t)b * NALL * 3;
  const float* cxb  = ctx_xyz + (size_t)b * P_ * 3;
  const int qloc = NCTX + q;
  const int p = NG1 + q / GS;

  const float qx = base[qloc * 3 + 0], qy = base[qloc * 3 + 1], qz = base[qloc * 3 + 2];
  const float sqi = qx * qx + qy * qy + qz * qz;

  float dcur = 3e38f;
  int   icur = 0x7fffffff;
  if (lane < GS) {
    int jloc = p * GS + lane;
    if (jloc != qloc) {
      float x = base[jloc * 3 + 0], y = base[jloc * 3 + 1], z = base[jloc * 3 + 2];
      dcur = sqi + (x * x + y * y + z * z) - 2.0f * (qx * x + qy * y + qz * z);
      icur = jloc;
    }
  }
  float t = 3e38f;
  #pragma unroll 1
  for (int r8 = 0; r8 < KNN; ++r8) {
    float d = dcur; int i = icur;
    #pragma unroll
    for (int mm = 1; mm < 64; mm <<= 1) {
      float od = __shfl_xor(d, mm);
      int   oi = __shfl_xor(i, mm);
      if (od < d || (od == d && oi < i)) { d = od; i = oi; }
    }
    t = d;
    if (icur == i) { dcur = 3e38f; icur = 0x7fffffff; }
  }
  float r = sqrtf(fmaxf(t, 0.f)) * 1.001f + 1e-6f;

  int ng = 0;
  #pragma unroll 1
  for (int gs0 = 0; gs0 < NG3; gs0 += 64) {
    int g = gs0 + lane;
    bool ok = false;
    if (g < NG3) {
      float cx, cy, cz, rad;
      float moff = __int_as_float(radmax[b * NG3 + g]) * 1.0002f + 1e-6f;
      if (g < NG1) {
        cx = cxb[g * 3 + 0]; cy = cxb[g * 3 + 1]; cz = cxb[g * 3 + 2];
        rad = 0.0201f + moff;
      } else {
        cx = anchor[b * 3 + 0]; cy = anchor[b * 3 + 1]; cz = anchor[b * 3 + 2];
        rad = 0.0501f + moff;
      }
      float dx = cx - qx, dy = cy - qy, dz = cz - qz;
      float lim = r + rad;
      ok = (dx * dx + dy * dy + dz * dz) < lim * lim * 1.001f;
    }
    unsigned long long mask = __ballot(ok);
    if (ok) gl[ng + (int)__popcll(mask & ((1ull << lane) - 1ull))] = g;
    ng += (int)__popcll(mask);
  }

  float bd[KNN];
  int   bi[KNN];
  #pragma unroll
  for (int u = 0; u < KNN; ++u) { bd[u] = 3e38f; bi[u] = 0x7fffffff; }
  const int total = ng * GS;
  #pragma unroll 2
  for (int ci = lane; ci < total; ci += 64) {
    int gg = gl[ci / GS];
    int j  = ci % GS;
    int jloc = gg * GS + j;
    float x = base[jloc * 3 + 0], y = base[jloc * 3 + 1], z = base[jloc * 3 + 2];
    float d2 = sqi + (x * x + y * y + z * z) - 2.0f * (qx * x + qy * y + qz * z);
    if (jloc != qloc && d2 < bd[KNN - 1]) {
      bd[KNN - 1] = d2; bi[KNN - 1] = jloc;
      #pragma unroll
      for (int u = KNN - 1; u > 0; --u) {
        if (bd[u] < bd[u - 1]) {
          float td = bd[u]; bd[u] = bd[u - 1]; bd[u - 1] = td;
          int   ti = bi[u]; bi[u] = bi[u - 1]; bi[u - 1] = ti;
        }
      }
    }
  }

  const int gid = b * NALL + qloc;
  #pragma unroll 1
  for (int r8 = 0; r8 < KNN; ++r8) {
    float d = bd[0]; int i = bi[0];
    #pragma unroll
    for (int mm = 1; mm < 64; mm <<= 1) {
      float od = __shfl_xor(d, mm);
      int   oi = __shfl_xor(i, mm);
      if (od < d || (od == d && oi < i)) { d = od; i = oi; }
    }
    if (lane == 0) idx_out[gid * KNN + r8] = b * NALL + i;
    if (bi[0] == i) {
      #pragma unroll
      for (int u = 0; u < KNN - 1; ++u) { bd[u] = bd[u + 1]; bi[u] = bi[u + 1]; }
      bd[KNN - 1] = 3e38f; bi[KNN - 1] = 0x7fffffff;
    }
  }
}

// ---------------------------------------------------------------------------
// FUSED: stage-1 AB assembly + stage-1 kNN (ctx groups only).
__global__ __launch_bounds__(256) void ab12_knn1_kernel(
    const float* __restrict__ Tp, const float* __restrict__ xyz_all,
    const float* __restrict__ Wcat, const float* __restrict__ cb,
    const float* __restrict__ ctx_xyz,
    float* __restrict__ AB, int* __restrict__ idx1) {
  __shared__ float4 own[4][GS];
  __shared__ int    gl[4][NG1];
  __shared__ float4 tile[4][64];
  __shared__ int    tilei[4][64];
  const int tid = threadIdx.x;
  if (blockIdx.x < AB1_BLOCKS) {
    const int base = blockIdx.x * 8;
    const float wx = Wcat[128 * 256 + tid];
    const float wy = Wcat[129 * 256 + tid];
    const float wz = Wcat[130 * 256 + tid];
    const float cbv = cb[tid];
    #pragma unroll
    for (int p = 0; p < 8; ++p) {
      int n = base + p;
      int b = n / NCTX, loc = n % NCTX;
      int trow = b * (NCTX / GS) + loc / GS;
      const float* xr = xyz_all + (size_t)(b * NALL + loc) * 3;
      float x = xr[0], y = xr[1], z = xr[2];
      float v = cbv;
      #pragma unroll
      for (int s = 0; s < KSPLIT; ++s)
        v += Tp[((size_t)s * TROWS + trow) * 256 + tid];
      v = fmaf(x, wx, v);
      v = fmaf(y, wy, v);
      v = fmaf(z, wz, v);
      AB[(size_t)n * 256 + tid] = v;
    }
  } else {
    int kblk = blockIdx.x - AB1_BLOCKS;
    int w = tid >> 6, lane = tid & 63;
    int b = kblk / (NG1 / 4);
    int p = (kblk % (NG1 / 4)) * 4 + w;
    knn_wave_body<1>(xyz_all, ctx_xyz, nullptr, nullptr, b, p, lane,
                     own[w], gl[w], tile[w], tilei[w], idx1);
  }
}

// ---------------------------------------------------------------------------
// FUSED: stage-2 AB assembly + stage-2 small kNN.
__global__ __launch_bounds__(256) void ab12_knn2_kernel(
    const float* __restrict__ Tp, const float* __restrict__ xyz_all,
    const float* __restrict__ Wcat, const float* __restrict__ cb,
    float* __restrict__ AB, int* __restrict__ idx2) {
  const int tid = threadIdx.x;
  if (blockIdx.x < AB2_BLOCKS) {
    const int base = blockIdx.x * 8;
    const float wx = Wcat[128 * 256 + tid];
    const float wy = Wcat[129 * 256 + tid];
    const float wz = Wcat[130 * 256 + tid];
    const float cbv = cb[tid];
    #pragma unroll
    for (int p = 0; p < 8; ++p) {
      int n = base + p;
      int b = n / NPRD, loc = n % NPRD;
      int trow = B_ * P_ + b * (NPRD / GS) + loc / GS;
      const float* xr = xyz_all + (size_t)(b * NALL + NCTX + loc) * 3;
      float x = xr[0], y = xr[1], z = xr[2];
      float v = cbv;
      #pragma unroll
      for (int s = 0; s < KSPLIT; ++s)
        v += Tp[((size_t)s * TROWS + trow) * 256 + tid];
      v = fmaf(x, wx, v);
      v = fmaf(y, wy, v);
      v = fmaf(z, wz, v);
      AB[(size_t)n * 256 + tid] = v;
    }
  } else {
    int q = (blockIdx.x - AB2_BLOCKS) * 256 + tid;
    int gr = q / RP, qi = q % RP;
    int b = gr / M_, w = gr % M_;
    const float* base = xyz_all + (size_t)(b * NALL + NCTX + w * RP) * 3;
    float cx[RP], cy[RP], cz[RP], cs[RP];
    #pragma unroll
    for (int j = 0; j < RP; ++j) {
      cx[j] = base[j * 3 + 0]; cy[j] = base[j * 3 + 1]; cz[j] = base[j * 3 + 2];
      cs[j] = cx[j] * cx[j] + cy[j] * cy[j] + cz[j] * cz[j];
    }
    float qx = cx[0], qy = cy[0], qz = cz[0], sqi = cs[0];
    #pragma unroll
    for (int j = 0; j < RP; ++j) {
      if (j == qi) { qx = cx[j]; qy = cy[j]; qz = cz[j]; sqi = cs[j]; }
    }
    float bd[KNN];
    int   bi[KNN];
    #pragma unroll
    for (int u = 0; u < KNN; ++u) { bd[u] = 3e38f; bi[u] = 0; }
    #pragma unroll
    for (int j = 0; j < RP; ++j) {
      float d2 = sqi + cs[j] - 2.0f * (qx * cx[j] + qy * cy[j] + qz * cz[j]);
      if (j != qi && d2 < bd[KNN - 1]) {
        bd[KNN - 1] = d2; bi[KNN - 1] = j;
        #pragma unroll
        for (int u = KNN - 1; u > 0; --u) {
          if (bd[u] < bd[u - 1]) {
            float td = bd[u]; bd[u] = bd[u - 1]; bd[u - 1] = td;
            int   ti = bi[u]; bi[u] = bi[u - 1]; bi[u - 1] = ti;
          }
        }
      }
    }
    #pragma unroll
    for (int u = 0; u < KNN; ++u) idx2[q * KNN + u] = gr * RP + bi[u];
  }
}

// ---------------------------------------------------------------------------
// FUSED: stage-3 precompute | ctx-group kNN | pred-query kNN.
__global__ __launch_bounds__(256) void pre3_knn3_kernel(
    const float* __restrict__ feat, const float* __restrict__ xyz_all,
    const float* __restrict__ Wcat, const float* __restrict__ be1,
    const float* __restrict__ ctx_xyz, const float* __restrict__ anchor,
    const int* __restrict__ radmax,
    float* __restrict__ AB, int* __restrict__ idx3) {
  __shared__ float x_lds[8][132];
  __shared__ float4 own[4][GS];
  __shared__ int    gl[4][NG3];
  __shared__ float4 tile[4][64];
  __shared__ int    tilei[4][64];
  const int tid = threadIdx.x;
  if (blockIdx.x < PRE3_BLOCKS) {
    const int base = blockIdx.x * 8;
    for (int l = tid; l < 8 * 131; l += 256) {
      int pt = l / 131, t = l % 131;
      int g = base + pt;
      int b = g / NALL, loc = g % NALL;
      float v;
      if (t < C) v = feat[(size_t)g * C + t];
      else       v = xyz_all[(size_t)(b * NALL + loc) * 3 + (t - C)];
      x_lds[pt][t] = v;
    }
    __syncthreads();
    float acc[8] = {0.f, 0.f, 0.f, 0.f, 0.f, 0.f, 0.f, 0.f};
    #pragma unroll 1
    for (int t = 0; t < 131; ++t) {
      float wv = Wcat[t * 256 + tid];
      #pragma unroll
      for (int p = 0; p < 8; ++p) acc[p] = fmaf(x_lds[p][t], wv, acc[p]);
    }
    float bias = (tid < C) ? be1[tid] : 0.0f;
    #pragma unroll
    for (int p = 0; p < 8; ++p) AB[(size_t)(base + p) * 256 + tid] = acc[p] + bias;
  } else if (blockIdx.x < PRE3_BLOCKS + KNN3C_BLOCKS) {
    int kblk = blockIdx.x - PRE3_BLOCKS;
    int w = tid >> 6, lane = tid & 63;
    int b = kblk / (NG1 / 4);
    int p = (kblk % (NG1 / 4)) * 4 + w;     // ctx groups only: p < NG1
    knn_wave_body<3>(xyz_all, ctx_xyz, anchor, radmax, b, p, lane,
                     own[w], gl[w], tile[w], tilei[w], idx3);
  } else {
    int kblk = blockIdx.x - PRE3_BLOCKS - KNN3C_BLOCKS;
    int w = tid >> 6, lane = tid & 63;
    int wid = kblk * 4 + w;                  // 0 .. B*NPRD-1
    int b = wid / NPRD, q = wid % NPRD;
    knn3_pred_wave(xyz_all, ctx_xyz, anchor, radmax, b, q, lane, gl[w], idx3);
  }
}

// ---------------------------------------------------------------------------
// MFMA EdgeConv core (split-bf16, 3 MFMAs, ~2^-16 err).
__global__ __launch_bounds__(256) void conv_mfma_kernel(const float* __restrict__ AB,
                                                        const int* __restrict__ idx,
                                                        const unsigned short* __restrict__ w2hi_g,
                                                        const unsigned short* __restrict__ w2lo_g,
                                                        const float* __restrict__ be2,
                                                        float* __restrict__ feat_out,
                                                        int NPB, int row_off) {
  __shared__ unsigned short hhi[64 * 128];    // 16 KB
  __shared__ unsigned short hlo[64 * 128];    // 16 KB
  __shared__ unsigned short w2hi[128 * 128];  // 32 KB
  const int tid = threadIdx.x;
  const int base = blockIdx.x * 8;

  #pragma unroll
  for (int i = 0; i < 8; ++i) {
    int q = tid + 256 * i;
    int n = q >> 4, c = q & 15;
    f32x4 v = *(const f32x4*)(w2hi_g + n * 128 + c * 8);
    *(f32x4*)(w2hi + (n * 16 + (c ^ (n & 15))) * 8) = v;
  }

  #pragma unroll
  for (int i = 0; i < 4; ++i) {
    int task = tid + 256 * i;
    int r = task >> 4, c = task & 15;
    int p = r >> 3, nb = r & 7;
    int g = base + p;
    int j = idx[g * KNN + nb];
    const float* aP = AB + (size_t)g * 256 + c * 8;
    const float* bP = AB + (size_t)j * 256 + 128 + c * 8;
    f32x4 a0 = *(const f32x4*)aP;
    f32x4 a1 = *(const f32x4*)(aP + 4);
    f32x4 b0 = *(const f32x4*)bP;
    f32x4 b1 = *(const f32x4*)(bP + 4);
    float hv[8] = {a0.x + b0.x, a0.y + b0.y, a0.z + b0.z, a0.w + b0.w,
                   a1.x + b1.x, a1.y + b1.y, a1.z + b1.z, a1.w + b1.w};
    union { unsigned short s[8]; f32x4 v; } oh, ol;
    #pragma unroll
    for (int e = 0; e < 8; ++e) {
      float h = fmaxf(hv[e], 0.0f);
      unsigned short x = f32_to_bf16_rne(h);
      oh.s[e] = x;
      ol.s[e] = f32_to_bf16_rne(h - bf16_to_f32(x));
    }
    int dst = (r * 16 + (c ^ (r & 15))) * 8;
    *(f32x4*)(hhi + dst) = oh.v;
    *(f32x4*)(hlo + dst) = ol.v;
  }
  __syncthreads();

  const int lane = tid & 63, w = tid >> 6;
  const int m = lane & 15, quad = lane >> 4;
  f32x4 acc[8];
  #pragma unroll
  for (int nt = 0; nt < 8; ++nt) acc[nt] = (f32x4){0.f, 0.f, 0.f, 0.f};

  #pragma unroll 1
  for (int ks = 0; ks < 4; ++ks) {
    int c0 = ks * 4 + quad;
    int rowA = w * 16 + m;
    int aoff = (rowA * 16 + (c0 ^ m)) * 8;
    bf16x8 ahi = *(const bf16x8*)(hhi + aoff);
    bf16x8 alo = *(const bf16x8*)(hlo + aoff);
    #pragma unroll
    for (int nt = 0; nt < 8; ++nt) {
      int n = nt * 16 + m;
      bf16x8 bhi = *(const bf16x8*)(w2hi + (n * 16 + (c0 ^ m)) * 8);
      bf16x8 blo = *(const bf16x8*)(w2lo_g + n * 128 + c0 * 8);
      acc[nt] = __builtin_amdgcn_mfma_f32_16x16x32_bf16(ahi, bhi, acc[nt], 0, 0, 0);
      acc[nt] = __builtin_amdgcn_mfma_f32_16x16x32_bf16(ahi, blo, acc[nt], 0, 0, 0);
      acc[nt] = __builtin_amdgcn_mfma_f32_16x16x32_bf16(alo, bhi, acc[nt], 0, 0, 0);
    }
  }

  int pt = 2 * w + (quad >> 1);
  int g = base + pt;
  int b = g / NPB, loc = g % NPB;
  float* orow = feat_out + (size_t)(b * NALL + row_off + loc) * C;
  bool writer = (quad & 1) == 0;
  #pragma unroll
  for (int nt = 0; nt < 8; ++nt) {
    float v = fmaxf(fmaxf(acc[nt].x, acc[nt].y), fmaxf(acc[nt].z, acc[nt].w));
    v = fmaxf(v, __shfl_xor(v, 16));
    if (writer) {
      int col = nt * 16 + m;
      orow[col] = v + be2[col];
    }
  }
}

// ---------------------------------------------------------------------------
// offset MLP: out_row = xyz_in_row + (relu(f@W1+b1) @ W2 + b2).
// Optionally accumulates per-group max |offset| into radmax (for knn3 bounds).
__global__ __launch_bounds__(256) void offset_kernel(const float* __restrict__ feat,
                                                     const float* __restrict__ W1,
                                                     const float* __restrict__ b1,
                                                     const float* __restrict__ W2,
                                                     const float* __restrict__ b2,
                                                     const float* __restrict__ xyz_in,
                                                     float* __restrict__ xyz_out,
                                                     int NPB, int row_off,
                                                     int* __restrict__ radmax) {
  __shared__ float w1c[64 * C];
  __shared__ float f_lds[16][C];
  __shared__ float wred[4][3];
  const int tid = threadIdx.x;
  const int base = blockIdx.x * 16;
  const int p = tid >> 7;
  const int cc = tid & 127;
  const int wave = tid >> 6, lane = tid & 63;

  for (int l = tid; l < 16 * C; l += 256) {
    int pt = l >> 7, t = l & 127;
    int g = base + pt;
    int b = g / NPB, loc = g % NPB;
    f_lds[pt][t] = feat[(size_t)(b * NALL + row_off + loc) * C + t];
  }

  float s[8];
  #pragma unroll
  for (int pp = 0; pp < 8; ++pp) s[pp] = 0.f;

  for (int kk = 0; kk < 2; ++kk) {
    __syncthreads();
    for (int l = tid * 4; l < 64 * C; l += 1024)
      *(float4*)&w1c[l] = *(const float4*)&W1[kk * 64 * C + l];
    __syncthreads();
    #pragma unroll
    for (int pp = 0; pp < 8; ++pp) {
      const float* f = &f_lds[pp * 2 + p][kk * 64];
      float acc = s[pp];
      #pragma unroll 4
      for (int t = 0; t < 64; ++t) acc = fmaf(f[t], w1c[t * C + cc], acc);
      s[pp] = acc;
    }
  }

  float b1v = b1[cc];
  float w20 = W2[cc * 3 + 0], w21 = W2[cc * 3 + 1], w22 = W2[cc * 3 + 2];
  float b20 = b2[0], b21 = b2[1], b22 = b2[2];

  #pragma unroll 1
  for (int pp = 0; pp < 8; ++pp) {
    float h = fmaxf(s[pp] + b1v, 0.0f);
    float p0 = h * w20, p1 = h * w21, p2 = h * w22;
    for (int o = 32; o > 0; o >>= 1) {
      p0 += __shfl_down(p0, o);
      p1 += __shfl_down(p1, o);
      p2 += __shfl_down(p2, o);
    }
    if (lane == 0) { wred[wave][0] = p0; wred[wave][1] = p1; wred[wave][2] = p2; }
    __syncthreads();
    if (tid < 2) {
      int g = base + pp * 2 + tid;
      int b = g / NPB, loc = g % NPB;
      int row = (b * NALL + row_off + loc) * 3;
      float o0 = wred[tid * 2][0] + wred[tid * 2 + 1][0] + b20;
      float o1 = wred[tid * 2][1] + wred[tid * 2 + 1][1] + b21;
      float o2 = wred[tid * 2][2] + wred[tid * 2 + 1][2] + b22;
      xyz_out[row + 0] = xyz_in[row + 0] + o0;
      xyz_out[row + 1] = xyz_in[row + 1] + o1;
      xyz_out[row + 2] = xyz_in[row + 2] + o2;
      if (radmax != nullptr) {
        float mag = sqrtf(o0 * o0 + o1 * o1 + o2 * o2);
        atomicMax(radmax + b * NG3 + (row_off + loc) / GS, __float_as_int(mag));
      }
    }
    __syncthreads();
  }
}

// ---------------------------------------------------------------------------
extern "C" void kernel_launch(void* const* d_in, const int* in_sizes, int n_in,
                              void* d_out, int out_size, void* d_ws, size_t ws_size,
                              hipStream_t stream) {
  (void)in_sizes; (void)n_in; (void)out_size; (void)ws_size;
  const float* ctx_xyz   = (const float*)d_in[0];
  const float* ctx_tok   = (const float*)d_in[1];
  const float* pred_tok  = (const float*)d_in[2];
  const float* noise_ctx = (const float*)d_in[3];
  const float* noise_prd = (const float*)d_in[4];
  const float* Wp  = (const float*)d_in[5];
  const float* bp  = (const float*)d_in[6];
  const float* We1 = (const float*)d_in[7];
  const float* be1 = (const float*)d_in[8];
  const float* We2 = (const float*)d_in[9];
  const float* be2 = (const float*)d_in[10];
  const float* Wc1 = (const float*)d_in[11];
  const float* bc1 = (const float*)d_in[12];
  const float* Wc2 = (const float*)d_in[13];
  const float* bc2 = (const float*)d_in[14];
  const float* Wq1 = (const float*)d_in[15];
  const float* bq1 = (const float*)d_in[16];
  const float* Wq2 = (const float*)d_in[17];
  const float* bq2 = (const float*)d_in[18];
  const float* Wf1 = (const float*)d_in[19];
  const float* bf1 = (const float*)d_in[20];
  const float* Wf2 = (const float*)d_in[21];
  const float* bf2 = (const float*)d_in[22];
  float* out = (float*)d_out;

  // workspace layout (floats)
  float* ws        = (float*)d_ws;
  float* T         = ws;                          // 1792*256 (unused legacy slot)
  float* anchor    = T + TROWS * 256;             // 16
  float* xyz_all   = anchor + 16;                 // B*NALL*3    = 64512
  float* feat_in   = xyz_all + B_ * NALL * 3;     // B*NALL*C    = 2752512
  float* feat_out  = feat_in + B_ * NALL * C;     // B*NALL*C    = 2752512
  float* AB        = feat_out + B_ * NALL * C;    // B*NALL*256  = 5505024
  float* Wcat      = AB + B_ * NALL * 256;        // 131*256     = 33536
  float* cb        = Wcat + 131 * 256;            // 256
  int*   idx1      = (int*)(cb + 256);            // B*NCTX*8    = 147456
  int*   idx2      = idx1 + B_ * NCTX * KNN;      // B*NPRD*8    = 24576
  int*   idx3      = idx2 + B_ * NPRD * KNN;      // B*NALL*8    = 172032
  unsigned short* we2hi = (unsigned short*)(idx3 + B_ * NALL * KNN); // 16384
  unsigned short* we2lo = we2hi + C * C;                             // 16384
  int*   radmax    = (int*)(we2lo + C * C);       // B*NG3       = 1792 ints
  // wbT aliases AB: fully consumed by t12_mfma before the first AB write.
  unsigned short* wbT_hi = (unsigned short*)AB;   // 256*1024 ushorts
  unsigned short* wbT_lo = wbT_hi + 256 * TOK;    // 256*1024 ushorts
  // Tpart aliases feat_out: last read at ab12_knn2 (stage 2), feat_out first
  // written at stage-3 conv. KSPLIT*TROWS*256 = 1835008 <= 2752512 floats.
  float* Tpart = feat_out;

  // prep (fused)
  prep1_kernel<<<196, 256, 0, stream>>>(We1, We2, ctx_xyz, Wcat, we2hi, we2lo, anchor);
  prep2_kernel<<<TOK / 4 + 1, 256, 0, stream>>>(Wp, bp, Wcat, be1, wbT_hi, wbT_lo, cb);
  build_all_kernel<<<72 + 12, 256, 0, stream>>>(ctx_xyz, noise_ctx, noise_prd, anchor,
                                                xyz_all, radmax);

  // token GEMM (split-K x4): Tpart[s] = [ctx_tok; pred_tok] @ Wbig[kslice s]
  t12_mfma_kernel<<<dim3(TROWS / 64, 2, KSPLIT), 256, 0, stream>>>(ctx_tok, pred_tok,
                                                                   wbT_hi, wbT_lo, Tpart);

  // ---- stage 1: context branch ----
  ab12_knn1_kernel<<<AB1_BLOCKS + KNN1_BLOCKS, 256, 0, stream>>>(Tpart, xyz_all, Wcat, cb,
                                                                 ctx_xyz, AB, idx1);
  conv_mfma_kernel<<<(B_ * NCTX) / 8, 256, 0, stream>>>(AB, idx1, we2hi, we2lo, be2, feat_in, NCTX, 0);
  offset_kernel<<<(B_ * NCTX) / 16, 256, 0, stream>>>(feat_in, Wc1, bc1, Wc2, bc2,
                                                      xyz_all, xyz_all, NCTX, 0, radmax);

  // ---- stage 2: prediction branch ----
  ab12_knn2_kernel<<<AB2_BLOCKS + KNS_BLOCKS, 256, 0, stream>>>(Tpart, xyz_all, Wcat, cb, AB, idx2);
  conv_mfma_kernel<<<(B_ * NPRD) / 8, 256, 0, stream>>>(AB, idx2, we2hi, we2lo, be2, feat_in, NPRD, NCTX);
  offset_kernel<<<(B_ * NPRD) / 16, 256, 0, stream>>>(feat_in, Wq1, bq1, Wq2, bq2,
                                                      xyz_all, xyz_all, NPRD, NCTX, radmax);

  // ---- stage 3: global refinement ----
  pre3_knn3_kernel<<<PRE3_BLOCKS + KNN3C_BLOCKS + KNN3P_BLOCKS, 256, 0, stream>>>(
      feat_in, xyz_all, Wcat, be1, ctx_xyz, anchor, radmax, AB, idx3);
  conv_mfma_kernel<<<(B_ * NALL) / 8, 256, 0, stream>>>(AB, idx3, we2hi, we2lo, be2, feat_out, NALL, 0);
  offset_kernel<<<(B_ * NALL) / 16, 256, 0, stream>>>(feat_out, Wf1, bf1, Wf2, bf2,
                                                      xyz_all, out, NALL, 0, nullptr);
}

// Round 10
// 398.463 us; speedup vs baseline: 4.4031x; 1.2472x over previous
//
#include <hip/hip_runtime.h>
#include <math.h>

// Problem constants (from setup_inputs; k==8 is fixed by the harness inputs).
constexpr int B_   = 4;
constexpr int P_   = 384;
constexpr int M_   = 64;
constexpr int TOK  = 1024;
constexpr int C    = 128;
constexpr int RC   = 12;
constexpr int RP   = 12;
constexpr int KNN  = 8;
constexpr int GS   = 12;           // group size (both ctx clusters and pred rings)
constexpr int NCTX = P_ * RC;      // 4608 ctx points per batch
constexpr int NPRD = M_ * RP;      // 768 pred points per batch
constexpr int NALL = NCTX + NPRD;  // 5376
constexpr int NG1  = NCTX / GS;    // 384 groups, stage 1
constexpr int NG3  = NALL / GS;    // 448 groups, stage 3
constexpr int TROWS = B_ * P_ + B_ * M_;  // 1792 token rows (ctx then pred)
constexpr int KSPLIT = 4;          // t12 split-K factor

// fused-grid split points
constexpr int AB1_BLOCKS   = (B_ * NCTX) / 8;      // 2304
constexpr int KNN1_BLOCKS  = B_ * (NG1 / 4);       // 384
constexpr int AB2_BLOCKS   = (B_ * NPRD) / 8;      // 384
constexpr int KNS_BLOCKS   = (B_ * M_ * RP) / 256; // 12
constexpr int P3G_BLOCKS   = (B_ * NALL) / 64;     // 336 (stage-3 MFMA GEMM)
constexpr int KNN3C_BLOCKS = B_ * (NG1 / 4);       // 384 (ctx groups, wave-per-group)
constexpr int KNN3P_BLOCKS = (B_ * NPRD) / 4;      // 768 (pred queries, wave-per-query)

typedef __attribute__((ext_vector_type(8))) short bf16x8;
typedef __attribute__((ext_vector_type(4))) float f32x4;

__device__ inline unsigned short f32_to_bf16_rne(float x) {
  union { float f; unsigned int u; } v; v.f = x;
  unsigned int r = v.u + 0x7fffu + ((v.u >> 16) & 1u);
  return (unsigned short)(r >> 16);
}
__device__ inline float bf16_to_f32(unsigned short h) {
  union { float f; unsigned int u; } v; v.u = ((unsigned int)h) << 16;
  return v.f;
}
// convert 8 fp32 (two f32x4) to bf16 hi/lo fragments in registers
__device__ inline void split8(const f32x4& a0, const f32x4& a1, bf16x8& hi, bf16x8& lo) {
  float vals[8] = {a0.x, a0.y, a0.z, a0.w, a1.x, a1.y, a1.z, a1.w};
  union { unsigned short s[8]; bf16x8 v; } oh, ol;
  #pragma unroll
  for (int e = 0; e < 8; ++e) {
    unsigned short h = f32_to_bf16_rne(vals[e]);
    oh.s[e] = h;
    ol.s[e] = f32_to_bf16_rne(vals[e] - bf16_to_f32(h));
  }
  hi = oh.v; lo = ol.v;
}

// ---------------------------------------------------------------------------
// FUSED prep1: Wcat | We2 transpose | anchor | W1T transposes (Wc1/Wq1/Wf1).
__global__ __launch_bounds__(256) void prep1_kernel(const float* __restrict__ We1,
                                                    const float* __restrict__ We2,
                                                    const float* __restrict__ cxyz,
                                                    const float* __restrict__ Wc1,
                                                    const float* __restrict__ Wq1,
                                                    const float* __restrict__ Wf1,
                                                    float* __restrict__ Wcat,
                                                    unsigned short* __restrict__ we2hi,
                                                    unsigned short* __restrict__ we2lo,
                                                    float* __restrict__ anchor,
                                                    unsigned short* __restrict__ w1T_hi,
                                                    unsigned short* __restrict__ w1T_lo) {
  const int tid = threadIdx.x;
  if (blockIdx.x < 131) {
    int n = blockIdx.x * 256 + tid;
    int t = n >> 8, cc = n & 255;
    float v;
    if (cc < C) v = We1[t * C + cc] - We1[(131 + t) * C + cc];
    else        v = We1[(131 + t) * C + (cc - C)];
    Wcat[n] = v;
  } else if (blockIdx.x < 195) {
    int e = (blockIdx.x - 131) * 256 + tid;
    int n = e >> 7, k = e & 127;
    float w = We2[k * C + n];
    unsigned short h = f32_to_bf16_rne(w);
    we2hi[n * C + k] = h;
    we2lo[n * C + k] = f32_to_bf16_rne(w - bf16_to_f32(h));
  } else if (blockIdx.x == 195) {
    const int w = tid >> 6, lane = tid & 63;
    float ax = 0.f, ay = 0.f, az = 0.f;
    for (int p = lane; p < P_; p += 64) {
      const float* c = &cxyz[(w * P_ + p) * 3];
      ax += c[0]; ay += c[1]; az += c[2];
    }
    for (int o = 32; o > 0; o >>= 1) {
      ax += __shfl_down(ax, o);
      ay += __shfl_down(ay, o);
      az += __shfl_down(az, o);
    }
    if (lane == 0) {
      anchor[w * 3 + 0] = ax * (1.0f / (float)P_);
      anchor[w * 3 + 1] = ay * (1.0f / (float)P_);
      anchor[w * 3 + 2] = az * (1.0f / (float)P_);
    }
  } else {
    int e = (blockIdx.x - 196) * 256 + tid;     // 0 .. 3*16384-1
    int wsel = e >> 14, r = e & 16383;
    int c = r >> 7, k = r & 127;
    const float* W1s = (wsel == 0) ? Wc1 : (wsel == 1) ? Wq1 : Wf1;
    float w = W1s[k * C + c];
    unsigned short h = f32_to_bf16_rne(w);
    w1T_hi[(size_t)wsel * 16384 + c * 128 + k] = h;
    w1T_lo[(size_t)wsel * 16384 + c * 128 + k] = f32_to_bf16_rne(w - bf16_to_f32(h));
  }
}

// ---------------------------------------------------------------------------
// FUSED prep2: WbigT hi/lo | cb vector | WcatT hi/lo (feat part, [256][128]).
__global__ __launch_bounds__(256) void prep2_kernel(const float* __restrict__ Wp,
                                                    const float* __restrict__ bp,
                                                    const float* __restrict__ Wcat,
                                                    const float* __restrict__ be1,
                                                    unsigned short* __restrict__ wbT_hi,
                                                    unsigned short* __restrict__ wbT_lo,
                                                    float* __restrict__ cb,
                                                    unsigned short* __restrict__ wcatT_hi,
                                                    unsigned short* __restrict__ wcatT_lo) {
  __shared__ float s_lds[4][128];
  const int tid = threadIdx.x;
  if (blockIdx.x < TOK / 4) {
    const int k0 = blockIdx.x * 4;
    for (int l = tid; l < 4 * 128; l += 256) {
      int r = l >> 7, f = l & 127;
      s_lds[r][f] = Wp[(k0 + r) * C + f];
    }
    __syncthreads();
    float acc[4] = {0.f, 0.f, 0.f, 0.f};
    #pragma unroll 4
    for (int f = 0; f < 128; ++f) {
      float wv = Wcat[f * 256 + tid];
      #pragma unroll
      for (int r = 0; r < 4; ++r) acc[r] = fmaf(s_lds[r][f], wv, acc[r]);
    }
    #pragma unroll
    for (int r = 0; r < 4; ++r) {
      unsigned short h = f32_to_bf16_rne(acc[r]);
      wbT_hi[(size_t)tid * TOK + k0 + r] = h;
      wbT_lo[(size_t)tid * TOK + k0 + r] = f32_to_bf16_rne(acc[r] - bf16_to_f32(h));
    }
  } else if (blockIdx.x == TOK / 4) {
    if (tid < 128) s_lds[0][tid] = bp[tid];
    __syncthreads();
    float a = (tid < 128) ? be1[tid] : 0.f;
    #pragma unroll 4
    for (int f = 0; f < 128; ++f) a = fmaf(s_lds[0][f], Wcat[f * 256 + tid], a);
    cb[tid] = a;
  } else {
    int e = (blockIdx.x - TOK / 4 - 1) * 256 + tid;   // 0 .. 256*128-1
    int c = e >> 7, k = e & 127;
    float w = Wcat[k * 256 + c];
    unsigned short h = f32_to_bf16_rne(w);
    wcatT_hi[c * 128 + k] = h;
    wcatT_lo[c * 128 + k] = f32_to_bf16_rne(w - bf16_to_f32(h));
  }
}

// ---------------------------------------------------------------------------
// FUSED geometry build: ctx points (+radmax zero-init) | pred points.
__global__ __launch_bounds__(256) void build_all_kernel(const float* __restrict__ cxyz,
                                                        const float* __restrict__ noise_c,
                                                        const float* __restrict__ noise_p,
                                                        const float* __restrict__ anchor,
                                                        float* __restrict__ xyz_all,
                                                        int* __restrict__ radmax) {
  if (blockIdx.x < 72) {
    int n = blockIdx.x * 256 + threadIdx.x;
    if (n < B_ * NG3) radmax[n] = 0;      // float 0.0 bits
    int b = n / NCTX, i = n % NCTX, p = i / RC;
    float x = noise_c[n * 3 + 0], y = noise_c[n * 3 + 1], z = noise_c[n * 3 + 2];
    float s = 0.02f / (sqrtf(x * x + y * y + z * z) + 1e-6f);
    const float* c = &cxyz[(b * P_ + p) * 3];
    float* o = &xyz_all[(b * NALL + i) * 3];
    o[0] = c[0] + x * s;
    o[1] = c[1] + y * s;
    o[2] = c[2] + z * s;
  } else {
    int n = (blockIdx.x - 72) * 256 + threadIdx.x;
    int b = n / NPRD, i = n % NPRD;
    float x = noise_p[n * 3 + 0], y = noise_p[n * 3 + 1], z = noise_p[n * 3 + 2];
    float s = 0.05f / (sqrtf(x * x + y * y + z * z) + 1e-6f);
    const float* a = &anchor[b * 3];
    float* o = &xyz_all[(b * NALL + NCTX + i) * 3];
    o[0] = a[0] + x * s;
    o[1] = a[1] + y * s;
    o[2] = a[2] + z * s;
  }
}

// ---------------------------------------------------------------------------
// Tpart[s][row][c] = tok[row] @ Wbig[kslice s]. Split-bf16 MFMA GEMM, split-K.
__global__ __launch_bounds__(256) void t12_mfma_kernel(const float* __restrict__ ctx_tok,
                                                       const float* __restrict__ pred_tok,
                                                       const unsigned short* __restrict__ wbT_hi,
                                                       const unsigned short* __restrict__ wbT_lo,
                                                       float* __restrict__ Tpart) {
  __shared__ unsigned short ahi[64 * 128];   // 16 KB
  __shared__ unsigned short alo[64 * 128];   // 16 KB
  __shared__ unsigned short bhi[128 * 128];  // 32 KB
  const int tid = threadIdx.x;
  const int r0 = blockIdx.x * 64;
  const int n0 = blockIdx.y * 128;
  const int s  = blockIdx.z;
  const float* src = (r0 < B_ * P_) ? (ctx_tok + (size_t)r0 * TOK)
                                    : (pred_tok + (size_t)(r0 - B_ * P_) * TOK);
  const int lane = tid & 63, w = tid >> 6;
  const int m = lane & 15, quad = lane >> 4;

  f32x4 acc[8];
  #pragma unroll
  for (int nt = 0; nt < 8; ++nt) acc[nt] = (f32x4){0.f, 0.f, 0.f, 0.f};

  #pragma unroll 1
  for (int kc = s * (8 / KSPLIT); kc < (s + 1) * (8 / KSPLIT); ++kc) {
    __syncthreads();
    #pragma unroll
    for (int i = 0; i < 4; ++i) {
      int task = tid + 256 * i;           // 0..1023
      int r = task >> 4, c = task & 15;
      const float* sp = src + (size_t)r * TOK + kc * 128 + c * 8;
      f32x4 a0 = *(const f32x4*)sp;
      f32x4 a1 = *(const f32x4*)(sp + 4);
      bf16x8 oh, ol;
      split8(a0, a1, oh, ol);
      int dst = (r * 16 + (c ^ (r & 15))) * 8;
      *(bf16x8*)(ahi + dst) = oh;
      *(bf16x8*)(alo + dst) = ol;
    }
    #pragma unroll
    for (int i = 0; i < 8; ++i) {
      int task = tid + 256 * i;           // 0..2047
      int n = task >> 4, c = task & 15;
      f32x4 v = *(const f32x4*)(wbT_hi + (size_t)(n0 + n) * TOK + kc * 128 + c * 8);
      *(f32x4*)(bhi + (n * 16 + (c ^ (n & 15))) * 8) = v;
    }
    __syncthreads();
    #pragma unroll
    for (int ks = 0; ks < 4; ++ks) {
      int c0 = ks * 4 + quad;
      int aoff = ((w * 16 + m) * 16 + (c0 ^ m)) * 8;
      bf16x8 av  = *(const bf16x8*)(ahi + aoff);
      bf16x8 av2 = *(const bf16x8*)(alo + aoff);
      #pragma unroll
      for (int nt = 0; nt < 8; ++nt) {
        int n = nt * 16 + m;
        bf16x8 bh = *(const bf16x8*)(bhi + (n * 16 + (c0 ^ m)) * 8);
        bf16x8 bl = *(const bf16x8*)(wbT_lo + (size_t)(n0 + n) * TOK + kc * 128 + c0 * 8);
        acc[nt] = __builtin_amdgcn_mfma_f32_16x16x32_bf16(av, bh, acc[nt], 0, 0, 0);
        acc[nt] = __builtin_amdgcn_mfma_f32_16x16x32_bf16(av, bl, acc[nt], 0, 0, 0);
        acc[nt] = __builtin_amdgcn_mfma_f32_16x16x32_bf16(av2, bh, acc[nt], 0, 0, 0);
      }
    }
  }
  #pragma unroll
  for (int nt = 0; nt < 8; ++nt) {
    int col = n0 + nt * 16 + m;
    #pragma unroll
    for (int reg = 0; reg < 4; ++reg) {
      int row = r0 + w * 16 + quad * 4 + reg;
      Tpart[((size_t)s * TROWS + row) * 256 + col] = acc[nt][reg];
    }
  }
}

// ---------------------------------------------------------------------------
// Wave-per-group kNN body for CTX groups (light: phase-3 list nearly empty).
template <int STAGE>
__device__ __forceinline__ void knn_wave_body(
    const float* __restrict__ xyz_all, const float* __restrict__ ctx_xyz,
    const float* __restrict__ anchor, const int* __restrict__ radmax,
    int b, int p, int lane,
    float4* own, int* gl, float4* tile, int* tilei,
    int* __restrict__ idx_out) {
  const int NG  = (STAGE == 1) ? NG1 : NG3;
  const int Npg = (STAGE == 1) ? NCTX : NALL;
  const float* base = xyz_all + (size_t)b * NALL * 3;
  const float* cxb  = ctx_xyz + (size_t)b * P_ * 3;
  const bool owner = lane < GS;
  const int qloc = p * GS + lane;

  auto sph = [&](int g) -> float4 {
    float4 c;
    float rad;
    if (STAGE == 1) {
      c = make_float4(cxb[g * 3 + 0], cxb[g * 3 + 1], cxb[g * 3 + 2], 0.f);
      rad = 0.0201f;
    } else {
      float moff = __int_as_float(radmax[b * NG3 + g]);
      if (g < NG1) {
        c = make_float4(cxb[g * 3 + 0], cxb[g * 3 + 1], cxb[g * 3 + 2], 0.f);
        rad = 0.0201f + moff * 1.0002f + 1e-6f;
      } else {
        c = make_float4(anchor[b * 3 + 0], anchor[b * 3 + 1], anchor[b * 3 + 2], 0.f);
        rad = 0.0501f + moff * 1.0002f + 1e-6f;
      }
    }
    c.w = rad;
    return c;
  };

  if (owner) {
    float x = base[qloc * 3 + 0], y = base[qloc * 3 + 1], z = base[qloc * 3 + 2];
    own[lane] = make_float4(x, y, z, x * x + y * y + z * z);
  }
  float qx = 0.f, qy = 0.f, qz = 0.f, sqi = 0.f;
  if (owner) {
    float4 q = own[lane];
    qx = q.x; qy = q.y; qz = q.z; sqi = q.w;
  }

  float bd[KNN];
  int   bi[KNN];
  #pragma unroll
  for (int u = 0; u < KNN; ++u) { bd[u] = 3e38f; bi[u] = 0x7fffffff; }

  #pragma unroll 1
  for (int j = 0; j < GS; ++j) {
    float4 cj = own[j];
    float d2 = sqi + cj.w - 2.0f * (qx * cj.x + qy * cj.y + qz * cj.z);
    if (owner && j != lane && d2 < bd[KNN - 1]) {
      bd[KNN - 1] = d2; bi[KNN - 1] = p * GS + j;
      #pragma unroll
      for (int u = KNN - 1; u > 0; --u) {
        if (bd[u] < bd[u - 1]) {
          float td = bd[u]; bd[u] = bd[u - 1]; bd[u - 1] = td;
          int   ti = bi[u]; bi[u] = bi[u - 1]; bi[u - 1] = ti;
        }
      }
    }
  }

  float t = owner ? bd[KNN - 1] : 0.f;
  #pragma unroll
  for (int mm = 1; mm < 64; mm <<= 1) t = fmaxf(t, __shfl_xor(t, mm));
  float r = sqrtf(fmaxf(t, 0.f)) * 1.001f + 1e-6f;

  const float4 gp = sph(p);
  const float rlim = r + gp.w;

  int ng = 0;
  #pragma unroll 1
  for (int gs0 = 0; gs0 < NG; gs0 += 64) {
    int g = gs0 + lane;
    bool ok = false;
    if (g < NG && g != p) {
      float4 gq = sph(g);
      float dx = gq.x - gp.x, dy = gq.y - gp.y, dz = gq.z - gp.z;
      float lim = rlim + gq.w;
      ok = (dx * dx + dy * dy + dz * dz) < lim * lim * 1.001f;
    }
    unsigned long long mask = __ballot(ok);
    if (ok) gl[ng + (int)__popcll(mask & ((1ull << lane) - 1ull))] = g;
    ng += (int)__popcll(mask);
  }

  const int total = ng * GS;
  #pragma unroll 1
  for (int cs = 0; cs < total; cs += 64) {
    int ci = cs + lane;
    if (ci < total) {
      int gg = gl[ci / GS];
      int j  = ci % GS;
      int jloc = gg * GS + j;
      float x = base[jloc * 3 + 0], y = base[jloc * 3 + 1], z = base[jloc * 3 + 2];
      tile[lane] = make_float4(x, y, z, x * x + y * y + z * z);
      tilei[lane] = jloc;
    }
    int nj = min(64, total - cs);
    #pragma unroll 1
    for (int jj = 0; jj < nj; ++jj) {
      float4 tt = tile[jj];
      int ti0 = tilei[jj];
      float d2 = sqi + tt.w - 2.0f * (qx * tt.x + qy * tt.y + qz * tt.z);
      if (owner && d2 < bd[KNN - 1]) {
        bd[KNN - 1] = d2; bi[KNN - 1] = ti0;
        #pragma unroll
        for (int u = KNN - 1; u > 0; --u) {
          if (bd[u] < bd[u - 1]) {
            float td = bd[u]; bd[u] = bd[u - 1]; bd[u - 1] = td;
            int   ti = bi[u]; bi[u] = bi[u - 1]; bi[u - 1] = ti;
          }
        }
      }
    }
  }

  if (owner) {
    int gid = b * Npg + qloc;
    #pragma unroll
    for (int u = 0; u < KNN; ++u) idx_out[gid * KNN + u] = b * Npg + bi[u];
  }
}

// ---------------------------------------------------------------------------
// Wave-per-QUERY kNN for stage-3 PRED points (lane-partitioned scan + merge).
__device__ __forceinline__ void knn3_pred_wave(
    const float* __restrict__ xyz_all, const float* __restrict__ ctx_xyz,
    const float* __restrict__ anchor, const int* __restrict__ radmax,
    int b, int q, int lane, int* gl, int* __restrict__ idx_out) {
  const float* base = xyz_all + (size_t)b * NALL * 3;
  const float* cxb  = ctx_xyz + (size_t)b * P_ * 3;
  const int qloc = NCTX + q;
  const int p = NG1 + q / GS;

  const float qx = base[qloc * 3 + 0], qy = base[qloc * 3 + 1], qz = base[qloc * 3 + 2];
  const float sqi = qx * qx + qy * qy + qz * qz;

  float dcur = 3e38f;
  int   icur = 0x7fffffff;
  if (lane < GS) {
    int jloc = p * GS + lane;
    if (jloc != qloc) {
      float x = base[jloc * 3 + 0], y = base[jloc * 3 + 1], z = base[jloc * 3 + 2];
      dcur = sqi + (x * x + y * y + z * z) - 2.0f * (qx * x + qy * y + qz * z);
      icur = jloc;
    }
  }
  float t = 3e38f;
  #pragma unroll 1
  for (int r8 = 0; r8 < KNN; ++r8) {
    float d = dcur; int i = icur;
    #pragma unroll
    for (int mm = 1; mm < 64; mm <<= 1) {
      float od = __shfl_xor(d, mm);
      int   oi = __shfl_xor(i, mm);
      if (od < d || (od == d && oi < i)) { d = od; i = oi; }
    }
    t = d;
    if (icur == i) { dcur = 3e38f; icur = 0x7fffffff; }
  }
  float r = sqrtf(fmaxf(t, 0.f)) * 1.001f + 1e-6f;

  int ng = 0;
  #pragma unroll 1
  for (int gs0 = 0; gs0 < NG3; gs0 += 64) {
    int g = gs0 + lane;
    bool ok = false;
    if (g < NG3) {
      float cx, cy, cz, rad;
      float moff = __int_as_float(radmax[b * NG3 + g]) * 1.0002f + 1e-6f;
      if (g < NG1) {
        cx = cxb[g * 3 + 0]; cy = cxb[g * 3 + 1]; cz = cxb[g * 3 + 2];
        rad = 0.0201f + moff;
      } else {
        cx = anchor[b * 3 + 0]; cy = anchor[b * 3 + 1]; cz = anchor[b * 3 + 2];
        rad = 0.0501f + moff;
      }
      float dx = cx - qx, dy = cy - qy, dz = cz - qz;
      float lim = r + rad;
      ok = (dx * dx + dy * dy + dz * dz) < lim * lim * 1.001f;
    }
    unsigned long long mask = __ballot(ok);
    if (ok) gl[ng + (int)__popcll(mask & ((1ull << lane) - 1ull))] = g;
    ng += (int)__popcll(mask);
  }

  float bd[KNN];
  int   bi[KNN];
  #pragma unroll
  for (int u = 0; u < KNN; ++u) { bd[u] = 3e38f; bi[u] = 0x7fffffff; }
  const int total = ng * GS;
  #pragma unroll 2
  for (int ci = lane; ci < total; ci += 64) {
    int gg = gl[ci / GS];
    int j  = ci % GS;
    int jloc = gg * GS + j;
    float x = base[jloc * 3 + 0], y = base[jloc * 3 + 1], z = base[jloc * 3 + 2];
    float d2 = sqi + (x * x + y * y + z * z) - 2.0f * (qx * x + qy * y + qz * z);
    if (jloc != qloc && d2 < bd[KNN - 1]) {
      bd[KNN - 1] = d2; bi[KNN - 1] = jloc;
      #pragma unroll
      for (int u = KNN - 1; u > 0; --u) {
        if (bd[u] < bd[u - 1]) {
          float td = bd[u]; bd[u] = bd[u - 1]; bd[u - 1] = td;
          int   ti = bi[u]; bi[u] = bi[u - 1]; bi[u - 1] = ti;
        }
      }
    }
  }

  const int gid = b * NALL + qloc;
  #pragma unroll 1
  for (int r8 = 0; r8 < KNN; ++r8) {
    float d = bd[0]; int i = bi[0];
    #pragma unroll
    for (int mm = 1; mm < 64; mm <<= 1) {
      float od = __shfl_xor(d, mm);
      int   oi = __shfl_xor(i, mm);
      if (od < d || (od == d && oi < i)) { d = od; i = oi; }
    }
    if (lane == 0) idx_out[gid * KNN + r8] = b * NALL + i;
    if (bi[0] == i) {
      #pragma unroll
      for (int u = 0; u < KNN - 1; ++u) { bd[u] = bd[u + 1]; bi[u] = bi[u + 1]; }
      bd[KNN - 1] = 3e38f; bi[KNN - 1] = 0x7fffffff;
    }
  }
}

// ---------------------------------------------------------------------------
// FUSED: stage-1 AB assembly + stage-1 kNN (ctx groups only).
__global__ __launch_bounds__(256) void ab12_knn1_kernel(
    const float* __restrict__ Tp, const float* __restrict__ xyz_all,
    const float* __restrict__ Wcat, const float* __restrict__ cb,
    const float* __restrict__ ctx_xyz,
    float* __restrict__ AB, int* __restrict__ idx1) {
  __shared__ float4 own[4][GS];
  __shared__ int    gl[4][NG1];
  __shared__ float4 tile[4][64];
  __shared__ int    tilei[4][64];
  const int tid = threadIdx.x;
  if (blockIdx.x < AB1_BLOCKS) {
    const int base = blockIdx.x * 8;
    const float wx = Wcat[128 * 256 + tid];
    const float wy = Wcat[129 * 256 + tid];
    const float wz = Wcat[130 * 256 + tid];
    const float cbv = cb[tid];
    #pragma unroll
    for (int p = 0; p < 8; ++p) {
      int n = base + p;
      int b = n / NCTX, loc = n % NCTX;
      int trow = b * (NCTX / GS) + loc / GS;
      const float* xr = xyz_all + (size_t)(b * NALL + loc) * 3;
      float x = xr[0], y = xr[1], z = xr[2];
      float v = cbv;
      #pragma unroll
      for (int s = 0; s < KSPLIT; ++s)
        v += Tp[((size_t)s * TROWS + trow) * 256 + tid];
      v = fmaf(x, wx, v);
      v = fmaf(y, wy, v);
      v = fmaf(z, wz, v);
      AB[(size_t)n * 256 + tid] = v;
    }
  } else {
    int kblk = blockIdx.x - AB1_BLOCKS;
    int w = tid >> 6, lane = tid & 63;
    int b = kblk / (NG1 / 4);
    int p = (kblk % (NG1 / 4)) * 4 + w;
    knn_wave_body<1>(xyz_all, ctx_xyz, nullptr, nullptr, b, p, lane,
                     own[w], gl[w], tile[w], tilei[w], idx1);
  }
}

// ---------------------------------------------------------------------------
// FUSED: stage-2 AB assembly + stage-2 small kNN.
__global__ __launch_bounds__(256) void ab12_knn2_kernel(
    const float* __restrict__ Tp, const float* __restrict__ xyz_all,
    const float* __restrict__ Wcat, const float* __restrict__ cb,
    float* __restrict__ AB, int* __restrict__ idx2) {
  const int tid = threadIdx.x;
  if (blockIdx.x < AB2_BLOCKS) {
    const int base = blockIdx.x * 8;
    const float wx = Wcat[128 * 256 + tid];
    const float wy = Wcat[129 * 256 + tid];
    const float wz = Wcat[130 * 256 + tid];
    const float cbv = cb[tid];
    #pragma unroll
    for (int p = 0; p < 8; ++p) {
      int n = base + p;
      int b = n / NPRD, loc = n % NPRD;
      int trow = B_ * P_ + b * (NPRD / GS) + loc / GS;
      const float* xr = xyz_all + (size_t)(b * NALL + NCTX + loc) * 3;
      float x = xr[0], y = xr[1], z = xr[2];
      float v = cbv;
      #pragma unroll
      for (int s = 0; s < KSPLIT; ++s)
        v += Tp[((size_t)s * TROWS + trow) * 256 + tid];
      v = fmaf(x, wx, v);
      v = fmaf(y, wy, v);
      v = fmaf(z, wz, v);
      AB[(size_t)n * 256 + tid] = v;
    }
  } else {
    int q = (blockIdx.x - AB2_BLOCKS) * 256 + tid;
    int gr = q / RP, qi = q % RP;
    int b = gr / M_, w = gr % M_;
    const float* base = xyz_all + (size_t)(b * NALL + NCTX + w * RP) * 3;
    float cx[RP], cy[RP], cz[RP], cs[RP];
    #pragma unroll
    for (int j = 0; j < RP; ++j) {
      cx[j] = base[j * 3 + 0]; cy[j] = base[j * 3 + 1]; cz[j] = base[j * 3 + 2];
      cs[j] = cx[j] * cx[j] + cy[j] * cy[j] + cz[j] * cz[j];
    }
    float qx = cx[0], qy = cy[0], qz = cz[0], sqi = cs[0];
    #pragma unroll
    for (int j = 0; j < RP; ++j) {
      if (j == qi) { qx = cx[j]; qy = cy[j]; qz = cz[j]; sqi = cs[j]; }
    }
    float bd[KNN];
    int   bi[KNN];
    #pragma unroll
    for (int u = 0; u < KNN; ++u) { bd[u] = 3e38f; bi[u] = 0; }
    #pragma unroll
    for (int j = 0; j < RP; ++j) {
      float d2 = sqi + cs[j] - 2.0f * (qx * cx[j] + qy * cy[j] + qz * cz[j]);
      if (j != qi && d2 < bd[KNN - 1]) {
        bd[KNN - 1] = d2; bi[KNN - 1] = j;
        #pragma unroll
        for (int u = KNN - 1; u > 0; --u) {
          if (bd[u] < bd[u - 1]) {
            float td = bd[u]; bd[u] = bd[u - 1]; bd[u - 1] = td;
            int   ti = bi[u]; bi[u] = bi[u - 1]; bi[u - 1] = ti;
          }
        }
      }
    }
    #pragma unroll
    for (int u = 0; u < KNN; ++u) idx2[q * KNN + u] = gr * RP + bi[u];
  }
}

// ---------------------------------------------------------------------------
// FUSED: stage-3 precompute as LDS-free MFMA GEMM | ctx-group kNN | pred kNN.
// GEMM: AB[n][c] = feat[n] @ WcatT(c<128 part) + be1/0 + xyz(n)·Wcat_xyz + ...
// A fragments converted fp32->bf16 hi/lo in registers straight from global.
__global__ __launch_bounds__(256) void pre3_knn3_kernel(
    const float* __restrict__ feat, const float* __restrict__ xyz_all,
    const float* __restrict__ Wcat, const float* __restrict__ be1,
    const unsigned short* __restrict__ wcatT_hi, const unsigned short* __restrict__ wcatT_lo,
    const float* __restrict__ ctx_xyz, const float* __restrict__ anchor,
    const int* __restrict__ radmax,
    float* __restrict__ AB, int* __restrict__ idx3) {
  __shared__ float4 own[4][GS];
  __shared__ int    gl[4][NG3];
  __shared__ float4 tile[4][64];
  __shared__ int    tilei[4][64];
  const int tid = threadIdx.x;
  if (blockIdx.x < P3G_BLOCKS) {
    const int lane = tid & 63, w = tid >> 6;
    const int m = lane & 15, quad = lane >> 4;
    const int r0 = blockIdx.x * 64;
    const float* arow = feat + (size_t)(r0 + w * 16 + m) * C;

    f32x4 acc[16];
    #pragma unroll
    for (int nt = 0; nt < 16; ++nt) acc[nt] = (f32x4){0.f, 0.f, 0.f, 0.f};

    #pragma unroll
    for (int ks = 0; ks < 4; ++ks) {
      int k0 = ks * 32 + quad * 8;
      f32x4 a0 = *(const f32x4*)(arow + k0);
      f32x4 a1 = *(const f32x4*)(arow + k0 + 4);
      bf16x8 ahi, alo;
      split8(a0, a1, ahi, alo);
      #pragma unroll
      for (int nt = 0; nt < 16; ++nt) {
        int n = nt * 16 + m;
        bf16x8 bh = *(const bf16x8*)(wcatT_hi + n * 128 + k0);
        bf16x8 bl = *(const bf16x8*)(wcatT_lo + n * 128 + k0);
        acc[nt] = __builtin_amdgcn_mfma_f32_16x16x32_bf16(ahi, bh, acc[nt], 0, 0, 0);
        acc[nt] = __builtin_amdgcn_mfma_f32_16x16x32_bf16(ahi, bl, acc[nt], 0, 0, 0);
        acc[nt] = __builtin_amdgcn_mfma_f32_16x16x32_bf16(alo, bh, acc[nt], 0, 0, 0);
      }
    }
    // epilogue: rows r0+w*16+quad*4+reg (== global xyz row), cols nt*16+m
    float xr[4], yr[4], zr[4];
    #pragma unroll
    for (int reg = 0; reg < 4; ++reg) {
      int row = r0 + w * 16 + quad * 4 + reg;
      xr[reg] = xyz_all[row * 3 + 0];
      yr[reg] = xyz_all[row * 3 + 1];
      zr[reg] = xyz_all[row * 3 + 2];
    }
    #pragma unroll
    for (int nt = 0; nt < 16; ++nt) {
      int col = nt * 16 + m;
      float cbv = (col < C) ? be1[col] : 0.0f;
      float wx = Wcat[128 * 256 + col];
      float wy = Wcat[129 * 256 + col];
      float wz = Wcat[130 * 256 + col];
      #pragma unroll
      for (int reg = 0; reg < 4; ++reg) {
        int row = r0 + w * 16 + quad * 4 + reg;
        float v = acc[nt][reg] + cbv;
        v = fmaf(xr[reg], wx, v);
        v = fmaf(yr[reg], wy, v);
        v = fmaf(zr[reg], wz, v);
        AB[(size_t)row * 256 + col] = v;
      }
    }
  } else if (blockIdx.x < P3G_BLOCKS + KNN3C_BLOCKS) {
    int kblk = blockIdx.x - P3G_BLOCKS;
    int w = tid >> 6, lane = tid & 63;
    int b = kblk / (NG1 / 4);
    int p = (kblk % (NG1 / 4)) * 4 + w;     // ctx groups only: p < NG1
    knn_wave_body<3>(xyz_all, ctx_xyz, anchor, radmax, b, p, lane,
                     own[w], gl[w], tile[w], tilei[w], idx3);
  } else {
    int kblk = blockIdx.x - P3G_BLOCKS - KNN3C_BLOCKS;
    int w = tid >> 6, lane = tid & 63;
    int wid = kblk * 4 + w;                  // 0 .. B*NPRD-1
    int b = wid / NPRD, q = wid % NPRD;
    knn3_pred_wave(xyz_all, ctx_xyz, anchor, radmax, b, q, lane, gl[w], idx3);
  }
}

// ---------------------------------------------------------------------------
// MFMA EdgeConv core (split-bf16, 3 MFMAs, ~2^-16 err).
__global__ __launch_bounds__(256) void conv_mfma_kernel(const float* __restrict__ AB,
                                                        const int* __restrict__ idx,
                                                        const unsigned short* __restrict__ w2hi_g,
                                                        const unsigned short* __restrict__ w2lo_g,
                                                        const float* __restrict__ be2,
                                                        float* __restrict__ feat_out,
                                                        int NPB, int row_off) {
  __shared__ unsigned short hhi[64 * 128];    // 16 KB
  __shared__ unsigned short hlo[64 * 128];    // 16 KB
  __shared__ unsigned short w2hi[128 * 128];  // 32 KB
  const int tid = threadIdx.x;
  const int base = blockIdx.x * 8;

  #pragma unroll
  for (int i = 0; i < 8; ++i) {
    int q = tid + 256 * i;
    int n = q >> 4, c = q & 15;
    f32x4 v = *(const f32x4*)(w2hi_g + n * 128 + c * 8);
    *(f32x4*)(w2hi + (n * 16 + (c ^ (n & 15))) * 8) = v;
  }

  #pragma unroll
  for (int i = 0; i < 4; ++i) {
    int task = tid + 256 * i;
    int r = task >> 4, c = task & 15;
    int p = r >> 3, nb = r & 7;
    int g = base + p;
    int j = idx[g * KNN + nb];
    const float* aP = AB + (size_t)g * 256 + c * 8;
    const float* bP = AB + (size_t)j * 256 + 128 + c * 8;
    f32x4 a0 = *(const f32x4*)aP;
    f32x4 a1 = *(const f32x4*)(aP + 4);
    f32x4 b0 = *(const f32x4*)bP;
    f32x4 b1 = *(const f32x4*)(bP + 4);
    f32x4 s0 = {fmaxf(a0.x + b0.x, 0.f), fmaxf(a0.y + b0.y, 0.f),
                fmaxf(a0.z + b0.z, 0.f), fmaxf(a0.w + b0.w, 0.f)};
    f32x4 s1 = {fmaxf(a1.x + b1.x, 0.f), fmaxf(a1.y + b1.y, 0.f),
                fmaxf(a1.z + b1.z, 0.f), fmaxf(a1.w + b1.w, 0.f)};
    bf16x8 oh, ol;
    split8(s0, s1, oh, ol);
    int dst = (r * 16 + (c ^ (r & 15))) * 8;
    *(bf16x8*)(hhi + dst) = oh;
    *(bf16x8*)(hlo + dst) = ol;
  }
  __syncthreads();

  const int lane = tid & 63, w = tid >> 6;
  const int m = lane & 15, quad = lane >> 4;
  f32x4 acc[8];
  #pragma unroll
  for (int nt = 0; nt < 8; ++nt) acc[nt] = (f32x4){0.f, 0.f, 0.f, 0.f};

  #pragma unroll 1
  for (int ks = 0; ks < 4; ++ks) {
    int c0 = ks * 4 + quad;
    int rowA = w * 16 + m;
    int aoff = (rowA * 16 + (c0 ^ m)) * 8;
    bf16x8 ahi = *(const bf16x8*)(hhi + aoff);
    bf16x8 alo = *(const bf16x8*)(hlo + aoff);
    #pragma unroll
    for (int nt = 0; nt < 8; ++nt) {
      int n = nt * 16 + m;
      bf16x8 bhi = *(const bf16x8*)(w2hi + (n * 16 + (c0 ^ m)) * 8);
      bf16x8 blo = *(const bf16x8*)(w2lo_g + n * 128 + c0 * 8);
      acc[nt] = __builtin_amdgcn_mfma_f32_16x16x32_bf16(ahi, bhi, acc[nt], 0, 0, 0);
      acc[nt] = __builtin_amdgcn_mfma_f32_16x16x32_bf16(ahi, blo, acc[nt], 0, 0, 0);
      acc[nt] = __builtin_amdgcn_mfma_f32_16x16x32_bf16(alo, bhi, acc[nt], 0, 0, 0);
    }
  }

  int pt = 2 * w + (quad >> 1);
  int g = base + pt;
  int b = g / NPB, loc = g % NPB;
  float* orow = feat_out + (size_t)(b * NALL + row_off + loc) * C;
  bool writer = (quad & 1) == 0;
  #pragma unroll
  for (int nt = 0; nt < 8; ++nt) {
    float v = fmaxf(fmaxf(acc[nt].x, acc[nt].y), fmaxf(acc[nt].z, acc[nt].w));
    v = fmaxf(v, __shfl_xor(v, 16));
    if (writer) {
      int col = nt * 16 + m;
      orow[col] = v + be2[col];
    }
  }
}

// ---------------------------------------------------------------------------
// MFMA offset MLP: out_row = xyz_in_row + (relu(f@W1+b1) @ W2 + b2).
// Layer-1 via LDS-free split-bf16 MFMA (W1T hi/lo pre-transposed); layer-2
// in fp32 via per-lane partials + shfl_xor reduce within each 16-lane quad.
__global__ __launch_bounds__(256) void offset_mfma_kernel(
    const float* __restrict__ feat,
    const unsigned short* __restrict__ w1T_hi, const unsigned short* __restrict__ w1T_lo,
    const float* __restrict__ b1, const float* __restrict__ W2, const float* __restrict__ b2,
    const float* __restrict__ xyz_in, float* __restrict__ xyz_out,
    int NPB, int row_off, int* __restrict__ radmax) {
  const int tid = threadIdx.x;
  const int lane = tid & 63, w = tid >> 6;
  const int m = lane & 15, quad = lane >> 4;
  const int r0 = blockIdx.x * 64;

  // A row for fragments (blocks never straddle a batch: NPB % 64 == 0)
  int nA = r0 + w * 16 + m;
  int bA = nA / NPB, locA = nA % NPB;
  const float* arow = feat + (size_t)(bA * NALL + row_off + locA) * C;

  f32x4 acc[8];
  #pragma unroll
  for (int nt = 0; nt < 8; ++nt) acc[nt] = (f32x4){0.f, 0.f, 0.f, 0.f};

  #pragma unroll
  for (int ks = 0; ks < 4; ++ks) {
    int k0 = ks * 32 + quad * 8;
    f32x4 a0 = *(const f32x4*)(arow + k0);
    f32x4 a1 = *(const f32x4*)(arow + k0 + 4);
    bf16x8 ahi, alo;
    split8(a0, a1, ahi, alo);
    #pragma unroll
    for (int nt = 0; nt < 8; ++nt) {
      int n = nt * 16 + m;
      bf16x8 bh = *(const bf16x8*)(w1T_hi + n * 128 + k0);
      bf16x8 bl = *(const bf16x8*)(w1T_lo + n * 128 + k0);
      acc[nt] = __builtin_amdgcn_mfma_f32_16x16x32_bf16(ahi, bh, acc[nt], 0, 0, 0);
      acc[nt] = __builtin_amdgcn_mfma_f32_16x16x32_bf16(ahi, bl, acc[nt], 0, 0, 0);
      acc[nt] = __builtin_amdgcn_mfma_f32_16x16x32_bf16(alo, bh, acc[nt], 0, 0, 0);
    }
  }

  // layer 2: rows r0+w*16+quad*4+reg, cols nt*16+m (each col once per quad-row)
  float p0[4] = {0.f, 0.f, 0.f, 0.f};
  float p1[4] = {0.f, 0.f, 0.f, 0.f};
  float p2[4] = {0.f, 0.f, 0.f, 0.f};
  #pragma unroll
  for (int nt = 0; nt < 8; ++nt) {
    int col = nt * 16 + m;
    float b1v = b1[col];
    float w20 = W2[col * 3 + 0], w21 = W2[col * 3 + 1], w22 = W2[col * 3 + 2];
    #pragma unroll
    for (int reg = 0; reg < 4; ++reg) {
      float h = fmaxf(acc[nt][reg] + b1v, 0.0f);
      p0[reg] = fmaf(h, w20, p0[reg]);
      p1[reg] = fmaf(h, w21, p1[reg]);
      p2[reg] = fmaf(h, w22, p2[reg]);
    }
  }
  #pragma unroll
  for (int o = 1; o < 16; o <<= 1) {
    #pragma unroll
    for (int reg = 0; reg < 4; ++reg) {
      p0[reg] += __shfl_xor(p0[reg], o);
      p1[reg] += __shfl_xor(p1[reg], o);
      p2[reg] += __shfl_xor(p2[reg], o);
    }
  }
  if (m == 0) {
    float b20 = b2[0], b21 = b2[1], b22 = b2[2];
    #pragma unroll
    for (int reg = 0; reg < 4; ++reg) {
      int nO = r0 + w * 16 + quad * 4 + reg;
      int b = nO / NPB, loc = nO % NPB;
      int row = (b * NALL + row_off + loc) * 3;
      float o0 = p0[reg] + b20;
      float o1 = p1[reg] + b21;
      float o2 = p2[reg] + b22;
      xyz_out[row + 0] = xyz_in[row + 0] + o0;
      xyz_out[row + 1] = xyz_in[row + 1] + o1;
      xyz_out[row + 2] = xyz_in[row + 2] + o2;
      if (radmax != nullptr) {
        float mag = sqrtf(o0 * o0 + o1 * o1 + o2 * o2);
        atomicMax(radmax + b * NG3 + (row_off + loc) / GS, __float_as_int(mag));
      }
    }
  }
}

// ---------------------------------------------------------------------------
extern "C" void kernel_launch(void* const* d_in, const int* in_sizes, int n_in,
                              void* d_out, int out_size, void* d_ws, size_t ws_size,
                              hipStream_t stream) {
  (void)in_sizes; (void)n_in; (void)out_size; (void)ws_size;
  const float* ctx_xyz   = (const float*)d_in[0];
  const float* ctx_tok   = (const float*)d_in[1];
  const float* pred_tok  = (const float*)d_in[2];
  const float* noise_ctx = (const float*)d_in[3];
  const float* noise_prd = (const float*)d_in[4];
  const float* Wp  = (const float*)d_in[5];
  const float* bp  = (const float*)d_in[6];
  const float* We1 = (const float*)d_in[7];
  const float* be1 = (const float*)d_in[8];
  const float* We2 = (const float*)d_in[9];
  const float* be2 = (const float*)d_in[10];
  const float* Wc1 = (const float*)d_in[11];
  const float* bc1 = (const float*)d_in[12];
  const float* Wc2 = (const float*)d_in[13];
  const float* bc2 = (const float*)d_in[14];
  const float* Wq1 = (const float*)d_in[15];
  const float* bq1 = (const float*)d_in[16];
  const float* Wq2 = (const float*)d_in[17];
  const float* bq2 = (const float*)d_in[18];
  const float* Wf1 = (const float*)d_in[19];
  const float* bf1 = (const float*)d_in[20];
  const float* Wf2 = (const float*)d_in[21];
  const float* bf2 = (const float*)d_in[22];
  float* out = (float*)d_out;

  // workspace layout (floats)
  float* ws        = (float*)d_ws;
  float* T         = ws;                          // 1792*256 (legacy slot)
  float* anchor    = T + TROWS * 256;             // 16
  float* xyz_all   = anchor + 16;                 // B*NALL*3    = 64512
  float* feat_in   = xyz_all + B_ * NALL * 3;     // B*NALL*C    = 2752512
  float* feat_out  = feat_in + B_ * NALL * C;     // B*NALL*C    = 2752512
  float* AB        = feat_out + B_ * NALL * C;    // B*NALL*256  = 5505024
  float* Wcat      = AB + B_ * NALL * 256;        // 131*256     = 33536
  float* cb        = Wcat + 131 * 256;            // 256
  int*   idx1      = (int*)(cb + 256);            // B*NCTX*8    = 147456
  int*   idx2      = idx1 + B_ * NCTX * KNN;      // B*NPRD*8    = 24576
  int*   idx3      = idx2 + B_ * NPRD * KNN;      // B*NALL*8    = 172032
  unsigned short* we2hi = (unsigned short*)(idx3 + B_ * NALL * KNN); // 16384
  unsigned short* we2lo = we2hi + C * C;                             // 16384
  int*   radmax    = (int*)(we2lo + C * C);       // B*NG3       = 1792 ints
  unsigned short* wcatT_hi = (unsigned short*)(radmax + B_ * NG3);   // 32768
  unsigned short* wcatT_lo = wcatT_hi + 256 * 128;                   // 32768
  unsigned short* w1T_hi   = wcatT_lo + 256 * 128;                   // 3*16384
  unsigned short* w1T_lo   = w1T_hi + 3 * C * C;                     // 3*16384
  // wbT aliases AB: fully consumed by t12_mfma before the first AB write.
  unsigned short* wbT_hi = (unsigned short*)AB;   // 256*1024 ushorts
  unsigned short* wbT_lo = wbT_hi + 256 * TOK;    // 256*1024 ushorts
  // Tpart aliases feat_out: last read at ab12_knn2 (stage 2), feat_out first
  // written at stage-3 conv. KSPLIT*TROWS*256 = 1835008 <= 2752512 floats.
  float* Tpart = feat_out;

  // prep (fused)
  prep1_kernel<<<388, 256, 0, stream>>>(We1, We2, ctx_xyz, Wc1, Wq1, Wf1,
                                        Wcat, we2hi, we2lo, anchor, w1T_hi, w1T_lo);
  prep2_kernel<<<TOK / 4 + 1 + 128, 256, 0, stream>>>(Wp, bp, Wcat, be1,
                                                      wbT_hi, wbT_lo, cb,
                                                      wcatT_hi, wcatT_lo);
  build_all_kernel<<<72 + 12, 256, 0, stream>>>(ctx_xyz, noise_ctx, noise_prd, anchor,
                                                xyz_all, radmax);

  // token GEMM (split-K x4): Tpart[s] = [ctx_tok; pred_tok] @ Wbig[kslice s]
  t12_mfma_kernel<<<dim3(TROWS / 64, 2, KSPLIT), 256, 0, stream>>>(ctx_tok, pred_tok,
                                                                   wbT_hi, wbT_lo, Tpart);

  // ---- stage 1: context branch ----
  ab12_knn1_kernel<<<AB1_BLOCKS + KNN1_BLOCKS, 256, 0, stream>>>(Tpart, xyz_all, Wcat, cb,
                                                                 ctx_xyz, AB, idx1);
  conv_mfma_kernel<<<(B_ * NCTX) / 8, 256, 0, stream>>>(AB, idx1, we2hi, we2lo, be2, feat_in, NCTX, 0);
  offset_mfma_kernel<<<(B_ * NCTX) / 64, 256, 0, stream>>>(feat_in, w1T_hi, w1T_lo,
                                                           bc1, Wc2, bc2,
                                                           xyz_all, xyz_all, NCTX, 0, radmax);

  // ---- stage 2: prediction branch ----
  ab12_knn2_kernel<<<AB2_BLOCKS + KNS_BLOCKS, 256, 0, stream>>>(Tpart, xyz_all, Wcat, cb, AB, idx2);
  conv_mfma_kernel<<<(B_ * NPRD) / 8, 256, 0, stream>>>(AB, idx2, we2hi, we2lo, be2, feat_in, NPRD, NCTX);
  offset_mfma_kernel<<<(B_ * NPRD) / 64, 256, 0, stream>>>(feat_in, w1T_hi + C * C, w1T_lo + C * C,
                                                           bq1, Wq2, bq2,
                                                           xyz_all, xyz_all, NPRD, NCTX, radmax);

  // ---- stage 3: global refinement ----
  pre3_knn3_kernel<<<P3G_BLOCKS + KNN3C_BLOCKS + KNN3P_BLOCKS, 256, 0, stream>>>(
      feat_in, xyz_all, Wcat, be1, wcatT_hi, wcatT_lo, ctx_xyz, anchor, radmax, AB, idx3);
  conv_mfma_kernel<<<(B_ * NALL) / 8, 256, 0, stream>>>(AB, idx3, we2hi, we2lo, be2, feat_out, NALL, 0);
  offset_mfma_kernel<<<(B_ * NALL) / 64, 256, 0, stream>>>(feat_out, w1T_hi + 2 * C * C, w1T_lo + 2 * C * C,
                                                           bf1, Wf2, bf2,
                                                           xyz_all, out, NALL, 0, nullptr);
}